// Round 16
// baseline (609.488 us; speedup 1.0000x reference)
//
#include <hip/hip_runtime.h>
#include <stdint.h>

typedef __attribute__((ext_vector_type(8))) short bf16x8;
typedef __attribute__((ext_vector_type(4))) float f32x4;

// ---- problem dims ----
#define B_    16
#define S_    256
#define LEFT_ 768
#define KT_   1024
#define D_    512
#define H_    8
#define G_    4
#define HD_   64
#define L_    4
#define FFH_  2048
#define M_    4096   // B*S
#define LOG2E 1.44269504f

__device__ __forceinline__ unsigned short f2b(float f){
  unsigned u = __float_as_uint(f);
  u += 0x7fffu + ((u>>16)&1u);
  return (unsigned short)(u>>16);
}

__device__ __forceinline__ void gl_lds16(const unsigned short* g, void* l){
  __builtin_amdgcn_global_load_lds(
    (const __attribute__((address_space(1))) unsigned int*)g,
    (__attribute__((address_space(3))) unsigned int*)l, 16, 0, 0);
}

// ================= MFMA GEMM core (NT layout), double-buffered, BK=32 ============
template<int BM, int BN, int WM, int WN, class BRowF>
__device__ __forceinline__ void mfma_core(
    const unsigned short* Abase, int lda, int m0, BRowF brow,
    int kd, char* As, char* Bs, f32x4* acc)
{
  constexpr int FR = WM/16, FC = WN/16;
  constexpr int NWC = BN/WN;
  constexpr int CA = BM/64, CB = BN/64;
  const int tid = threadIdx.x, wave = tid>>6, lane = tid&63;
  const int wr = wave / NWC, wc = wave % NWC;
  const int lr = lane>>2;
  const int swl = (lane&3) ^ ((lane>>2)&3) ^ (lane>>4);

  auto stage = [&](int buf, int k0){
    #pragma unroll
    for (int i = 0; i < CA; ++i) {
      const int chunk = wave*CA + i;
      const unsigned short* gp = Abase + (size_t)(m0 + chunk*16 + lr)*lda + k0 + swl*8;
      gl_lds16(gp, As + buf*(BM*64) + chunk*1024);
    }
    #pragma unroll
    for (int i = 0; i < CB; ++i) {
      const int chunk = wave*CB + i;
      const unsigned short* gp = brow(chunk*16 + lr) + k0 + swl*8;
      gl_lds16(gp, Bs + buf*(BN*64) + chunk*1024);
    }
  };

  stage(0, 0);
  __syncthreads();
  int cur = 0;
  for (int k0 = 0; k0 < kd; k0 += 32) {
    if (k0 + 32 < kd) stage(cur^1, k0 + 32);
    bf16x8 af[FR], bfr[FC];
    #pragma unroll
    for (int r = 0; r < FR; ++r)
      af[r] = *(const bf16x8*)(As + cur*(BM*64) + (wr*WM + r*16 + (lane&15))*64 + swl*16);
    #pragma unroll
    for (int c = 0; c < FC; ++c)
      bfr[c] = *(const bf16x8*)(Bs + cur*(BN*64) + (wc*WN + c*16 + (lane&15))*64 + swl*16);
    #pragma unroll
    for (int r = 0; r < FR; ++r)
      #pragma unroll
      for (int c = 0; c < FC; ++c)
        acc[r*FC+c] = __builtin_amdgcn_mfma_f32_16x16x32_bf16(af[r], bfr[c], acc[r*FC+c], 0, 0, 0);
    __syncthreads();
    cur ^= 1;
  }
}

// ================= unified weight transpose+convert =================
__device__ __forceinline__ void tcvt_body(
    const float* __restrict__ src, unsigned short* __restrict__ dst,
    int K, int N, int ntk, int ntn, int bx)
{
  __shared__ float t[64][65];
  int kt = bx % ntk; int nt = (bx/ntk) % ntn; int l = bx/(ntk*ntn);
  src += (size_t)l*K*N; dst += (size_t)l*N*K;
  const int k0 = kt*64, n0 = nt*64;
  const int tid = threadIdx.x;
  #pragma unroll
  for (int i = 0; i < 4; ++i) {
    int kr = (tid>>4) + i*16;
    const float4 v = *(const float4*)&src[(size_t)(k0+kr)*N + n0 + (tid&15)*4];
    t[kr][(tid&15)*4+0]=v.x; t[kr][(tid&15)*4+1]=v.y;
    t[kr][(tid&15)*4+2]=v.z; t[kr][(tid&15)*4+3]=v.w;
  }
  __syncthreads();
  const int nn = tid>>2, kk = (tid&3)*16;
  unsigned w[8];
  #pragma unroll
  for (int j = 0; j < 8; ++j)
    w[j] = (unsigned)f2b(t[kk+2*j][nn]) | ((unsigned)f2b(t[kk+2*j+1][nn])<<16);
  size_t off = (size_t)(n0+nn)*K + k0 + kk;
  *(uint4*)&dst[off]     = make_uint4(w[0],w[1],w[2],w[3]);
  *(uint4*)&dst[off + 8] = make_uint4(w[4],w[5],w[6],w[7]);
}

__global__ __launch_bounds__(256) void transpose_all(
    const float* __restrict__ Wq, const float* __restrict__ Wk,
    const float* __restrict__ Wv, const float* __restrict__ Wo,
    const float* __restrict__ W1, const float* __restrict__ W3,
    const float* __restrict__ W2,
    unsigned short* __restrict__ Wqt, unsigned short* __restrict__ Wkt,
    unsigned short* __restrict__ Wvt, unsigned short* __restrict__ Wot,
    unsigned short* __restrict__ W1t, unsigned short* __restrict__ W3t,
    unsigned short* __restrict__ W2t)
{
  int bx = blockIdx.x;
  if      (bx < 256)  tcvt_body(Wq, Wqt, 512, 512, 8, 8,  bx);
  else if (bx < 384)  tcvt_body(Wk, Wkt, 512, 256, 8, 4,  bx-256);
  else if (bx < 512)  tcvt_body(Wv, Wvt, 512, 256, 8, 4,  bx-384);
  else if (bx < 768)  tcvt_body(Wo, Wot, 512, 512, 8, 8,  bx-512);
  else if (bx < 1792) tcvt_body(W1, W1t, 512, 2048, 8, 32, bx-768);
  else if (bx < 2816) tcvt_body(W3, W3t, 512, 2048, 8, 32, bx-1792);
  else                tcvt_body(W2, W2t, 2048, 512, 32, 8, bx-2816);
}

// ======= patchify + input projection: 16 tokens/block, inW staged in LDS =======
__global__ __launch_bounds__(256) void patchify_inproj(
    const float* __restrict__ x, const float* __restrict__ inW,
    const float* __restrict__ inb, float* __restrict__ h)
{
  __shared__ float wlds[32*512];
  __shared__ float ps[16][33];
  const int tid = threadIdx.x;
  const int tb = blockIdx.x*16;

  #pragma unroll
  for (int i = 0; i < 16; ++i)
    ((float4*)wlds)[i*256 + tid] = ((const float4*)inW)[i*256 + tid];
  {
    int tok = tid >> 5, idx = tid & 31;
    int bs = tb + tok;
    int b = bs >> 8, s = bs & 255;
    int tic = s >> 6, mf = s & 63;
    int tp = idx >> 3, fp = (idx >> 1) & 3, c = idx & 1;
    ps[tok][idx] = x[((size_t)(b*2 + c)*16 + tic*4 + tp)*256 + mf*4 + fp];
    int tok2 = tok + 8;
    int bs2 = tb + tok2;
    int b2 = bs2 >> 8, s2 = bs2 & 255;
    int tic2 = s2 >> 6, mf2 = s2 & 63;
    ps[tok2][idx] = x[((size_t)(b2*2 + c)*16 + tic2*4 + tp)*256 + mf2*4 + fp];
  }
  __syncthreads();

  const int g = tid >> 4, qd = tid & 15;
  const int bs = tb + g;
  for (int j = 0; j < 32; ++j) {
    int d = j*16 + qd;
    float acc = inb[d];
    #pragma unroll
    for (int i = 0; i < 32; ++i) acc += ps[g][i] * wlds[i*512 + d];
    h[(size_t)bs*512 + d] = acc;
  }
}

// ================= LN1 row stats (one pass over h) =================
__global__ __launch_bounds__(256) void ln_stats(
    const float* __restrict__ h, float* __restrict__ smean, float* __restrict__ srstd)
{
  const int tid = threadIdx.x;
  const int row = blockIdx.x*16 + (tid>>4);
  const int qd = tid & 15;
  const float* rp = h + (size_t)row*512 + qd*32;
  float s = 0.f, sq = 0.f;
  #pragma unroll
  for (int i = 0; i < 8; ++i) {
    float4 v = ((const float4*)rp)[i];
    s  += (v.x+v.y)+(v.z+v.w);
    sq += (v.x*v.x+v.y*v.y)+(v.z*v.z+v.w*v.w);
  }
  #pragma unroll
  for (int o = 1; o < 16; o <<= 1) { s += __shfl_xor(s,o,64); sq += __shfl_xor(sq,o,64); }
  if (qd == 0) {
    float mean = s*(1.f/512.f);
    smean[row] = mean;
    srstd[row] = rsqrtf(sq*(1.f/512.f) - mean*mean + 1e-5f);
  }
}

// ================= lean layernorm f32 -> bf16 (ln2): 16 rows/block =============
__global__ __launch_bounds__(256) void ln_kernel(
    const float* __restrict__ in, unsigned short* __restrict__ out,
    const float* __restrict__ g, const float* __restrict__ bta)
{
  const int tid = threadIdx.x;
  const int row = blockIdx.x*16 + (tid>>4);
  const int qd = tid & 15;
  const float* rp = in + (size_t)row*512 + qd*32;
  float4 xv[8];
  float s = 0.f, sq = 0.f;
  #pragma unroll
  for (int i = 0; i < 8; ++i) {
    xv[i] = ((const float4*)rp)[i];
    s  += (xv[i].x+xv[i].y)+(xv[i].z+xv[i].w);
    sq += (xv[i].x*xv[i].x + xv[i].y*xv[i].y)+(xv[i].z*xv[i].z + xv[i].w*xv[i].w);
  }
  #pragma unroll
  for (int o = 1; o < 16; o <<= 1) { s += __shfl_xor(s,o,64); sq += __shfl_xor(sq,o,64); }
  const float mean = s*(1.f/512.f);
  const float rstd = rsqrtf(sq*(1.f/512.f) - mean*mean + 1e-5f);
  const float* gp = g + qd*32;
  const float* bp = bta + qd*32;
  unsigned short* op = out + (size_t)row*512 + qd*32;
  #pragma unroll
  for (int i = 0; i < 4; ++i) {
    float4 a  = xv[2*i],                 b2 = xv[2*i+1];
    float4 ga = ((const float4*)gp)[2*i], gb = ((const float4*)gp)[2*i+1];
    float4 ba = ((const float4*)bp)[2*i], bb = ((const float4*)bp)[2*i+1];
    unsigned w0 = (unsigned)f2b((a.x-mean)*rstd*ga.x + ba.x) | ((unsigned)f2b((a.y-mean)*rstd*ga.y + ba.y)<<16);
    unsigned w1 = (unsigned)f2b((a.z-mean)*rstd*ga.z + ba.z) | ((unsigned)f2b((a.w-mean)*rstd*ga.w + ba.w)<<16);
    unsigned w2 = (unsigned)f2b((b2.x-mean)*rstd*gb.x + bb.x) | ((unsigned)f2b((b2.y-mean)*rstd*gb.y + bb.y)<<16);
    unsigned w3 = (unsigned)f2b((b2.z-mean)*rstd*gb.z + bb.z) | ((unsigned)f2b((b2.w-mean)*rstd*gb.w + bb.w)<<16);
    *(uint4*)(op + i*8) = make_uint4(w0,w1,w2,w3);
  }
}

// ========== QKV GEMM with fused LN1 (stats precomputed), BK=64 ==============
__global__ __launch_bounds__(256) void qkv_ln_gemm(
    const float* __restrict__ h,
    const float* __restrict__ smean, const float* __restrict__ srstd,
    const float* __restrict__ lng, const float* __restrict__ lnb,
    const unsigned short* __restrict__ Wqt, const unsigned short* __restrict__ Wkt,
    const unsigned short* __restrict__ Wvt,
    const float* __restrict__ bq, const float* __restrict__ bk_, const float* __restrict__ bv_,
    unsigned short* __restrict__ q_bf, unsigned short* __restrict__ kf_bf,
    unsigned short* __restrict__ vnew, float* __restrict__ nck, float* __restrict__ ncv)
{
  __shared__ alignas(16) char As[4][64*64];
  __shared__ alignas(16) char Bs[4][128*64];
  int bx = (blockIdx.x & 7)*64 + (blockIdx.x >> 3);   // XCD-chunked swizzle (nwg=512)
  const int mt = bx >> 3, nt = bx & 7;
  const int m0 = mt*64, n0 = nt*128;
  const int tid = threadIdx.x, wave = tid>>6, lane = tid&63;

  const int ar = tid >> 2, au = tid & 3;
  const int ap = au ^ (ar&3) ^ ((ar>>2)&3);
  const float* arow = h + (size_t)(m0 + ar)*512;
  const float mean_r = smean[m0 + ar];
  const float rstd_r = srstd[m0 + ar];

  const int lr = lane>>2;
  const int swl = (lane&3) ^ ((lane>>2)&3) ^ (lane>>4);
  auto brow = [&](int rr) -> const unsigned short* {
    int n = n0 + rr;
    return n < 512 ? Wqt + (size_t)n*512
         : n < 768 ? Wkt + (size_t)(n-512)*512
                   : Wvt + (size_t)(n-768)*512;
  };
  auto stageB = [&](int slot, int k0){
    #pragma unroll
    for (int i = 0; i < 2; ++i) {
      const int chunk = wave*2 + i;
      gl_lds16(brow(chunk*16+lr) + k0 + swl*8, (char*)Bs[slot] + chunk*1024);
    }
  };

  float4 av[6];
  auto loadA = [&](int k0){
    av[0] = *(const float4*)(arow + k0 + au*8);
    av[1] = *(const float4*)(arow + k0 + au*8 + 4);
    av[2] = *(const float4*)(lng  + k0 + au*8);
    av[3] = *(const float4*)(lng  + k0 + au*8 + 4);
    av[4] = *(const float4*)(lnb  + k0 + au*8);
    av[5] = *(const float4*)(lnb  + k0 + au*8 + 4);
  };
  auto writeA = [&](int slot){
    const float* xv = (const float*)&av[0];
    const float* gv = (const float*)&av[2];
    const float* bv2 = (const float*)&av[4];
    unsigned w[4];
    #pragma unroll
    for (int j = 0; j < 4; ++j) {
      float e0 = (xv[2*j]   - mean_r)*rstd_r*gv[2*j]   + bv2[2*j];
      float e1 = (xv[2*j+1] - mean_r)*rstd_r*gv[2*j+1] + bv2[2*j+1];
      w[j] = (unsigned)f2b(e0) | ((unsigned)f2b(e1)<<16);
    }
    *(uint4*)((char*)As[slot] + ar*64 + ap*16) = make_uint4(w[0],w[1],w[2],w[3]);
  };

  loadA(0);  stageB(0, 0);  writeA(0);
  loadA(32); stageB(1, 32); writeA(1);
  __syncthreads();

  f32x4 acc[8] = {};
  const int wr = wave >> 1, wc = wave & 1;

  auto mfmaP = [&](int slot){
    bf16x8 af[2], bfv[4];
    #pragma unroll
    for (int r = 0; r < 2; ++r)
      af[r] = *(const bf16x8*)((char*)As[slot] + (wr*32 + r*16 + (lane&15))*64 + swl*16);
    #pragma unroll
    for (int c = 0; c < 4; ++c)
      bfv[c] = *(const bf16x8*)((char*)Bs[slot] + (wc*64 + c*16 + (lane&15))*64 + swl*16);
    #pragma unroll
    for (int r = 0; r < 2; ++r)
      #pragma unroll
      for (int c = 0; c < 4; ++c)
        acc[r*4+c] = __builtin_amdgcn_mfma_f32_16x16x32_bf16(af[r], bfv[c], acc[r*4+c], 0,0,0);
  };

  int cur = 0;
  for (int k0 = 0; k0 < 512; k0 += 64) {
    const bool more = (k0 + 64 < 512);
    if (more) { stageB((cur^1)*2, k0+64); loadA(k0+64); }
    mfmaP(cur*2);
    if (more) { writeA((cur^1)*2); stageB((cur^1)*2+1, k0+96); loadA(k0+96); }
    mfmaP(cur*2+1);
    if (more) writeA((cur^1)*2+1);
    __syncthreads();
    cur ^= 1;
  }

  #pragma unroll
  for (int r = 0; r < 2; ++r)
  #pragma unroll
  for (int c = 0; c < 4; ++c) {
    f32x4 v = acc[r*4+c];
    #pragma unroll
    for (int reg = 0; reg < 4; ++reg) {
      int m = m0 + wr*32 + r*16 + ((lane>>4)<<2) + reg;
      int n = n0 + wc*64 + c*16 + (lane&15);
      float val = v[reg];
      int b = m >> 8, s = m & 255;
      if (n < 512) {
        q_bf[(size_t)m*512 + n] = f2b(val + bq[n]);
      } else if (n < 768) {
        int g = (n-512) >> 6, hd = n & 63;
        float kv = val + bk_[n-512];
        kf_bf[((size_t)(b*4+g)*1024 + 768 + s)*64 + hd] = f2b(kv);
        nck [((size_t)(b*4+g)*768  + 512 + s)*64 + hd] = kv;
      } else {
        int g = (n-768) >> 6, hd = n & 63;
        float vv = val + bv_[n-768];
        vnew[(size_t)m*256 + (n-768)] = f2b(vv);     // coalesced (consecutive n)
        ncv [((size_t)(b*4+g)*768 + 512 + s)*64 + hd] = vv;
      }
    }
  }
}

// ================= fused cache merge + new-V transpose =================
__global__ __launch_bounds__(256) void merge_kv(
    const float* __restrict__ ck, const float* __restrict__ cv,
    const unsigned short* __restrict__ vnew,
    unsigned short* __restrict__ kf_bf, unsigned short* __restrict__ vt_bf,
    float* __restrict__ nck, float* __restrict__ ncv)
{
  __shared__ float t[64][65];
  const int bb = blockIdx.x;
  const int tid = threadIdx.x;
  if (bb < 3072) {
    size_t idx = (size_t)bb*256 + tid;
    int hd4 = idx & 15;
    size_t tt = (idx >> 4) % 768;
    size_t bg = idx / (16*768);
    const float4 v = ((const float4*)ck)[idx];
    uint2 pk;
    pk.x = (unsigned)f2b(v.x) | ((unsigned)f2b(v.y)<<16);
    pk.y = (unsigned)f2b(v.z) | ((unsigned)f2b(v.w)<<16);
    *(uint2*)&kf_bf[((bg*1024 + tt)*64) + hd4*4] = pk;
    if (tt >= 256)
      ((float4*)nck)[(bg*768 + (tt-256))*16 + hd4] = v;
  } else if (bb < 3840) {
    const int bi = bb - 3072;
    const int bg = bi / 12, tt = bi % 12;
    const int t0 = tt*64;
    #pragma unroll
    for (int i = 0; i < 4; ++i) {
      int tr = (tid>>4) + i*16;
      const float4 v = ((const float4*)cv)[((size_t)bg*768 + t0+tr)*16 + (tid&15)];
      t[tr][(tid&15)*4+0]=v.x; t[tr][(tid&15)*4+1]=v.y;
      t[tr][(tid&15)*4+2]=v.z; t[tr][(tid&15)*4+3]=v.w;
      if (t0+tr >= 256)
        ((float4*)ncv)[((size_t)bg*768 + t0+tr-256)*16 + (tid&15)] = v;
    }
    __syncthreads();
    const int hd = tid>>2, tc = (tid&3)*16;
    unsigned w[8];
    #pragma unroll
    for (int j = 0; j < 8; ++j)
      w[j] = (unsigned)f2b(t[tc+2*j][hd]) | ((unsigned)f2b(t[tc+2*j+1][hd])<<16);
    size_t off = ((size_t)bg*64 + hd)*1024 + t0 + tc;
    *(uint4*)&vt_bf[off]     = make_uint4(w[0],w[1],w[2],w[3]);
    *(uint4*)&vt_bf[off + 8] = make_uint4(w[4],w[5],w[6],w[7]);
  } else {
    const int bi = bb - 3840;            // 0..255
    const int bg = bi >> 2, tt4 = bi & 3;
    const int b = bg >> 2, g = bg & 3;
    const int t0 = 768 + tt4*64;
    unsigned short* ts = (unsigned short*)&t[0][0];   // reuse LDS, stride 68 shorts
    #pragma unroll
    for (int i = 0; i < 4; ++i) {
      int tr = (tid>>4) + i*16;          // token s = (t0-768) + tr
      uint2 v = *(const uint2*)&vnew[((size_t)(b*256 + (t0-768) + tr))*256 + g*64 + (tid&15)*4];
      const unsigned short* pv4 = (const unsigned short*)&v;
      ts[tr*68 + (tid&15)*4 + 0] = pv4[0];
      ts[tr*68 + (tid&15)*4 + 1] = pv4[1];
      ts[tr*68 + (tid&15)*4 + 2] = pv4[2];
      ts[tr*68 + (tid&15)*4 + 3] = pv4[3];
    }
    __syncthreads();
    const int hd = tid>>2, tc = (tid&3)*16;
    unsigned w[8];
    #pragma unroll
    for (int j = 0; j < 8; ++j)
      w[j] = (unsigned)ts[(tc+2*j)*68 + hd] | ((unsigned)ts[(tc+2*j+1)*68 + hd] << 16);
    size_t off = ((size_t)bg*64 + hd)*1024 + t0 + tc;
    *(uint4*)&vt_bf[off]     = make_uint4(w[0],w[1],w[2],w[3]);
    *(uint4*)&vt_bf[off + 8] = make_uint4(w[4],w[5],w[6],w[7]);
  }
}

// ======== fused flash attention, KVBLK=128, QBLK=128, exp2-domain softmax ========
// grid: b(16) * hh(8) * qt(2) = 256 blocks, 512 threads.
__global__ __launch_bounds__(512) void flash_attn(
    const unsigned short* __restrict__ q_bf,   // [B*256][512]
    const unsigned short* __restrict__ kf_bf,  // [bg][1024][64]
    const unsigned short* __restrict__ vt_bf,  // [bg][64hd][1024]
    const float* __restrict__ relt,            // [31][8]
    const float* __restrict__ relf,            // [127][8]
    unsigned short* __restrict__ att_bf)       // [B*256][512]
{
  int bx = (blockIdx.x & 7)*32 + (blockIdx.x >> 3);   // XCD-chunked swizzle (nwg=256)
  const int qt = bx & 1, hh = (bx>>1) & 7, b = bx >> 4;
  const int g = hh >> 1;
  const int tid = threadIdx.x, wave = tid>>6, lane = tid&63;
  const int lg = lane>>4, lq = lane&15;
  const int qloc = wave*16 + lq;         // 0..127
  const int q0 = qt*128;
  const int qtg = qt*2 + (wave>>2);      // query time tile in [0,4)

  __shared__ alignas(16) char Ks[2][16384];
  __shared__ alignas(16) char Vs[2][16384];

  const unsigned short* kfb  = kf_bf + (size_t)(b*4+g)*1024*64;
  const unsigned short* vtb2 = vt_bf + (size_t)(b*4+g)*64*1024;

  auto stage = [&](int buf, int t){
    #pragma unroll
    for (int it = 0; it < 2; ++it) {
      int slot = it*512 + tid;                 // 1024 slots each
      int kr = slot>>3, kp = slot&7,  ku = kp ^ (kr&7);
      gl_lds16(kfb + (size_t)(t*128 + kr)*64 + ku*8, Ks[buf] + slot*16);
      int vr = slot>>4, vp = slot&15, vu = vp ^ (vr&15);
      gl_lds16(vtb2 + (size_t)vr*1024 + t*128 + vu*8, Vs[buf] + slot*16);
    }
  };

  const unsigned short* qrow = q_bf + ((size_t)(b*256 + q0 + qloc))*512 + hh*64;
  bf16x8 qfrag[2];
  qfrag[0] = *(const bf16x8*)(qrow + lg*8);
  qfrag[1] = *(const bf16x8*)(qrow + 32 + lg*8);

  float bias_f[4][4];
  {
    int sq = qloc & 63;
    #pragma unroll
    for (int f = 0; f < 4; ++f)
      #pragma unroll
      for (int r = 0; r < 4; ++r)
        bias_f[f][r] = relf[((sq - (f*16 + lg*4 + r)) + 63)*8 + hh] * LOG2E;
  }
  const float scale2 = 0.125f * LOG2E;

  f32x4 ot[4] = {};
  float m_run = -1e30f, l_part = 0.f;

  stage(0, 0);
  __syncthreads();

  for (int t = 0; t < 8; ++t) {
    const int cur = t & 1;
    if (t + 1 < 8) stage(cur^1, t+1);

    f32x4 st[8] = {};
    __builtin_amdgcn_s_setprio(1);
    #pragma unroll
    for (int c = 0; c < 2; ++c)
      #pragma unroll
      for (int f = 0; f < 8; ++f) {
        int row = f*16 + lq;
        int pu = (c*4 + lg) ^ (row & 7);
        bf16x8 kf_ = *(const bf16x8*)(Ks[cur] + row*128 + pu*16);
        st[f] = __builtin_amdgcn_mfma_f32_16x16x32_bf16(kf_, qfrag[c], st[f], 0,0,0);
      }
    __builtin_amdgcn_s_setprio(0);

    const float bt0 = relt[(27 + qtg - 2*t)*8 + hh] * LOG2E;
    const float bt1 = relt[(27 + qtg - 2*t - 1)*8 + hh] * LOG2E;
    float mt = -1e30f;
    #pragma unroll
    for (int f = 0; f < 8; ++f) {
      const float bt = (f < 4) ? bt0 : bt1;
      #pragma unroll
      for (int r = 0; r < 4; ++r) {
        float v = st[f][r]*scale2 + bt + bias_f[f&3][r];
        st[f][r] = v;
        mt = fmaxf(mt, v);
      }
    }
    mt = fmaxf(mt, __shfl_xor(mt, 16, 64));
    mt = fmaxf(mt, __shfl_xor(mt, 32, 64));
    // T13 defer-max (log2 domain: 8*log2e)
    if (!__all(mt - m_run <= 11.5416f)) {
      const float m_new = fmaxf(m_run, mt);
      const float corr = exp2f(m_run - m_new);
      m_run = m_new;
      l_part *= corr;
      #pragma unroll
      for (int f = 0; f < 4; ++f) {
        ot[f][0] *= corr; ot[f][1] *= corr; ot[f][2] *= corr; ot[f][3] *= corr;
      }
    }
    float psum = 0.f;
    unsigned r01[8], r23[8];
    #pragma unroll
    for (int f = 0; f < 8; ++f) {
      float e0 = exp2f(st[f][0] - m_run);
      float e1 = exp2f(st[f][1] - m_run);
      float e2 = exp2f(st[f][2] - m_run);
      float e3 = exp2f(st[f][3] - m_run);
      psum += (e0+e1)+(e2+e3);
      r01[f] = (unsigned)f2b(e0) | ((unsigned)f2b(e1)<<16);
      r23[f] = (unsigned)f2b(e2) | ((unsigned)f2b(e3)<<16);
    }
    l_part += psum;

    const int src0 = (lg&1)*32 + lq;
    const int src1 = src0 + 16;
    const bool hi = (lg>>1) != 0;
    #pragma unroll
    for (int c = 0; c < 4; ++c) {
      unsigned a0 = (unsigned)__shfl((int)r01[c*2],   src0, 64);
      unsigned b0 = (unsigned)__shfl((int)r01[c*2+1], src0, 64);
      unsigned a1 = (unsigned)__shfl((int)r23[c*2],   src0, 64);
      unsigned b1 = (unsigned)__shfl((int)r23[c*2+1], src0, 64);
      unsigned a2 = (unsigned)__shfl((int)r01[c*2],   src1, 64);
      unsigned b2 = (unsigned)__shfl((int)r01[c*2+1], src1, 64);
      unsigned a3 = (unsigned)__shfl((int)r23[c*2],   src1, 64);
      unsigned b3 = (unsigned)__shfl((int)r23[c*2+1], src1, 64);
      uint4 bw;
      bw.x = hi ? b0 : a0;
      bw.y = hi ? b1 : a1;
      bw.z = hi ? b2 : a2;
      bw.w = hi ? b3 : a3;
      bf16x8 pfrag = *(bf16x8*)&bw;
      __builtin_amdgcn_s_setprio(1);
      #pragma unroll
      for (int f = 0; f < 4; ++f) {
        int row = f*16 + lq;
        int pu = (c*4 + lg) ^ (row & 15);
        bf16x8 vf_ = *(const bf16x8*)(Vs[cur] + row*256 + pu*16);
        ot[f] = __builtin_amdgcn_mfma_f32_16x16x32_bf16(vf_, pfrag, ot[f], 0,0,0);
      }
      __builtin_amdgcn_s_setprio(0);
    }
    __syncthreads();
  }

  float l_tot = l_part + __shfl_xor(l_part, 16, 64);
  l_tot += __shfl_xor(l_tot, 32, 64);
  const float inv = 1.0f / l_tot;
  unsigned short* orow = att_bf + ((size_t)(b*256 + q0 + qloc))*512 + hh*64;
  #pragma unroll
  for (int f = 0; f < 4; ++f) {
    uint2 w;
    w.x = (unsigned)f2b(ot[f][0]*inv) | ((unsigned)f2b(ot[f][1]*inv)<<16);
    w.y = (unsigned)f2b(ot[f][2]*inv) | ((unsigned)f2b(ot[f][3]*inv)<<16);
    *(uint2*)(orow + f*16 + lg*4) = w;
  }
}

// ================= FFN1: interleaved W1|W3 + SwiGLU =================
__global__ __launch_bounds__(256) void ffn1_gemm(
    const unsigned short* __restrict__ xin,
    const unsigned short* __restrict__ W1t, const unsigned short* __restrict__ W3t,
    const float* __restrict__ b1_, const float* __restrict__ b3_,
    unsigned short* __restrict__ ff_bf)
{
  __shared__ alignas(16) char As[2*128*64];
  __shared__ alignas(16) char Bs[2*128*64];
  f32x4 acc[16] = {};
  int bx = (blockIdx.x & 7)*128 + (blockIdx.x >> 3);  // XCD-chunked swizzle (nwg=1024)
  const int nt = bx & 31, mt = bx >> 5;
  const int m0 = mt*128, n0 = nt*128;
  auto brow = [&](int r) -> const unsigned short* {
    int p = n0 + r;
    int pb = p >> 4;
    int j = ((pb>>1)<<4) | (p & 15);
    return (pb & 1) ? W3t + (size_t)j*512 : W1t + (size_t)j*512;
  };
  mfma_core<128,128,64,64>(xin, 512, m0, brow, 512, As, Bs, acc);
  const int lane = threadIdx.x & 63, wave = threadIdx.x >> 6;
  const int wr = wave >> 1, wc = wave & 1;
  #pragma unroll
  for (int r = 0; r < 4; ++r)
  #pragma unroll
  for (int cp = 0; cp < 4; cp += 2) {
    f32x4 va = acc[r*4+cp];
    f32x4 vb = acc[r*4+cp+1];
    #pragma unroll
    for (int reg = 0; reg < 4; ++reg) {
      int m = m0 + wr*64 + r*16 + ((lane>>4)<<2) + reg;
      int p = n0 + wc*64 + cp*16 + (lane&15);
      int j = ((p>>5)<<4) | (p & 15);
      float a = va[reg] + b1_[j];
      float bb = vb[reg] + b3_[j];
      float gval = (a / (1.0f + __expf(-a))) * bb;
      ff_bf[(size_t)m*2048 + j] = f2b(gval);
    }
  }
}

// ====== residual GEMM (64x64 tile, BK=64: two 32-k panels per barrier) ==========
__global__ __launch_bounds__(256) void res_gemm(
    const unsigned short* __restrict__ A, int lda,
    const unsigned short* __restrict__ Wt, int kd,
    const float* __restrict__ bias, const float* __restrict__ resv,
    float* __restrict__ h)
{
  __shared__ alignas(16) char As[4][64*64];
  __shared__ alignas(16) char Bs[4][64*64];
  f32x4 acc[4] = {};
  int bx = (blockIdx.x & 7)*64 + (blockIdx.x >> 3);   // XCD-chunked swizzle (nwg=512)
  const int mt = bx >> 3, nt = bx & 7;
  const int m0 = mt*64, n0 = nt*64;
  const int tid = threadIdx.x, wave = tid>>6, lane = tid&63;
  const int wr = wave >> 1, wc = wave & 1;
  const int lr = lane>>2;
  const int swl = (lane&3) ^ ((lane>>2)&3) ^ (lane>>4);

  auto stageP = [&](int slot, int k0){
    gl_lds16(A  + (size_t)(m0 + wave*16 + lr)*lda + k0 + swl*8, As[slot] + wave*1024);
    gl_lds16(Wt + (size_t)(n0 + wave*16 + lr)*kd  + k0 + swl*8, Bs[slot] + wave*1024);
  };

  stageP(0, 0);
  stageP(1, 32);
  __syncthreads();
  int cur = 0;
  for (int k0 = 0; k0 < kd; k0 += 64) {
    if (k0 + 64 < kd) { stageP((cur^1)*2, k0+64); stageP((cur^1)*2+1, k0+96); }
    #pragma unroll
    for (int p = 0; p < 2; ++p) {
      const char* ab = As[cur*2+p];
      const char* bb = Bs[cur*2+p];
      bf16x8 af[2], bfv[2];
      #pragma unroll
      for (int r = 0; r < 2; ++r)
        af[r] = *(const bf16x8*)(ab + (wr*32 + r*16 + (lane&15))*64 + swl*16);
      #pragma unroll
      for (int c = 0; c < 2; ++c)
        bfv[c] = *(const bf16x8*)(bb + (wc*32 + c*16 + (lane&15))*64 + swl*16);
      #pragma unroll
      for (int r = 0; r < 2; ++r)
        #pragma unroll
        for (int c = 0; c < 2; ++c)
          acc[r*2+c] = __builtin_amdgcn_mfma_f32_16x16x32_bf16(af[r], bfv[c], acc[r*2+c], 0,0,0);
    }
    __syncthreads();
    cur ^= 1;
  }

  const float rv = resv[0];
  #pragma unroll
  for (int r = 0; r < 2; ++r)
  #pragma unroll
  for (int c = 0; c < 2; ++c) {
    f32x4 v = acc[r*2+c];
    #pragma unroll
    for (int reg = 0; reg < 4; ++reg) {
      int m = m0 + wr*32 + r*16 + ((lane>>4)<<2) + reg;
      int n = n0 + wc*32 + c*16 + (lane&15);
      h[(size_t)m*512 + n] += rv * (v[reg] + bias[n]);
    }
  }
}

// ===== output projection + unpatchify: 8 tokens/block, outW staged in LDS =====
__global__ __launch_bounds__(256) void outproj_kernel(
    const float* __restrict__ h, const float* __restrict__ outW,
    const float* __restrict__ outb, float* __restrict__ y)
{
  __shared__ float wlds[512*32];   // 64 KB
  __shared__ float hr[8][520];     // padded rows (2-way bank alias only)
  const int tid = threadIdx.x;
  const int tb = blockIdx.x*8;

  #pragma unroll
  for (int i = 0; i < 16; ++i)
    ((float4*)wlds)[i*256 + tid] = ((const float4*)outW)[i*256 + tid];
  {
    const int tok = tid >> 5, idx = tid & 31;
    const float* hrow = h + (size_t)(tb + tok)*512;
    #pragma unroll
    for (int i = 0; i < 4; ++i) {
      float4 v = ((const float4*)hrow)[idx + i*32];
      int e = (idx + i*32)*4;
      hr[tok][e+0] = v.x; hr[tok][e+1] = v.y; hr[tok][e+2] = v.z; hr[tok][e+3] = v.w;
    }
  }
  __syncthreads();

  const int tok = tid >> 5, i = tid & 31;
  float acc = outb[i];
  #pragma unroll 8
  for (int k = 0; k < 512; ++k) acc += hr[tok][k] * wlds[k*32 + i];

  const int bs = tb + tok;
  const int b = bs >> 8, s = bs & 255;
  const int tic = s >> 6, mf = s & 63;
  const int tp = i >> 3, fp = (i >> 1) & 3, c = i & 1;
  y[((size_t)(b*2 + c)*16 + tic*4 + tp)*256 + mf*4 + fp] = acc;
}

// ================= launch =================
extern "C" void kernel_launch(void* const* d_in, const int* in_sizes, int n_in,
                              void* d_out, int out_size, void* d_ws, size_t ws_size,
                              hipStream_t stream) {
  (void)in_sizes; (void)n_in; (void)out_size; (void)ws_size;
  const float* x        = (const float*)d_in[0];
  const float* cache_k  = (const float*)d_in[1];
  const float* cache_v  = (const float*)d_in[2];
  const float* in_W     = (const float*)d_in[3];
  const float* in_b     = (const float*)d_in[4];
  const float* ln1_g    = (const float*)d_in[5];
  const float* ln1_b    = (const float*)d_in[6];
  const float* Wq       = (const float*)d_in[7];
  const float* bq       = (const float*)d_in[8];
  const float* Wk       = (const float*)d_in[9];
  const float* bk       = (const float*)d_in[10];
  const float* Wv       = (const float*)d_in[11];
  const float* bv       = (const float*)d_in[12];
  const float* Wo       = (const float*)d_in[13];
  const float* bo       = (const float*)d_in[14];
  const float* rel_time = (const float*)d_in[15];
  const float* rel_freq = (const float*)d_in[16];
  const float* res_a    = (const float*)d_in[17];
  const float* ln2_g    = (const float*)d_in[18];
  const float* ln2_b    = (const float*)d_in[19];
  const float* W1       = (const float*)d_in[20];
  const float* b1       = (const float*)d_in[21];
  const float* W3       = (const float*)d_in[22];
  const float* b3       = (const float*)d_in[23];
  const float* W2       = (const float*)d_in[24];
  const float* b2       = (const float*)d_in[25];
  const float* res_f    = (const float*)d_in[26];
  const float* out_W    = (const float*)d_in[27];
  const float* out_b    = (const float*)d_in[28];

  char* ws = (char*)d_ws;
  size_t o = 0;
  float* h            = (float*)(ws + o);          o += (size_t)4096*512*4;
  unsigned short* xin = (unsigned short*)(ws + o); o += (size_t)4096*512*2;
  unsigned short* qb  = (unsigned short*)(ws + o); o += (size_t)4096*512*2;
  unsigned short* att = (unsigned short*)(ws + o); o += (size_t)4096*512*2;
  unsigned short* kfb = (unsigned short*)(ws + o); o += (size_t)64*1024*64*2;
  unsigned short* vtb = (unsigned short*)(ws + o); o += (size_t)64*64*1024*2;
  unsigned short* vnw = (unsigned short*)(ws + o); o += (size_t)4096*256*2;
  float* smean        = (float*)(ws + o);          o += (size_t)4096*4;
  float* srstd        = (float*)(ws + o);          o += (size_t)4096*4;
  unsigned short* Wqt = (unsigned short*)(ws + o); o += (size_t)4*512*512*2;
  unsigned short* Wkt = (unsigned short*)(ws + o); o += (size_t)4*256*512*2;
  unsigned short* Wvt = (unsigned short*)(ws + o); o += (size_t)4*256*512*2;
  unsigned short* Wot = (unsigned short*)(ws + o); o += (size_t)4*512*512*2;
  unsigned short* W1t = (unsigned short*)(ws + o); o += (size_t)4*2048*512*2;
  unsigned short* W3t = (unsigned short*)(ws + o); o += (size_t)4*2048*512*2;
  unsigned short* W2t = (unsigned short*)(ws + o); o += (size_t)4*512*2048*2;
  unsigned short* ffb = (unsigned short*)(ws + o);

  float* y    = (float*)d_out;
  float* nck0 = y + 131072;
  float* ncv0 = nck0 + 12582912;

  transpose_all<<<3840, 256, 0, stream>>>(Wq, Wk, Wv, Wo, W1, W3, W2,
                                          Wqt, Wkt, Wvt, Wot, W1t, W3t, W2t);

  patchify_inproj<<<256, 256, 0, stream>>>(x, in_W, in_b, h);

  for (int l = 0; l < L_; ++l) {
    ln_stats<<<256, 256, 0, stream>>>(h, smean, srstd);
    qkv_ln_gemm<<<512, 256, 0, stream>>>(
        h, smean, srstd, ln1_g + l*512, ln1_b + l*512,
        Wqt + (size_t)l*512*512, Wkt + (size_t)l*256*512, Wvt + (size_t)l*256*512,
        bq + l*512, bk + l*256, bv + l*256,
        qb, kfb, vnw, nck0 + (size_t)l*3145728, ncv0 + (size_t)l*3145728);
    merge_kv<<<4096, 256, 0, stream>>>(
        cache_k + (size_t)l*3145728, cache_v + (size_t)l*3145728, vnw,
        kfb, vtb, nck0 + (size_t)l*3145728, ncv0 + (size_t)l*3145728);
    flash_attn<<<256, 512, 0, stream>>>(qb, kfb, vtb,
        rel_time + l*31*8, rel_freq + l*127*8, att);
    res_gemm<<<512, 256, 0, stream>>>(att, 512, Wot + (size_t)l*512*512, 512,
                                      bo + l*512, res_a + l, h);
    ln_kernel<<<256, 256, 0, stream>>>(h, xin, ln2_g + l*512, ln2_b + l*512);
    ffn1_gemm<<<1024, 256, 0, stream>>>(
        xin, W1t + (size_t)l*2048*512, W3t + (size_t)l*2048*512,
        b1 + l*2048, b3 + l*2048, ffb);
    res_gemm<<<512, 256, 0, stream>>>(ffb, 2048, W2t + (size_t)l*512*2048, 2048,
                                      b2 + l*512, res_f + l, h);
  }

  outproj_kernel<<<512, 256, 0, stream>>>(h, out_W, out_b, y);
}

// Round 17
// 605.941 us; speedup vs baseline: 1.0059x; 1.0059x over previous
//
#include <hip/hip_runtime.h>
#include <stdint.h>

typedef __attribute__((ext_vector_type(8))) short bf16x8;
typedef __attribute__((ext_vector_type(4))) float f32x4;

// ---- problem dims ----
#define B_    16
#define S_    256
#define LEFT_ 768
#define KT_   1024
#define D_    512
#define H_    8
#define G_    4
#define HD_   64
#define L_    4
#define FFH_  2048
#define M_    4096   // B*S
#define LOG2E 1.44269504f

__device__ __forceinline__ unsigned short f2b(float f){
  unsigned u = __float_as_uint(f);
  u += 0x7fffu + ((u>>16)&1u);
  return (unsigned short)(u>>16);
}

__device__ __forceinline__ void gl_lds16(const unsigned short* g, void* l){
  __builtin_amdgcn_global_load_lds(
    (const __attribute__((address_space(1))) unsigned int*)g,
    (__attribute__((address_space(3))) unsigned int*)l, 16, 0, 0);
}

// ================= MFMA GEMM core (NT layout), double-buffered, BK=32 ============
template<int BM, int BN, int WM, int WN, class BRowF>
__device__ __forceinline__ void mfma_core(
    const unsigned short* Abase, int lda, int m0, BRowF brow,
    int kd, char* As, char* Bs, f32x4* acc)
{
  constexpr int FR = WM/16, FC = WN/16;
  constexpr int NWC = BN/WN;
  constexpr int CA = BM/64, CB = BN/64;
  const int tid = threadIdx.x, wave = tid>>6, lane = tid&63;
  const int wr = wave / NWC, wc = wave % NWC;
  const int lr = lane>>2;
  const int swl = (lane&3) ^ ((lane>>2)&3) ^ (lane>>4);

  auto stage = [&](int buf, int k0){
    #pragma unroll
    for (int i = 0; i < CA; ++i) {
      const int chunk = wave*CA + i;
      const unsigned short* gp = Abase + (size_t)(m0 + chunk*16 + lr)*lda + k0 + swl*8;
      gl_lds16(gp, As + buf*(BM*64) + chunk*1024);
    }
    #pragma unroll
    for (int i = 0; i < CB; ++i) {
      const int chunk = wave*CB + i;
      const unsigned short* gp = brow(chunk*16 + lr) + k0 + swl*8;
      gl_lds16(gp, Bs + buf*(BN*64) + chunk*1024);
    }
  };

  stage(0, 0);
  __syncthreads();
  int cur = 0;
  for (int k0 = 0; k0 < kd; k0 += 32) {
    if (k0 + 32 < kd) stage(cur^1, k0 + 32);
    bf16x8 af[FR], bfr[FC];
    #pragma unroll
    for (int r = 0; r < FR; ++r)
      af[r] = *(const bf16x8*)(As + cur*(BM*64) + (wr*WM + r*16 + (lane&15))*64 + swl*16);
    #pragma unroll
    for (int c = 0; c < FC; ++c)
      bfr[c] = *(const bf16x8*)(Bs + cur*(BN*64) + (wc*WN + c*16 + (lane&15))*64 + swl*16);
    #pragma unroll
    for (int r = 0; r < FR; ++r)
      #pragma unroll
      for (int c = 0; c < FC; ++c)
        acc[r*FC+c] = __builtin_amdgcn_mfma_f32_16x16x32_bf16(af[r], bfr[c], acc[r*FC+c], 0, 0, 0);
    __syncthreads();
    cur ^= 1;
  }
}

// ================= unified weight transpose+convert =================
__device__ __forceinline__ void tcvt_body(
    const float* __restrict__ src, unsigned short* __restrict__ dst,
    int K, int N, int ntk, int ntn, int bx)
{
  __shared__ float t[64][65];
  int kt = bx % ntk; int nt = (bx/ntk) % ntn; int l = bx/(ntk*ntn);
  src += (size_t)l*K*N; dst += (size_t)l*N*K;
  const int k0 = kt*64, n0 = nt*64;
  const int tid = threadIdx.x;
  #pragma unroll
  for (int i = 0; i < 4; ++i) {
    int kr = (tid>>4) + i*16;
    const float4 v = *(const float4*)&src[(size_t)(k0+kr)*N + n0 + (tid&15)*4];
    t[kr][(tid&15)*4+0]=v.x; t[kr][(tid&15)*4+1]=v.y;
    t[kr][(tid&15)*4+2]=v.z; t[kr][(tid&15)*4+3]=v.w;
  }
  __syncthreads();
  const int nn = tid>>2, kk = (tid&3)*16;
  unsigned w[8];
  #pragma unroll
  for (int j = 0; j < 8; ++j)
    w[j] = (unsigned)f2b(t[kk+2*j][nn]) | ((unsigned)f2b(t[kk+2*j+1][nn])<<16);
  size_t off = (size_t)(n0+nn)*K + k0 + kk;
  *(uint4*)&dst[off]     = make_uint4(w[0],w[1],w[2],w[3]);
  *(uint4*)&dst[off + 8] = make_uint4(w[4],w[5],w[6],w[7]);
}

__global__ __launch_bounds__(256) void transpose_all(
    const float* __restrict__ Wq, const float* __restrict__ Wk,
    const float* __restrict__ Wv, const float* __restrict__ Wo,
    const float* __restrict__ W1, const float* __restrict__ W3,
    const float* __restrict__ W2,
    unsigned short* __restrict__ Wqt, unsigned short* __restrict__ Wkt,
    unsigned short* __restrict__ Wvt, unsigned short* __restrict__ Wot,
    unsigned short* __restrict__ W1t, unsigned short* __restrict__ W3t,
    unsigned short* __restrict__ W2t)
{
  int bx = blockIdx.x;
  if      (bx < 256)  tcvt_body(Wq, Wqt, 512, 512, 8, 8,  bx);
  else if (bx < 384)  tcvt_body(Wk, Wkt, 512, 256, 8, 4,  bx-256);
  else if (bx < 512)  tcvt_body(Wv, Wvt, 512, 256, 8, 4,  bx-384);
  else if (bx < 768)  tcvt_body(Wo, Wot, 512, 512, 8, 8,  bx-512);
  else if (bx < 1792) tcvt_body(W1, W1t, 512, 2048, 8, 32, bx-768);
  else if (bx < 2816) tcvt_body(W3, W3t, 512, 2048, 8, 32, bx-1792);
  else                tcvt_body(W2, W2t, 2048, 512, 32, 8, bx-2816);
}

// ======= patchify + input projection: 16 tokens/block, inW staged in LDS =======
__global__ __launch_bounds__(256) void patchify_inproj(
    const float* __restrict__ x, const float* __restrict__ inW,
    const float* __restrict__ inb, float* __restrict__ h)
{
  __shared__ float wlds[32*512];
  __shared__ float ps[16][33];
  const int tid = threadIdx.x;
  const int tb = blockIdx.x*16;

  #pragma unroll
  for (int i = 0; i < 16; ++i)
    ((float4*)wlds)[i*256 + tid] = ((const float4*)inW)[i*256 + tid];
  {
    int tok = tid >> 5, idx = tid & 31;
    int bs = tb + tok;
    int b = bs >> 8, s = bs & 255;
    int tic = s >> 6, mf = s & 63;
    int tp = idx >> 3, fp = (idx >> 1) & 3, c = idx & 1;
    ps[tok][idx] = x[((size_t)(b*2 + c)*16 + tic*4 + tp)*256 + mf*4 + fp];
    int tok2 = tok + 8;
    int bs2 = tb + tok2;
    int b2 = bs2 >> 8, s2 = bs2 & 255;
    int tic2 = s2 >> 6, mf2 = s2 & 63;
    ps[tok2][idx] = x[((size_t)(b2*2 + c)*16 + tic2*4 + tp)*256 + mf2*4 + fp];
  }
  __syncthreads();

  const int g = tid >> 4, qd = tid & 15;
  const int bs = tb + g;
  for (int j = 0; j < 32; ++j) {
    int d = j*16 + qd;
    float acc = inb[d];
    #pragma unroll
    for (int i = 0; i < 32; ++i) acc += ps[g][i] * wlds[i*512 + d];
    h[(size_t)bs*512 + d] = acc;
  }
}

// ================= LN1 row stats (one pass over h) =================
__global__ __launch_bounds__(256) void ln_stats(
    const float* __restrict__ h, float* __restrict__ smean, float* __restrict__ srstd)
{
  const int tid = threadIdx.x;
  const int row = blockIdx.x*16 + (tid>>4);
  const int qd = tid & 15;
  const float* rp = h + (size_t)row*512 + qd*32;
  float s = 0.f, sq = 0.f;
  #pragma unroll
  for (int i = 0; i < 8; ++i) {
    float4 v = ((const float4*)rp)[i];
    s  += (v.x+v.y)+(v.z+v.w);
    sq += (v.x*v.x+v.y*v.y)+(v.z*v.z+v.w*v.w);
  }
  #pragma unroll
  for (int o = 1; o < 16; o <<= 1) { s += __shfl_xor(s,o,64); sq += __shfl_xor(sq,o,64); }
  if (qd == 0) {
    float mean = s*(1.f/512.f);
    smean[row] = mean;
    srstd[row] = rsqrtf(sq*(1.f/512.f) - mean*mean + 1e-5f);
  }
}

// ================= lean layernorm f32 -> bf16 (ln2): 16 rows/block =============
__global__ __launch_bounds__(256) void ln_kernel(
    const float* __restrict__ in, unsigned short* __restrict__ out,
    const float* __restrict__ g, const float* __restrict__ bta)
{
  const int tid = threadIdx.x;
  const int row = blockIdx.x*16 + (tid>>4);
  const int qd = tid & 15;
  const float* rp = in + (size_t)row*512 + qd*32;
  float4 xv[8];
  float s = 0.f, sq = 0.f;
  #pragma unroll
  for (int i = 0; i < 8; ++i) {
    xv[i] = ((const float4*)rp)[i];
    s  += (xv[i].x+xv[i].y)+(xv[i].z+xv[i].w);
    sq += (xv[i].x*xv[i].x + xv[i].y*xv[i].y)+(xv[i].z*xv[i].z + xv[i].w*xv[i].w);
  }
  #pragma unroll
  for (int o = 1; o < 16; o <<= 1) { s += __shfl_xor(s,o,64); sq += __shfl_xor(sq,o,64); }
  const float mean = s*(1.f/512.f);
  const float rstd = rsqrtf(sq*(1.f/512.f) - mean*mean + 1e-5f);
  const float* gp = g + qd*32;
  const float* bp = bta + qd*32;
  unsigned short* op = out + (size_t)row*512 + qd*32;
  #pragma unroll
  for (int i = 0; i < 4; ++i) {
    float4 a  = xv[2*i],                 b2 = xv[2*i+1];
    float4 ga = ((const float4*)gp)[2*i], gb = ((const float4*)gp)[2*i+1];
    float4 ba = ((const float4*)bp)[2*i], bb = ((const float4*)bp)[2*i+1];
    unsigned w0 = (unsigned)f2b((a.x-mean)*rstd*ga.x + ba.x) | ((unsigned)f2b((a.y-mean)*rstd*ga.y + ba.y)<<16);
    unsigned w1 = (unsigned)f2b((a.z-mean)*rstd*ga.z + ba.z) | ((unsigned)f2b((a.w-mean)*rstd*ga.w + ba.w)<<16);
    unsigned w2 = (unsigned)f2b((b2.x-mean)*rstd*gb.x + bb.x) | ((unsigned)f2b((b2.y-mean)*rstd*gb.y + bb.y)<<16);
    unsigned w3 = (unsigned)f2b((b2.z-mean)*rstd*gb.z + bb.z) | ((unsigned)f2b((b2.w-mean)*rstd*gb.w + bb.w)<<16);
    *(uint4*)(op + i*8) = make_uint4(w0,w1,w2,w3);
  }
}

// ================= QKV GEMM with fused LN1 (stats precomputed) ==============
__global__ __launch_bounds__(256) void qkv_ln_gemm(
    const float* __restrict__ h,
    const float* __restrict__ smean, const float* __restrict__ srstd,
    const float* __restrict__ lng, const float* __restrict__ lnb,
    const unsigned short* __restrict__ Wqt, const unsigned short* __restrict__ Wkt,
    const unsigned short* __restrict__ Wvt,
    const float* __restrict__ bq, const float* __restrict__ bk_, const float* __restrict__ bv_,
    unsigned short* __restrict__ q_bf, unsigned short* __restrict__ kf_bf,
    unsigned short* __restrict__ vnew, float* __restrict__ nck, float* __restrict__ ncv)
{
  __shared__ alignas(16) char As[2][64*64];
  __shared__ alignas(16) char Bs[2][128*64];
  int bx = (blockIdx.x & 7)*64 + (blockIdx.x >> 3);   // XCD-chunked swizzle (nwg=512)
  const int mt = bx >> 3, nt = bx & 7;
  const int m0 = mt*64, n0 = nt*128;
  const int tid = threadIdx.x, wave = tid>>6, lane = tid&63;

  const int ar = tid >> 2, au = tid & 3;
  const int ap = au ^ (ar&3) ^ ((ar>>2)&3);
  const float* arow = h + (size_t)(m0 + ar)*512;
  const float mean_r = smean[m0 + ar];
  const float rstd_r = srstd[m0 + ar];

  const int lr = lane>>2;
  const int swl = (lane&3) ^ ((lane>>2)&3) ^ (lane>>4);
  auto brow = [&](int rr) -> const unsigned short* {
    int n = n0 + rr;
    return n < 512 ? Wqt + (size_t)n*512
         : n < 768 ? Wkt + (size_t)(n-512)*512
                   : Wvt + (size_t)(n-768)*512;
  };
  auto stageB = [&](int buf, int k0){
    #pragma unroll
    for (int i = 0; i < 2; ++i) {
      const int chunk = wave*2 + i;
      gl_lds16(brow(chunk*16+lr) + k0 + swl*8, (char*)Bs[buf] + chunk*1024);
    }
  };

  float4 av[6];
  auto loadA = [&](int k0){
    av[0] = *(const float4*)(arow + k0 + au*8);
    av[1] = *(const float4*)(arow + k0 + au*8 + 4);
    av[2] = *(const float4*)(lng  + k0 + au*8);
    av[3] = *(const float4*)(lng  + k0 + au*8 + 4);
    av[4] = *(const float4*)(lnb  + k0 + au*8);
    av[5] = *(const float4*)(lnb  + k0 + au*8 + 4);
  };
  auto writeA = [&](int buf){
    const float* xv = (const float*)&av[0];
    const float* gv = (const float*)&av[2];
    const float* bv2 = (const float*)&av[4];
    unsigned w[4];
    #pragma unroll
    for (int j = 0; j < 4; ++j) {
      float e0 = (xv[2*j]   - mean_r)*rstd_r*gv[2*j]   + bv2[2*j];
      float e1 = (xv[2*j+1] - mean_r)*rstd_r*gv[2*j+1] + bv2[2*j+1];
      w[j] = (unsigned)f2b(e0) | ((unsigned)f2b(e1)<<16);
    }
    *(uint4*)((char*)As[buf] + ar*64 + ap*16) = make_uint4(w[0],w[1],w[2],w[3]);
  };

  loadA(0);
  stageB(0, 0);
  writeA(0);
  __syncthreads();

  f32x4 acc[8] = {};
  const int wr = wave >> 1, wc = wave & 1;
  for (int k0 = 0; k0 < 512; k0 += 32) {
    const int cur = (k0>>5)&1;
    const bool more = (k0 + 32 < 512);
    if (more) { stageB(cur^1, k0+32); loadA(k0+32); }
    bf16x8 af[2], bfv[4];
    #pragma unroll
    for (int r = 0; r < 2; ++r)
      af[r] = *(const bf16x8*)((char*)As[cur] + (wr*32 + r*16 + (lane&15))*64 + swl*16);
    #pragma unroll
    for (int c = 0; c < 4; ++c)
      bfv[c] = *(const bf16x8*)((char*)Bs[cur] + (wc*64 + c*16 + (lane&15))*64 + swl*16);
    #pragma unroll
    for (int r = 0; r < 2; ++r)
      #pragma unroll
      for (int c = 0; c < 4; ++c)
        acc[r*4+c] = __builtin_amdgcn_mfma_f32_16x16x32_bf16(af[r], bfv[c], acc[r*4+c], 0,0,0);
    if (more) writeA(cur^1);
    __syncthreads();
  }

  #pragma unroll
  for (int r = 0; r < 2; ++r)
  #pragma unroll
  for (int c = 0; c < 4; ++c) {
    f32x4 v = acc[r*4+c];
    #pragma unroll
    for (int reg = 0; reg < 4; ++reg) {
      int m = m0 + wr*32 + r*16 + ((lane>>4)<<2) + reg;
      int n = n0 + wc*64 + c*16 + (lane&15);
      float val = v[reg];
      int b = m >> 8, s = m & 255;
      if (n < 512) {
        q_bf[(size_t)m*512 + n] = f2b(val + bq[n]);
      } else if (n < 768) {
        int g = (n-512) >> 6, hd = n & 63;
        float kv = val + bk_[n-512];
        kf_bf[((size_t)(b*4+g)*1024 + 768 + s)*64 + hd] = f2b(kv);
        nck [((size_t)(b*4+g)*768  + 512 + s)*64 + hd] = kv;
      } else {
        int g = (n-768) >> 6, hd = n & 63;
        float vv = val + bv_[n-768];
        vnew[(size_t)m*256 + (n-768)] = f2b(vv);     // coalesced (consecutive n)
        ncv [((size_t)(b*4+g)*768 + 512 + s)*64 + hd] = vv;
      }
    }
  }
}

// ================= fused cache merge + new-V transpose =================
__global__ __launch_bounds__(256) void merge_kv(
    const float* __restrict__ ck, const float* __restrict__ cv,
    const unsigned short* __restrict__ vnew,
    unsigned short* __restrict__ kf_bf, unsigned short* __restrict__ vt_bf,
    float* __restrict__ nck, float* __restrict__ ncv)
{
  __shared__ float t[64][65];
  const int bb = blockIdx.x;
  const int tid = threadIdx.x;
  if (bb < 3072) {
    size_t idx = (size_t)bb*256 + tid;
    int hd4 = idx & 15;
    size_t tt = (idx >> 4) % 768;
    size_t bg = idx / (16*768);
    const float4 v = ((const float4*)ck)[idx];
    uint2 pk;
    pk.x = (unsigned)f2b(v.x) | ((unsigned)f2b(v.y)<<16);
    pk.y = (unsigned)f2b(v.z) | ((unsigned)f2b(v.w)<<16);
    *(uint2*)&kf_bf[((bg*1024 + tt)*64) + hd4*4] = pk;
    if (tt >= 256)
      ((float4*)nck)[(bg*768 + (tt-256))*16 + hd4] = v;
  } else if (bb < 3840) {
    const int bi = bb - 3072;
    const int bg = bi / 12, tt = bi % 12;
    const int t0 = tt*64;
    #pragma unroll
    for (int i = 0; i < 4; ++i) {
      int tr = (tid>>4) + i*16;
      const float4 v = ((const float4*)cv)[((size_t)bg*768 + t0+tr)*16 + (tid&15)];
      t[tr][(tid&15)*4+0]=v.x; t[tr][(tid&15)*4+1]=v.y;
      t[tr][(tid&15)*4+2]=v.z; t[tr][(tid&15)*4+3]=v.w;
      if (t0+tr >= 256)
        ((float4*)ncv)[((size_t)bg*768 + t0+tr-256)*16 + (tid&15)] = v;
    }
    __syncthreads();
    const int hd = tid>>2, tc = (tid&3)*16;
    unsigned w[8];
    #pragma unroll
    for (int j = 0; j < 8; ++j)
      w[j] = (unsigned)f2b(t[tc+2*j][hd]) | ((unsigned)f2b(t[tc+2*j+1][hd])<<16);
    size_t off = ((size_t)bg*64 + hd)*1024 + t0 + tc;
    *(uint4*)&vt_bf[off]     = make_uint4(w[0],w[1],w[2],w[3]);
    *(uint4*)&vt_bf[off + 8] = make_uint4(w[4],w[5],w[6],w[7]);
  } else {
    const int bi = bb - 3840;            // 0..255
    const int bg = bi >> 2, tt4 = bi & 3;
    const int b = bg >> 2, g = bg & 3;
    const int t0 = 768 + tt4*64;
    unsigned short* ts = (unsigned short*)&t[0][0];   // reuse LDS, stride 68 shorts
    #pragma unroll
    for (int i = 0; i < 4; ++i) {
      int tr = (tid>>4) + i*16;          // token s = (t0-768) + tr
      uint2 v = *(const uint2*)&vnew[((size_t)(b*256 + (t0-768) + tr))*256 + g*64 + (tid&15)*4];
      const unsigned short* pv4 = (const unsigned short*)&v;
      ts[tr*68 + (tid&15)*4 + 0] = pv4[0];
      ts[tr*68 + (tid&15)*4 + 1] = pv4[1];
      ts[tr*68 + (tid&15)*4 + 2] = pv4[2];
      ts[tr*68 + (tid&15)*4 + 3] = pv4[3];
    }
    __syncthreads();
    const int hd = tid>>2, tc = (tid&3)*16;
    unsigned w[8];
    #pragma unroll
    for (int j = 0; j < 8; ++j)
      w[j] = (unsigned)ts[(tc+2*j)*68 + hd] | ((unsigned)ts[(tc+2*j+1)*68 + hd] << 16);
    size_t off = ((size_t)bg*64 + hd)*1024 + t0 + tc;
    *(uint4*)&vt_bf[off]     = make_uint4(w[0],w[1],w[2],w[3]);
    *(uint4*)&vt_bf[off + 8] = make_uint4(w[4],w[5],w[6],w[7]);
  }
}

// ======== fused flash attention, KVBLK=128, QBLK=128, exp2-domain softmax ========
// grid: b(16) * hh(8) * qt(2) = 256 blocks, 512 threads.
__global__ __launch_bounds__(512) void flash_attn(
    const unsigned short* __restrict__ q_bf,   // [B*256][512]
    const unsigned short* __restrict__ kf_bf,  // [bg][1024][64]
    const unsigned short* __restrict__ vt_bf,  // [bg][64hd][1024]
    const float* __restrict__ relt,            // [31][8]
    const float* __restrict__ relf,            // [127][8]
    unsigned short* __restrict__ att_bf)       // [B*256][512]
{
  int bx = (blockIdx.x & 7)*32 + (blockIdx.x >> 3);   // XCD-chunked swizzle (nwg=256)
  const int qt = bx & 1, hh = (bx>>1) & 7, b = bx >> 4;
  const int g = hh >> 1;
  const int tid = threadIdx.x, wave = tid>>6, lane = tid&63;
  const int lg = lane>>4, lq = lane&15;
  const int qloc = wave*16 + lq;         // 0..127
  const int q0 = qt*128;
  const int qtg = qt*2 + (wave>>2);      // query time tile in [0,4)

  __shared__ alignas(16) char Ks[2][16384];
  __shared__ alignas(16) char Vs[2][16384];

  const unsigned short* kfb  = kf_bf + (size_t)(b*4+g)*1024*64;
  const unsigned short* vtb2 = vt_bf + (size_t)(b*4+g)*64*1024;

  auto stage = [&](int buf, int t){
    #pragma unroll
    for (int it = 0; it < 2; ++it) {
      int slot = it*512 + tid;                 // 1024 slots each
      int kr = slot>>3, kp = slot&7,  ku = kp ^ (kr&7);
      gl_lds16(kfb + (size_t)(t*128 + kr)*64 + ku*8, Ks[buf] + slot*16);
      int vr = slot>>4, vp = slot&15, vu = vp ^ (vr&15);
      gl_lds16(vtb2 + (size_t)vr*1024 + t*128 + vu*8, Vs[buf] + slot*16);
    }
  };

  const unsigned short* qrow = q_bf + ((size_t)(b*256 + q0 + qloc))*512 + hh*64;
  bf16x8 qfrag[2];
  qfrag[0] = *(const bf16x8*)(qrow + lg*8);
  qfrag[1] = *(const bf16x8*)(qrow + 32 + lg*8);

  float bias_f[4][4];
  {
    int sq = qloc & 63;
    #pragma unroll
    for (int f = 0; f < 4; ++f)
      #pragma unroll
      for (int r = 0; r < 4; ++r)
        bias_f[f][r] = relf[((sq - (f*16 + lg*4 + r)) + 63)*8 + hh] * LOG2E;
  }
  const float scale2 = 0.125f * LOG2E;

  f32x4 ot[4] = {};
  float m_run = -1e30f, l_part = 0.f;

  stage(0, 0);
  __syncthreads();

  for (int t = 0; t < 8; ++t) {
    const int cur = t & 1;
    if (t + 1 < 8) stage(cur^1, t+1);

    f32x4 st[8] = {};
    __builtin_amdgcn_s_setprio(1);
    #pragma unroll
    for (int c = 0; c < 2; ++c)
      #pragma unroll
      for (int f = 0; f < 8; ++f) {
        int row = f*16 + lq;
        int pu = (c*4 + lg) ^ (row & 7);
        bf16x8 kf_ = *(const bf16x8*)(Ks[cur] + row*128 + pu*16);
        st[f] = __builtin_amdgcn_mfma_f32_16x16x32_bf16(kf_, qfrag[c], st[f], 0,0,0);
      }
    __builtin_amdgcn_s_setprio(0);

    const float bt0 = relt[(27 + qtg - 2*t)*8 + hh] * LOG2E;
    const float bt1 = relt[(27 + qtg - 2*t - 1)*8 + hh] * LOG2E;
    float mt = -1e30f;
    #pragma unroll
    for (int f = 0; f < 8; ++f) {
      const float bt = (f < 4) ? bt0 : bt1;
      #pragma unroll
      for (int r = 0; r < 4; ++r) {
        float v = st[f][r]*scale2 + bt + bias_f[f&3][r];
        st[f][r] = v;
        mt = fmaxf(mt, v);
      }
    }
    mt = fmaxf(mt, __shfl_xor(mt, 16, 64));
    mt = fmaxf(mt, __shfl_xor(mt, 32, 64));
    // T13 defer-max (log2 domain: 8*log2e)
    if (!__all(mt - m_run <= 11.5416f)) {
      const float m_new = fmaxf(m_run, mt);
      const float corr = exp2f(m_run - m_new);
      m_run = m_new;
      l_part *= corr;
      #pragma unroll
      for (int f = 0; f < 4; ++f) {
        ot[f][0] *= corr; ot[f][1] *= corr; ot[f][2] *= corr; ot[f][3] *= corr;
      }
    }
    float psum = 0.f;
    unsigned r01[8], r23[8];
    #pragma unroll
    for (int f = 0; f < 8; ++f) {
      float e0 = exp2f(st[f][0] - m_run);
      float e1 = exp2f(st[f][1] - m_run);
      float e2 = exp2f(st[f][2] - m_run);
      float e3 = exp2f(st[f][3] - m_run);
      psum += (e0+e1)+(e2+e3);
      r01[f] = (unsigned)f2b(e0) | ((unsigned)f2b(e1)<<16);
      r23[f] = (unsigned)f2b(e2) | ((unsigned)f2b(e3)<<16);
    }
    l_part += psum;

    const int src0 = (lg&1)*32 + lq;
    const int src1 = src0 + 16;
    const bool hi = (lg>>1) != 0;
    #pragma unroll
    for (int c = 0; c < 4; ++c) {
      unsigned a0 = (unsigned)__shfl((int)r01[c*2],   src0, 64);
      unsigned b0 = (unsigned)__shfl((int)r01[c*2+1], src0, 64);
      unsigned a1 = (unsigned)__shfl((int)r23[c*2],   src0, 64);
      unsigned b1 = (unsigned)__shfl((int)r23[c*2+1], src0, 64);
      unsigned a2 = (unsigned)__shfl((int)r01[c*2],   src1, 64);
      unsigned b2 = (unsigned)__shfl((int)r01[c*2+1], src1, 64);
      unsigned a3 = (unsigned)__shfl((int)r23[c*2],   src1, 64);
      unsigned b3 = (unsigned)__shfl((int)r23[c*2+1], src1, 64);
      uint4 bw;
      bw.x = hi ? b0 : a0;
      bw.y = hi ? b1 : a1;
      bw.z = hi ? b2 : a2;
      bw.w = hi ? b3 : a3;
      bf16x8 pfrag = *(bf16x8*)&bw;
      __builtin_amdgcn_s_setprio(1);
      #pragma unroll
      for (int f = 0; f < 4; ++f) {
        int row = f*16 + lq;
        int pu = (c*4 + lg) ^ (row & 15);
        bf16x8 vf_ = *(const bf16x8*)(Vs[cur] + row*256 + pu*16);
        ot[f] = __builtin_amdgcn_mfma_f32_16x16x32_bf16(vf_, pfrag, ot[f], 0,0,0);
      }
      __builtin_amdgcn_s_setprio(0);
    }
    __syncthreads();
  }

  float l_tot = l_part + __shfl_xor(l_part, 16, 64);
  l_tot += __shfl_xor(l_tot, 32, 64);
  const float inv = 1.0f / l_tot;
  unsigned short* orow = att_bf + ((size_t)(b*256 + q0 + qloc))*512 + hh*64;
  #pragma unroll
  for (int f = 0; f < 4; ++f) {
    uint2 w;
    w.x = (unsigned)f2b(ot[f][0]*inv) | ((unsigned)f2b(ot[f][1]*inv)<<16);
    w.y = (unsigned)f2b(ot[f][2]*inv) | ((unsigned)f2b(ot[f][3]*inv)<<16);
    *(uint2*)(orow + f*16 + lg*4) = w;
  }
}

// ================= FFN1: interleaved W1|W3 + SwiGLU =================
__global__ __launch_bounds__(256) void ffn1_gemm(
    const unsigned short* __restrict__ xin,
    const unsigned short* __restrict__ W1t, const unsigned short* __restrict__ W3t,
    const float* __restrict__ b1_, const float* __restrict__ b3_,
    unsigned short* __restrict__ ff_bf)
{
  __shared__ alignas(16) char As[2*128*64];
  __shared__ alignas(16) char Bs[2*128*64];
  f32x4 acc[16] = {};
  int bx = (blockIdx.x & 7)*128 + (blockIdx.x >> 3);  // XCD-chunked swizzle (nwg=1024)
  const int nt = bx & 31, mt = bx >> 5;
  const int m0 = mt*128, n0 = nt*128;
  auto brow = [&](int r) -> const unsigned short* {
    int p = n0 + r;
    int pb = p >> 4;
    int j = ((pb>>1)<<4) | (p & 15);
    return (pb & 1) ? W3t + (size_t)j*512 : W1t + (size_t)j*512;
  };
  mfma_core<128,128,64,64>(xin, 512, m0, brow, 512, As, Bs, acc);
  const int lane = threadIdx.x & 63, wave = threadIdx.x >> 6;
  const int wr = wave >> 1, wc = wave & 1;
  #pragma unroll
  for (int r = 0; r < 4; ++r)
  #pragma unroll
  for (int cp = 0; cp < 4; cp += 2) {
    f32x4 va = acc[r*4+cp];
    f32x4 vb = acc[r*4+cp+1];
    #pragma unroll
    for (int reg = 0; reg < 4; ++reg) {
      int m = m0 + wr*64 + r*16 + ((lane>>4)<<2) + reg;
      int p = n0 + wc*64 + cp*16 + (lane&15);
      int j = ((p>>5)<<4) | (p & 15);
      float a = va[reg] + b1_[j];
      float bb = vb[reg] + b3_[j];
      float gval = (a / (1.0f + __expf(-a))) * bb;
      ff_bf[(size_t)m*2048 + j] = f2b(gval);
    }
  }
}

// ====== residual GEMM (64x64 tile, BK=64: two 32-k panels per barrier) ==========
__global__ __launch_bounds__(256) void res_gemm(
    const unsigned short* __restrict__ A, int lda,
    const unsigned short* __restrict__ Wt, int kd,
    const float* __restrict__ bias, const float* __restrict__ resv,
    float* __restrict__ h)
{
  __shared__ alignas(16) char As[4][64*64];
  __shared__ alignas(16) char Bs[4][64*64];
  f32x4 acc[4] = {};
  int bx = (blockIdx.x & 7)*64 + (blockIdx.x >> 3);   // XCD-chunked swizzle (nwg=512)
  const int mt = bx >> 3, nt = bx & 7;
  const int m0 = mt*64, n0 = nt*64;
  const int tid = threadIdx.x, wave = tid>>6, lane = tid&63;
  const int wr = wave >> 1, wc = wave & 1;
  const int lr = lane>>2;
  const int swl = (lane&3) ^ ((lane>>2)&3) ^ (lane>>4);

  auto stageP = [&](int slot, int k0){
    gl_lds16(A  + (size_t)(m0 + wave*16 + lr)*lda + k0 + swl*8, As[slot] + wave*1024);
    gl_lds16(Wt + (size_t)(n0 + wave*16 + lr)*kd  + k0 + swl*8, Bs[slot] + wave*1024);
  };

  stageP(0, 0);
  stageP(1, 32);
  __syncthreads();
  int cur = 0;
  for (int k0 = 0; k0 < kd; k0 += 64) {
    if (k0 + 64 < kd) { stageP((cur^1)*2, k0+64); stageP((cur^1)*2+1, k0+96); }
    #pragma unroll
    for (int p = 0; p < 2; ++p) {
      const char* ab = As[cur*2+p];
      const char* bb = Bs[cur*2+p];
      bf16x8 af[2], bfv[2];
      #pragma unroll
      for (int r = 0; r < 2; ++r)
        af[r] = *(const bf16x8*)(ab + (wr*32 + r*16 + (lane&15))*64 + swl*16);
      #pragma unroll
      for (int c = 0; c < 2; ++c)
        bfv[c] = *(const bf16x8*)(bb + (wc*32 + c*16 + (lane&15))*64 + swl*16);
      #pragma unroll
      for (int r = 0; r < 2; ++r)
        #pragma unroll
        for (int c = 0; c < 2; ++c)
          acc[r*2+c] = __builtin_amdgcn_mfma_f32_16x16x32_bf16(af[r], bfv[c], acc[r*2+c], 0,0,0);
    }
    __syncthreads();
    cur ^= 1;
  }

  const float rv = resv[0];
  #pragma unroll
  for (int r = 0; r < 2; ++r)
  #pragma unroll
  for (int c = 0; c < 2; ++c) {
    f32x4 v = acc[r*2+c];
    #pragma unroll
    for (int reg = 0; reg < 4; ++reg) {
      int m = m0 + wr*32 + r*16 + ((lane>>4)<<2) + reg;
      int n = n0 + wc*32 + c*16 + (lane&15);
      h[(size_t)m*512 + n] += rv * (v[reg] + bias[n]);
    }
  }
}

// ================= output projection + unpatchify (f32) =================
__global__ __launch_bounds__(256) void outproj_kernel(
    const float* __restrict__ h, const float* __restrict__ outW,
    const float* __restrict__ outb, float* __restrict__ y)
{
  int bs = blockIdx.x;
  int b = bs >> 8, s = bs & 255;
  int tic = s >> 6, mf = s & 63;
  __shared__ float hr[512];
  __shared__ float part[8][32];
  int tid = threadIdx.x;
  hr[tid]     = h[(size_t)bs*D_ + tid];
  hr[tid+256] = h[(size_t)bs*D_ + tid + 256];
  __syncthreads();
  int i = tid & 31, seg = tid >> 5;
  float acc = 0.0f;
  #pragma unroll
  for (int k = 0; k < 64; ++k) acc += hr[seg*64 + k] * outW[(seg*64 + k)*32 + i];
  part[seg][i] = acc;
  __syncthreads();
  if (tid < 32) {
    float v = outb[tid];
    #pragma unroll
    for (int s2 = 0; s2 < 8; ++s2) v += part[s2][tid];
    int tp = tid >> 3, fp = (tid >> 1) & 3, c = tid & 1;
    y[((size_t)(b*2 + c)*16 + tic*4 + tp)*256 + mf*4 + fp] = v;
  }
}

// ================= launch =================
extern "C" void kernel_launch(void* const* d_in, const int* in_sizes, int n_in,
                              void* d_out, int out_size, void* d_ws, size_t ws_size,
                              hipStream_t stream) {
  (void)in_sizes; (void)n_in; (void)out_size; (void)ws_size;
  const float* x        = (const float*)d_in[0];
  const float* cache_k  = (const float*)d_in[1];
  const float* cache_v  = (const float*)d_in[2];
  const float* in_W     = (const float*)d_in[3];
  const float* in_b     = (const float*)d_in[4];
  const float* ln1_g    = (const float*)d_in[5];
  const float* ln1_b    = (const float*)d_in[6];
  const float* Wq       = (const float*)d_in[7];
  const float* bq       = (const float*)d_in[8];
  const float* Wk       = (const float*)d_in[9];
  const float* bk       = (const float*)d_in[10];
  const float* Wv       = (const float*)d_in[11];
  const float* bv       = (const float*)d_in[12];
  const float* Wo       = (const float*)d_in[13];
  const float* bo       = (const float*)d_in[14];
  const float* rel_time = (const float*)d_in[15];
  const float* rel_freq = (const float*)d_in[16];
  const float* res_a    = (const float*)d_in[17];
  const float* ln2_g    = (const float*)d_in[18];
  const float* ln2_b    = (const float*)d_in[19];
  const float* W1       = (const float*)d_in[20];
  const float* b1       = (const float*)d_in[21];
  const float* W3       = (const float*)d_in[22];
  const float* b3       = (const float*)d_in[23];
  const float* W2       = (const float*)d_in[24];
  const float* b2       = (const float*)d_in[25];
  const float* res_f    = (const float*)d_in[26];
  const float* out_W    = (const float*)d_in[27];
  const float* out_b    = (const float*)d_in[28];

  char* ws = (char*)d_ws;
  size_t o = 0;
  float* h            = (float*)(ws + o);          o += (size_t)4096*512*4;
  unsigned short* xin = (unsigned short*)(ws + o); o += (size_t)4096*512*2;
  unsigned short* qb  = (unsigned short*)(ws + o); o += (size_t)4096*512*2;
  unsigned short* att = (unsigned short*)(ws + o); o += (size_t)4096*512*2;
  unsigned short* kfb = (unsigned short*)(ws + o); o += (size_t)64*1024*64*2;
  unsigned short* vtb = (unsigned short*)(ws + o); o += (size_t)64*64*1024*2;
  unsigned short* vnw = (unsigned short*)(ws + o); o += (size_t)4096*256*2;
  float* smean        = (float*)(ws + o);          o += (size_t)4096*4;
  float* srstd        = (float*)(ws + o);          o += (size_t)4096*4;
  unsigned short* Wqt = (unsigned short*)(ws + o); o += (size_t)4*512*512*2;
  unsigned short* Wkt = (unsigned short*)(ws + o); o += (size_t)4*256*512*2;
  unsigned short* Wvt = (unsigned short*)(ws + o); o += (size_t)4*256*512*2;
  unsigned short* Wot = (unsigned short*)(ws + o); o += (size_t)4*512*512*2;
  unsigned short* W1t = (unsigned short*)(ws + o); o += (size_t)4*2048*512*2;
  unsigned short* W3t = (unsigned short*)(ws + o); o += (size_t)4*2048*512*2;
  unsigned short* W2t = (unsigned short*)(ws + o); o += (size_t)4*512*2048*2;
  unsigned short* ffb = (unsigned short*)(ws + o);

  float* y    = (float*)d_out;
  float* nck0 = y + 131072;
  float* ncv0 = nck0 + 12582912;

  transpose_all<<<3840, 256, 0, stream>>>(Wq, Wk, Wv, Wo, W1, W3, W2,
                                          Wqt, Wkt, Wvt, Wot, W1t, W3t, W2t);

  patchify_inproj<<<256, 256, 0, stream>>>(x, in_W, in_b, h);

  for (int l = 0; l < L_; ++l) {
    ln_stats<<<256, 256, 0, stream>>>(h, smean, srstd);
    qkv_ln_gemm<<<512, 256, 0, stream>>>(
        h, smean, srstd, ln1_g + l*512, ln1_b + l*512,
        Wqt + (size_t)l*512*512, Wkt + (size_t)l*256*512, Wvt + (size_t)l*256*512,
        bq + l*512, bk + l*256, bv + l*256,
        qb, kfb, vnw, nck0 + (size_t)l*3145728, ncv0 + (size_t)l*3145728);
    merge_kv<<<4096, 256, 0, stream>>>(
        cache_k + (size_t)l*3145728, cache_v + (size_t)l*3145728, vnw,
        kfb, vtb, nck0 + (size_t)l*3145728, ncv0 + (size_t)l*3145728);
    flash_attn<<<256, 512, 0, stream>>>(qb, kfb, vtb,
        rel_time + l*31*8, rel_freq + l*127*8, att);
    res_gemm<<<512, 256, 0, stream>>>(att, 512, Wot + (size_t)l*512*512, 512,
                                      bo + l*512, res_a + l, h);
    ln_kernel<<<256, 256, 0, stream>>>(h, xin, ln2_g + l*512, ln2_b + l*512);
    ffn1_gemm<<<1024, 256, 0, stream>>>(
        xin, W1t + (size_t)l*2048*512, W3t + (size_t)l*2048*512,
        b1 + l*2048, b3 + l*2048, ffb);
    res_gemm<<<512, 256, 0, stream>>>(ffb, 2048, W2t + (size_t)l*512*2048, 2048,
                                      b2 + l*512, res_f + l, h);
  }

  outproj_kernel<<<M_, 256, 0, stream>>>(h, out_W, out_b, y);
}

// Round 18
// 596.726 us; speedup vs baseline: 1.0214x; 1.0154x over previous
//
#include <hip/hip_runtime.h>
#include <stdint.h>

typedef __attribute__((ext_vector_type(8))) short bf16x8;
typedef __attribute__((ext_vector_type(4))) float f32x4;

// ---- problem dims ----
#define B_    16
#define S_    256
#define LEFT_ 768
#define KT_   1024
#define D_    512
#define H_    8
#define G_    4
#define HD_   64
#define L_    4
#define FFH_  2048
#define M_    4096   // B*S
#define LOG2E 1.44269504f

__device__ __forceinline__ unsigned short f2b(float f){
  unsigned u = __float_as_uint(f);
  u += 0x7fffu + ((u>>16)&1u);
  return (unsigned short)(u>>16);
}

__device__ __forceinline__ void gl_lds16(const unsigned short* g, void* l){
  __builtin_amdgcn_global_load_lds(
    (const __attribute__((address_space(1))) unsigned int*)g,
    (__attribute__((address_space(3))) unsigned int*)l, 16, 0, 0);
}

// ================= MFMA GEMM core (NT layout), double-buffered, BK=32 ============
template<int BM, int BN, int WM, int WN, class BRowF>
__device__ __forceinline__ void mfma_core(
    const unsigned short* Abase, int lda, int m0, BRowF brow,
    int kd, char* As, char* Bs, f32x4* acc)
{
  constexpr int FR = WM/16, FC = WN/16;
  constexpr int NWC = BN/WN;
  constexpr int CA = BM/64, CB = BN/64;
  const int tid = threadIdx.x, wave = tid>>6, lane = tid&63;
  const int wr = wave / NWC, wc = wave % NWC;
  const int lr = lane>>2;
  const int swl = (lane&3) ^ ((lane>>2)&3) ^ (lane>>4);

  auto stage = [&](int buf, int k0){
    #pragma unroll
    for (int i = 0; i < CA; ++i) {
      const int chunk = wave*CA + i;
      const unsigned short* gp = Abase + (size_t)(m0 + chunk*16 + lr)*lda + k0 + swl*8;
      gl_lds16(gp, As + buf*(BM*64) + chunk*1024);
    }
    #pragma unroll
    for (int i = 0; i < CB; ++i) {
      const int chunk = wave*CB + i;
      const unsigned short* gp = brow(chunk*16 + lr) + k0 + swl*8;
      gl_lds16(gp, Bs + buf*(BN*64) + chunk*1024);
    }
  };

  stage(0, 0);
  __syncthreads();
  int cur = 0;
  for (int k0 = 0; k0 < kd; k0 += 32) {
    if (k0 + 32 < kd) stage(cur^1, k0 + 32);
    bf16x8 af[FR], bfr[FC];
    #pragma unroll
    for (int r = 0; r < FR; ++r)
      af[r] = *(const bf16x8*)(As + cur*(BM*64) + (wr*WM + r*16 + (lane&15))*64 + swl*16);
    #pragma unroll
    for (int c = 0; c < FC; ++c)
      bfr[c] = *(const bf16x8*)(Bs + cur*(BN*64) + (wc*WN + c*16 + (lane&15))*64 + swl*16);
    #pragma unroll
    for (int r = 0; r < FR; ++r)
      #pragma unroll
      for (int c = 0; c < FC; ++c)
        acc[r*FC+c] = __builtin_amdgcn_mfma_f32_16x16x32_bf16(af[r], bfr[c], acc[r*FC+c], 0, 0, 0);
    __syncthreads();
    cur ^= 1;
  }
}

// ================= unified weight transpose+convert =================
__device__ __forceinline__ void tcvt_body(
    const float* __restrict__ src, unsigned short* __restrict__ dst,
    int K, int N, int ntk, int ntn, int bx)
{
  __shared__ float t[64][65];
  int kt = bx % ntk; int nt = (bx/ntk) % ntn; int l = bx/(ntk*ntn);
  src += (size_t)l*K*N; dst += (size_t)l*N*K;
  const int k0 = kt*64, n0 = nt*64;
  const int tid = threadIdx.x;
  #pragma unroll
  for (int i = 0; i < 4; ++i) {
    int kr = (tid>>4) + i*16;
    const float4 v = *(const float4*)&src[(size_t)(k0+kr)*N + n0 + (tid&15)*4];
    t[kr][(tid&15)*4+0]=v.x; t[kr][(tid&15)*4+1]=v.y;
    t[kr][(tid&15)*4+2]=v.z; t[kr][(tid&15)*4+3]=v.w;
  }
  __syncthreads();
  const int nn = tid>>2, kk = (tid&3)*16;
  unsigned w[8];
  #pragma unroll
  for (int j = 0; j < 8; ++j)
    w[j] = (unsigned)f2b(t[kk+2*j][nn]) | ((unsigned)f2b(t[kk+2*j+1][nn])<<16);
  size_t off = (size_t)(n0+nn)*K + k0 + kk;
  *(uint4*)&dst[off]     = make_uint4(w[0],w[1],w[2],w[3]);
  *(uint4*)&dst[off + 8] = make_uint4(w[4],w[5],w[6],w[7]);
}

__global__ __launch_bounds__(256) void transpose_all(
    const float* __restrict__ Wq, const float* __restrict__ Wk,
    const float* __restrict__ Wv, const float* __restrict__ Wo,
    const float* __restrict__ W1, const float* __restrict__ W3,
    const float* __restrict__ W2,
    unsigned short* __restrict__ Wqt, unsigned short* __restrict__ Wkt,
    unsigned short* __restrict__ Wvt, unsigned short* __restrict__ Wot,
    unsigned short* __restrict__ W1t, unsigned short* __restrict__ W3t,
    unsigned short* __restrict__ W2t)
{
  int bx = blockIdx.x;
  if      (bx < 256)  tcvt_body(Wq, Wqt, 512, 512, 8, 8,  bx);
  else if (bx < 384)  tcvt_body(Wk, Wkt, 512, 256, 8, 4,  bx-256);
  else if (bx < 512)  tcvt_body(Wv, Wvt, 512, 256, 8, 4,  bx-384);
  else if (bx < 768)  tcvt_body(Wo, Wot, 512, 512, 8, 8,  bx-512);
  else if (bx < 1792) tcvt_body(W1, W1t, 512, 2048, 8, 32, bx-768);
  else if (bx < 2816) tcvt_body(W3, W3t, 512, 2048, 8, 32, bx-1792);
  else                tcvt_body(W2, W2t, 2048, 512, 32, 8, bx-2816);
}

// ======= patchify + input projection: 16 tokens/block, inW staged in LDS =======
__global__ __launch_bounds__(256) void patchify_inproj(
    const float* __restrict__ x, const float* __restrict__ inW,
    const float* __restrict__ inb, float* __restrict__ h)
{
  __shared__ float wlds[32*512];
  __shared__ float ps[16][33];
  const int tid = threadIdx.x;
  const int tb = blockIdx.x*16;

  #pragma unroll
  for (int i = 0; i < 16; ++i)
    ((float4*)wlds)[i*256 + tid] = ((const float4*)inW)[i*256 + tid];
  {
    int tok = tid >> 5, idx = tid & 31;
    int bs = tb + tok;
    int b = bs >> 8, s = bs & 255;
    int tic = s >> 6, mf = s & 63;
    int tp = idx >> 3, fp = (idx >> 1) & 3, c = idx & 1;
    ps[tok][idx] = x[((size_t)(b*2 + c)*16 + tic*4 + tp)*256 + mf*4 + fp];
    int tok2 = tok + 8;
    int bs2 = tb + tok2;
    int b2 = bs2 >> 8, s2 = bs2 & 255;
    int tic2 = s2 >> 6, mf2 = s2 & 63;
    ps[tok2][idx] = x[((size_t)(b2*2 + c)*16 + tic2*4 + tp)*256 + mf2*4 + fp];
  }
  __syncthreads();

  const int g = tid >> 4, qd = tid & 15;
  const int bs = tb + g;
  for (int j = 0; j < 32; ++j) {
    int d = j*16 + qd;
    float acc = inb[d];
    #pragma unroll
    for (int i = 0; i < 32; ++i) acc += ps[g][i] * wlds[i*512 + d];
    h[(size_t)bs*512 + d] = acc;
  }
}

// ================= LN1 row stats (one pass over h) =================
__global__ __launch_bounds__(256) void ln_stats(
    const float* __restrict__ h, float* __restrict__ smean, float* __restrict__ srstd)
{
  const int tid = threadIdx.x;
  const int row = blockIdx.x*16 + (tid>>4);
  const int qd = tid & 15;
  const float* rp = h + (size_t)row*512 + qd*32;
  float s = 0.f, sq = 0.f;
  #pragma unroll
  for (int i = 0; i < 8; ++i) {
    float4 v = ((const float4*)rp)[i];
    s  += (v.x+v.y)+(v.z+v.w);
    sq += (v.x*v.x+v.y*v.y)+(v.z*v.z+v.w*v.w);
  }
  #pragma unroll
  for (int o = 1; o < 16; o <<= 1) { s += __shfl_xor(s,o,64); sq += __shfl_xor(sq,o,64); }
  if (qd == 0) {
    float mean = s*(1.f/512.f);
    smean[row] = mean;
    srstd[row] = rsqrtf(sq*(1.f/512.f) - mean*mean + 1e-5f);
  }
}

// ================= lean layernorm f32 -> bf16 (ln2): 16 rows/block =============
__global__ __launch_bounds__(256) void ln_kernel(
    const float* __restrict__ in, unsigned short* __restrict__ out,
    const float* __restrict__ g, const float* __restrict__ bta)
{
  const int tid = threadIdx.x;
  const int row = blockIdx.x*16 + (tid>>4);
  const int qd = tid & 15;
  const float* rp = in + (size_t)row*512 + qd*32;
  float4 xv[8];
  float s = 0.f, sq = 0.f;
  #pragma unroll
  for (int i = 0; i < 8; ++i) {
    xv[i] = ((const float4*)rp)[i];
    s  += (xv[i].x+xv[i].y)+(xv[i].z+xv[i].w);
    sq += (xv[i].x*xv[i].x + xv[i].y*xv[i].y)+(xv[i].z*xv[i].z + xv[i].w*xv[i].w);
  }
  #pragma unroll
  for (int o = 1; o < 16; o <<= 1) { s += __shfl_xor(s,o,64); sq += __shfl_xor(sq,o,64); }
  const float mean = s*(1.f/512.f);
  const float rstd = rsqrtf(sq*(1.f/512.f) - mean*mean + 1e-5f);
  const float* gp = g + qd*32;
  const float* bp = bta + qd*32;
  unsigned short* op = out + (size_t)row*512 + qd*32;
  #pragma unroll
  for (int i = 0; i < 4; ++i) {
    float4 a  = xv[2*i],                 b2 = xv[2*i+1];
    float4 ga = ((const float4*)gp)[2*i], gb = ((const float4*)gp)[2*i+1];
    float4 ba = ((const float4*)bp)[2*i], bb = ((const float4*)bp)[2*i+1];
    unsigned w0 = (unsigned)f2b((a.x-mean)*rstd*ga.x + ba.x) | ((unsigned)f2b((a.y-mean)*rstd*ga.y + ba.y)<<16);
    unsigned w1 = (unsigned)f2b((a.z-mean)*rstd*ga.z + ba.z) | ((unsigned)f2b((a.w-mean)*rstd*ga.w + ba.w)<<16);
    unsigned w2 = (unsigned)f2b((b2.x-mean)*rstd*gb.x + bb.x) | ((unsigned)f2b((b2.y-mean)*rstd*gb.y + bb.y)<<16);
    unsigned w3 = (unsigned)f2b((b2.z-mean)*rstd*gb.z + bb.z) | ((unsigned)f2b((b2.w-mean)*rstd*gb.w + bb.w)<<16);
    *(uint4*)(op + i*8) = make_uint4(w0,w1,w2,w3);
  }
}

// ================= QKV GEMM with fused LN1 (stats precomputed) ==============
__global__ __launch_bounds__(256) void qkv_ln_gemm(
    const float* __restrict__ h,
    const float* __restrict__ smean, const float* __restrict__ srstd,
    const float* __restrict__ lng, const float* __restrict__ lnb,
    const unsigned short* __restrict__ Wqt, const unsigned short* __restrict__ Wkt,
    const unsigned short* __restrict__ Wvt,
    const float* __restrict__ bq, const float* __restrict__ bk_, const float* __restrict__ bv_,
    unsigned short* __restrict__ q_bf, unsigned short* __restrict__ kf_bf,
    unsigned short* __restrict__ vnew, float* __restrict__ nck, float* __restrict__ ncv)
{
  __shared__ alignas(16) char As[2][64*64];
  __shared__ alignas(16) char Bs[2][128*64];
  int bx = (blockIdx.x & 7)*64 + (blockIdx.x >> 3);   // XCD-chunked swizzle (nwg=512)
  const int mt = bx >> 3, nt = bx & 7;
  const int m0 = mt*64, n0 = nt*128;
  const int tid = threadIdx.x, wave = tid>>6, lane = tid&63;

  const int ar = tid >> 2, au = tid & 3;
  const int ap = au ^ (ar&3) ^ ((ar>>2)&3);
  const float* arow = h + (size_t)(m0 + ar)*512;
  const float mean_r = smean[m0 + ar];
  const float rstd_r = srstd[m0 + ar];

  const int lr = lane>>2;
  const int swl = (lane&3) ^ ((lane>>2)&3) ^ (lane>>4);
  auto brow = [&](int rr) -> const unsigned short* {
    int n = n0 + rr;
    return n < 512 ? Wqt + (size_t)n*512
         : n < 768 ? Wkt + (size_t)(n-512)*512
                   : Wvt + (size_t)(n-768)*512;
  };
  auto stageB = [&](int buf, int k0){
    #pragma unroll
    for (int i = 0; i < 2; ++i) {
      const int chunk = wave*2 + i;
      gl_lds16(brow(chunk*16+lr) + k0 + swl*8, (char*)Bs[buf] + chunk*1024);
    }
  };

  float4 av[6];
  auto loadA = [&](int k0){
    av[0] = *(const float4*)(arow + k0 + au*8);
    av[1] = *(const float4*)(arow + k0 + au*8 + 4);
    av[2] = *(const float4*)(lng  + k0 + au*8);
    av[3] = *(const float4*)(lng  + k0 + au*8 + 4);
    av[4] = *(const float4*)(lnb  + k0 + au*8);
    av[5] = *(const float4*)(lnb  + k0 + au*8 + 4);
  };
  auto writeA = [&](int buf){
    const float* xv = (const float*)&av[0];
    const float* gv = (const float*)&av[2];
    const float* bv2 = (const float*)&av[4];
    unsigned w[4];
    #pragma unroll
    for (int j = 0; j < 4; ++j) {
      float e0 = (xv[2*j]   - mean_r)*rstd_r*gv[2*j]   + bv2[2*j];
      float e1 = (xv[2*j+1] - mean_r)*rstd_r*gv[2*j+1] + bv2[2*j+1];
      w[j] = (unsigned)f2b(e0) | ((unsigned)f2b(e1)<<16);
    }
    *(uint4*)((char*)As[buf] + ar*64 + ap*16) = make_uint4(w[0],w[1],w[2],w[3]);
  };

  loadA(0);
  stageB(0, 0);
  writeA(0);
  __syncthreads();

  f32x4 acc[8] = {};
  const int wr = wave >> 1, wc = wave & 1;
  for (int k0 = 0; k0 < 512; k0 += 32) {
    const int cur = (k0>>5)&1;
    const bool more = (k0 + 32 < 512);
    if (more) { stageB(cur^1, k0+32); loadA(k0+32); }
    bf16x8 af[2], bfv[4];
    #pragma unroll
    for (int r = 0; r < 2; ++r)
      af[r] = *(const bf16x8*)((char*)As[cur] + (wr*32 + r*16 + (lane&15))*64 + swl*16);
    #pragma unroll
    for (int c = 0; c < 4; ++c)
      bfv[c] = *(const bf16x8*)((char*)Bs[cur] + (wc*64 + c*16 + (lane&15))*64 + swl*16);
    #pragma unroll
    for (int r = 0; r < 2; ++r)
      #pragma unroll
      for (int c = 0; c < 4; ++c)
        acc[r*4+c] = __builtin_amdgcn_mfma_f32_16x16x32_bf16(af[r], bfv[c], acc[r*4+c], 0,0,0);
    if (more) writeA(cur^1);
    __syncthreads();
  }

  #pragma unroll
  for (int r = 0; r < 2; ++r)
  #pragma unroll
  for (int c = 0; c < 4; ++c) {
    f32x4 v = acc[r*4+c];
    #pragma unroll
    for (int reg = 0; reg < 4; ++reg) {
      int m = m0 + wr*32 + r*16 + ((lane>>4)<<2) + reg;
      int n = n0 + wc*64 + c*16 + (lane&15);
      float val = v[reg];
      int b = m >> 8, s = m & 255;
      if (n < 512) {
        q_bf[(size_t)m*512 + n] = f2b(val + bq[n]);
      } else if (n < 768) {
        int g = (n-512) >> 6, hd = n & 63;
        float kv = val + bk_[n-512];
        kf_bf[((size_t)(b*4+g)*1024 + 768 + s)*64 + hd] = f2b(kv);
        nck [((size_t)(b*4+g)*768  + 512 + s)*64 + hd] = kv;
      } else {
        int g = (n-768) >> 6, hd = n & 63;
        float vv = val + bv_[n-768];
        vnew[(size_t)m*256 + (n-768)] = f2b(vv);     // coalesced (consecutive n)
        ncv [((size_t)(b*4+g)*768 + 512 + s)*64 + hd] = vv;
      }
    }
  }
}

// ================= fused cache merge + new-V transpose =================
__global__ __launch_bounds__(256) void merge_kv(
    const float* __restrict__ ck, const float* __restrict__ cv,
    const unsigned short* __restrict__ vnew,
    unsigned short* __restrict__ kf_bf, unsigned short* __restrict__ vt_bf,
    float* __restrict__ nck, float* __restrict__ ncv)
{
  __shared__ float t[64][65];
  const int bb = blockIdx.x;
  const int tid = threadIdx.x;
  if (bb < 3072) {
    size_t idx = (size_t)bb*256 + tid;
    int hd4 = idx & 15;
    size_t tt = (idx >> 4) % 768;
    size_t bg = idx / (16*768);
    const float4 v = ((const float4*)ck)[idx];
    uint2 pk;
    pk.x = (unsigned)f2b(v.x) | ((unsigned)f2b(v.y)<<16);
    pk.y = (unsigned)f2b(v.z) | ((unsigned)f2b(v.w)<<16);
    *(uint2*)&kf_bf[((bg*1024 + tt)*64) + hd4*4] = pk;
    if (tt >= 256)
      ((float4*)nck)[(bg*768 + (tt-256))*16 + hd4] = v;
  } else if (bb < 3840) {
    const int bi = bb - 3072;
    const int bg = bi / 12, tt = bi % 12;
    const int t0 = tt*64;
    #pragma unroll
    for (int i = 0; i < 4; ++i) {
      int tr = (tid>>4) + i*16;
      const float4 v = ((const float4*)cv)[((size_t)bg*768 + t0+tr)*16 + (tid&15)];
      t[tr][(tid&15)*4+0]=v.x; t[tr][(tid&15)*4+1]=v.y;
      t[tr][(tid&15)*4+2]=v.z; t[tr][(tid&15)*4+3]=v.w;
      if (t0+tr >= 256)
        ((float4*)ncv)[((size_t)bg*768 + t0+tr-256)*16 + (tid&15)] = v;
    }
    __syncthreads();
    const int hd = tid>>2, tc = (tid&3)*16;
    unsigned w[8];
    #pragma unroll
    for (int j = 0; j < 8; ++j)
      w[j] = (unsigned)f2b(t[tc+2*j][hd]) | ((unsigned)f2b(t[tc+2*j+1][hd])<<16);
    size_t off = ((size_t)bg*64 + hd)*1024 + t0 + tc;
    *(uint4*)&vt_bf[off]     = make_uint4(w[0],w[1],w[2],w[3]);
    *(uint4*)&vt_bf[off + 8] = make_uint4(w[4],w[5],w[6],w[7]);
  } else {
    const int bi = bb - 3840;            // 0..255
    const int bg = bi >> 2, tt4 = bi & 3;
    const int b = bg >> 2, g = bg & 3;
    const int t0 = 768 + tt4*64;
    unsigned short* ts = (unsigned short*)&t[0][0];   // reuse LDS, stride 68 shorts
    #pragma unroll
    for (int i = 0; i < 4; ++i) {
      int tr = (tid>>4) + i*16;          // token s = (t0-768) + tr
      uint2 v = *(const uint2*)&vnew[((size_t)(b*256 + (t0-768) + tr))*256 + g*64 + (tid&15)*4];
      const unsigned short* pv4 = (const unsigned short*)&v;
      ts[tr*68 + (tid&15)*4 + 0] = pv4[0];
      ts[tr*68 + (tid&15)*4 + 1] = pv4[1];
      ts[tr*68 + (tid&15)*4 + 2] = pv4[2];
      ts[tr*68 + (tid&15)*4 + 3] = pv4[3];
    }
    __syncthreads();
    const int hd = tid>>2, tc = (tid&3)*16;
    unsigned w[8];
    #pragma unroll
    for (int j = 0; j < 8; ++j)
      w[j] = (unsigned)ts[(tc+2*j)*68 + hd] | ((unsigned)ts[(tc+2*j+1)*68 + hd] << 16);
    size_t off = ((size_t)bg*64 + hd)*1024 + t0 + tc;
    *(uint4*)&vt_bf[off]     = make_uint4(w[0],w[1],w[2],w[3]);
    *(uint4*)&vt_bf[off + 8] = make_uint4(w[4],w[5],w[6],w[7]);
  }
}

// ======== fused flash attention, KVBLK=128, QBLK=128, exp2-domain softmax ========
// grid: b(16) * hh(8) * qt(2) = 256 blocks, 512 threads.
__global__ __launch_bounds__(512) void flash_attn(
    const unsigned short* __restrict__ q_bf,   // [B*256][512]
    const unsigned short* __restrict__ kf_bf,  // [bg][1024][64]
    const unsigned short* __restrict__ vt_bf,  // [bg][64hd][1024]
    const float* __restrict__ relt,            // [31][8]
    const float* __restrict__ relf,            // [127][8]
    unsigned short* __restrict__ att_bf)       // [B*256][512]
{
  int bx = (blockIdx.x & 7)*32 + (blockIdx.x >> 3);   // XCD-chunked swizzle (nwg=256)
  const int qt = bx & 1, hh = (bx>>1) & 7, b = bx >> 4;
  const int g = hh >> 1;
  const int tid = threadIdx.x, wave = tid>>6, lane = tid&63;
  const int lg = lane>>4, lq = lane&15;
  const int qloc = wave*16 + lq;         // 0..127
  const int q0 = qt*128;
  const int qtg = qt*2 + (wave>>2);      // query time tile in [0,4)

  __shared__ alignas(16) char Ks[2][16384];
  __shared__ alignas(16) char Vs[2][16384];

  const unsigned short* kfb  = kf_bf + (size_t)(b*4+g)*1024*64;
  const unsigned short* vtb2 = vt_bf + (size_t)(b*4+g)*64*1024;

  auto stage = [&](int buf, int t){
    #pragma unroll
    for (int it = 0; it < 2; ++it) {
      int slot = it*512 + tid;                 // 1024 slots each
      int kr = slot>>3, kp = slot&7,  ku = kp ^ (kr&7);
      gl_lds16(kfb + (size_t)(t*128 + kr)*64 + ku*8, Ks[buf] + slot*16);
      int vr = slot>>4, vp = slot&15, vu = vp ^ (vr&15);
      gl_lds16(vtb2 + (size_t)vr*1024 + t*128 + vu*8, Vs[buf] + slot*16);
    }
  };

  const unsigned short* qrow = q_bf + ((size_t)(b*256 + q0 + qloc))*512 + hh*64;
  bf16x8 qfrag[2];
  qfrag[0] = *(const bf16x8*)(qrow + lg*8);
  qfrag[1] = *(const bf16x8*)(qrow + 32 + lg*8);

  float bias_f[4][4];
  {
    int sq = qloc & 63;
    #pragma unroll
    for (int f = 0; f < 4; ++f)
      #pragma unroll
      for (int r = 0; r < 4; ++r)
        bias_f[f][r] = relf[((sq - (f*16 + lg*4 + r)) + 63)*8 + hh] * LOG2E;
  }
  const float scale2 = 0.125f * LOG2E;

  f32x4 ot[4] = {};
  float m_run = -1e30f, l_part = 0.f;

  stage(0, 0);
  __syncthreads();

  for (int t = 0; t < 8; ++t) {
    const int cur = t & 1;
    if (t + 1 < 8) stage(cur^1, t+1);

    f32x4 st[8] = {};
    __builtin_amdgcn_s_setprio(1);
    #pragma unroll
    for (int c = 0; c < 2; ++c)
      #pragma unroll
      for (int f = 0; f < 8; ++f) {
        int row = f*16 + lq;
        int pu = (c*4 + lg) ^ (row & 7);
        bf16x8 kf_ = *(const bf16x8*)(Ks[cur] + row*128 + pu*16);
        st[f] = __builtin_amdgcn_mfma_f32_16x16x32_bf16(kf_, qfrag[c], st[f], 0,0,0);
      }
    __builtin_amdgcn_s_setprio(0);

    const float bt0 = relt[(27 + qtg - 2*t)*8 + hh] * LOG2E;
    const float bt1 = relt[(27 + qtg - 2*t - 1)*8 + hh] * LOG2E;
    float mt = -1e30f;
    #pragma unroll
    for (int f = 0; f < 8; ++f) {
      const float bt = (f < 4) ? bt0 : bt1;
      #pragma unroll
      for (int r = 0; r < 4; ++r) {
        float v = st[f][r]*scale2 + bt + bias_f[f&3][r];
        st[f][r] = v;
        mt = fmaxf(mt, v);
      }
    }
    mt = fmaxf(mt, __shfl_xor(mt, 16, 64));
    mt = fmaxf(mt, __shfl_xor(mt, 32, 64));
    // T13 defer-max (log2 domain: 8*log2e)
    if (!__all(mt - m_run <= 11.5416f)) {
      const float m_new = fmaxf(m_run, mt);
      const float corr = exp2f(m_run - m_new);
      m_run = m_new;
      l_part *= corr;
      #pragma unroll
      for (int f = 0; f < 4; ++f) {
        ot[f][0] *= corr; ot[f][1] *= corr; ot[f][2] *= corr; ot[f][3] *= corr;
      }
    }
    float psum = 0.f;
    unsigned r01[8], r23[8];
    #pragma unroll
    for (int f = 0; f < 8; ++f) {
      float e0 = exp2f(st[f][0] - m_run);
      float e1 = exp2f(st[f][1] - m_run);
      float e2 = exp2f(st[f][2] - m_run);
      float e3 = exp2f(st[f][3] - m_run);
      psum += (e0+e1)+(e2+e3);
      r01[f] = (unsigned)f2b(e0) | ((unsigned)f2b(e1)<<16);
      r23[f] = (unsigned)f2b(e2) | ((unsigned)f2b(e3)<<16);
    }
    l_part += psum;

    const int src0 = (lg&1)*32 + lq;
    const int src1 = src0 + 16;
    const bool hi = (lg>>1) != 0;
    #pragma unroll
    for (int c = 0; c < 4; ++c) {
      unsigned a0 = (unsigned)__shfl((int)r01[c*2],   src0, 64);
      unsigned b0 = (unsigned)__shfl((int)r01[c*2+1], src0, 64);
      unsigned a1 = (unsigned)__shfl((int)r23[c*2],   src0, 64);
      unsigned b1 = (unsigned)__shfl((int)r23[c*2+1], src0, 64);
      unsigned a2 = (unsigned)__shfl((int)r01[c*2],   src1, 64);
      unsigned b2 = (unsigned)__shfl((int)r01[c*2+1], src1, 64);
      unsigned a3 = (unsigned)__shfl((int)r23[c*2],   src1, 64);
      unsigned b3 = (unsigned)__shfl((int)r23[c*2+1], src1, 64);
      uint4 bw;
      bw.x = hi ? b0 : a0;
      bw.y = hi ? b1 : a1;
      bw.z = hi ? b2 : a2;
      bw.w = hi ? b3 : a3;
      bf16x8 pfrag = *(bf16x8*)&bw;
      __builtin_amdgcn_s_setprio(1);
      #pragma unroll
      for (int f = 0; f < 4; ++f) {
        int row = f*16 + lq;
        int pu = (c*4 + lg) ^ (row & 15);
        bf16x8 vf_ = *(const bf16x8*)(Vs[cur] + row*256 + pu*16);
        ot[f] = __builtin_amdgcn_mfma_f32_16x16x32_bf16(vf_, pfrag, ot[f], 0,0,0);
      }
      __builtin_amdgcn_s_setprio(0);
    }
    __syncthreads();
  }

  float l_tot = l_part + __shfl_xor(l_part, 16, 64);
  l_tot += __shfl_xor(l_tot, 32, 64);
  const float inv = 1.0f / l_tot;
  unsigned short* orow = att_bf + ((size_t)(b*256 + q0 + qloc))*512 + hh*64;
  #pragma unroll
  for (int f = 0; f < 4; ++f) {
    uint2 w;
    w.x = (unsigned)f2b(ot[f][0]*inv) | ((unsigned)f2b(ot[f][1]*inv)<<16);
    w.y = (unsigned)f2b(ot[f][2]*inv) | ((unsigned)f2b(ot[f][3]*inv)<<16);
    *(uint2*)(orow + f*16 + lg*4) = w;
  }
}

// ================= FFN1: interleaved W1|W3 + SwiGLU =================
__global__ __launch_bounds__(256) void ffn1_gemm(
    const unsigned short* __restrict__ xin,
    const unsigned short* __restrict__ W1t, const unsigned short* __restrict__ W3t,
    const float* __restrict__ b1_, const float* __restrict__ b3_,
    unsigned short* __restrict__ ff_bf)
{
  __shared__ alignas(16) char As[2*128*64];
  __shared__ alignas(16) char Bs[2*128*64];
  f32x4 acc[16] = {};
  // Column-chunk XCD swizzle (nwg=1024): XCD k = bid&7 owns nt in [4k,4k+4),
  // so its B-slice (1 MB of W1t|W3t) and A (4 MB xin) are both L2-resident.
  const int bid = blockIdx.x;
  const int q = bid >> 3;
  int bx = (q >> 2)*32 + (bid & 7)*4 + (q & 3);
  const int nt = bx & 31, mt = bx >> 5;
  const int m0 = mt*128, n0 = nt*128;
  auto brow = [&](int r) -> const unsigned short* {
    int p = n0 + r;
    int pb = p >> 4;
    int j = ((pb>>1)<<4) | (p & 15);
    return (pb & 1) ? W3t + (size_t)j*512 : W1t + (size_t)j*512;
  };
  mfma_core<128,128,64,64>(xin, 512, m0, brow, 512, As, Bs, acc);
  const int lane = threadIdx.x & 63, wave = threadIdx.x >> 6;
  const int wr = wave >> 1, wc = wave & 1;
  #pragma unroll
  for (int r = 0; r < 4; ++r)
  #pragma unroll
  for (int cp = 0; cp < 4; cp += 2) {
    f32x4 va = acc[r*4+cp];
    f32x4 vb = acc[r*4+cp+1];
    #pragma unroll
    for (int reg = 0; reg < 4; ++reg) {
      int m = m0 + wr*64 + r*16 + ((lane>>4)<<2) + reg;
      int p = n0 + wc*64 + cp*16 + (lane&15);
      int j = ((p>>5)<<4) | (p & 15);
      float a = va[reg] + b1_[j];
      float bb = vb[reg] + b3_[j];
      float gval = (a / (1.0f + __expf(-a))) * bb;
      ff_bf[(size_t)m*2048 + j] = f2b(gval);
    }
  }
}

// ====== residual GEMM (64x64 tile, BK=64: two 32-k panels per barrier) ==========
__global__ __launch_bounds__(256) void res_gemm(
    const unsigned short* __restrict__ A, int lda,
    const unsigned short* __restrict__ Wt, int kd,
    const float* __restrict__ bias, const float* __restrict__ resv,
    float* __restrict__ h)
{
  __shared__ alignas(16) char As[4][64*64];
  __shared__ alignas(16) char Bs[4][64*64];
  f32x4 acc[4] = {};
  int bx = (blockIdx.x & 7)*64 + (blockIdx.x >> 3);   // XCD-chunked swizzle (nwg=512)
  const int mt = bx >> 3, nt = bx & 7;
  const int m0 = mt*64, n0 = nt*64;
  const int tid = threadIdx.x, wave = tid>>6, lane = tid&63;
  const int wr = wave >> 1, wc = wave & 1;
  const int lr = lane>>2;
  const int swl = (lane&3) ^ ((lane>>2)&3) ^ (lane>>4);

  auto stageP = [&](int slot, int k0){
    gl_lds16(A  + (size_t)(m0 + wave*16 + lr)*lda + k0 + swl*8, As[slot] + wave*1024);
    gl_lds16(Wt + (size_t)(n0 + wave*16 + lr)*kd  + k0 + swl*8, Bs[slot] + wave*1024);
  };

  stageP(0, 0);
  stageP(1, 32);
  __syncthreads();
  int cur = 0;
  for (int k0 = 0; k0 < kd; k0 += 64) {
    if (k0 + 64 < kd) { stageP((cur^1)*2, k0+64); stageP((cur^1)*2+1, k0+96); }
    #pragma unroll
    for (int p = 0; p < 2; ++p) {
      const char* ab = As[cur*2+p];
      const char* bb = Bs[cur*2+p];
      bf16x8 af[2], bfv[2];
      #pragma unroll
      for (int r = 0; r < 2; ++r)
        af[r] = *(const bf16x8*)(ab + (wr*32 + r*16 + (lane&15))*64 + swl*16);
      #pragma unroll
      for (int c = 0; c < 2; ++c)
        bfv[c] = *(const bf16x8*)(bb + (wc*32 + c*16 + (lane&15))*64 + swl*16);
      #pragma unroll
      for (int r = 0; r < 2; ++r)
        #pragma unroll
        for (int c = 0; c < 2; ++c)
          acc[r*2+c] = __builtin_amdgcn_mfma_f32_16x16x32_bf16(af[r], bfv[c], acc[r*2+c], 0,0,0);
    }
    __syncthreads();
    cur ^= 1;
  }

  const float rv = resv[0];
  #pragma unroll
  for (int r = 0; r < 2; ++r)
  #pragma unroll
  for (int c = 0; c < 2; ++c) {
    f32x4 v = acc[r*2+c];
    #pragma unroll
    for (int reg = 0; reg < 4; ++reg) {
      int m = m0 + wr*32 + r*16 + ((lane>>4)<<2) + reg;
      int n = n0 + wc*32 + c*16 + (lane&15);
      h[(size_t)m*512 + n] += rv * (v[reg] + bias[n]);
    }
  }
}

// ================= output projection + unpatchify (f32) =================
__global__ __launch_bounds__(256) void outproj_kernel(
    const float* __restrict__ h, const float* __restrict__ outW,
    const float* __restrict__ outb, float* __restrict__ y)
{
  int bs = blockIdx.x;
  int b = bs >> 8, s = bs & 255;
  int tic = s >> 6, mf = s & 63;
  __shared__ float hr[512];
  __shared__ float part[8][32];
  int tid = threadIdx.x;
  hr[tid]     = h[(size_t)bs*D_ + tid];
  hr[tid+256] = h[(size_t)bs*D_ + tid + 256];
  __syncthreads();
  int i = tid & 31, seg = tid >> 5;
  float acc = 0.0f;
  #pragma unroll
  for (int k = 0; k < 64; ++k) acc += hr[seg*64 + k] * outW[(seg*64 + k)*32 + i];
  part[seg][i] = acc;
  __syncthreads();
  if (tid < 32) {
    float v = outb[tid];
    #pragma unroll
    for (int s2 = 0; s2 < 8; ++s2) v += part[s2][tid];
    int tp = tid >> 3, fp = (tid >> 1) & 3, c = tid & 1;
    y[((size_t)(b*2 + c)*16 + tic*4 + tp)*256 + mf*4 + fp] = v;
  }
}

// ================= launch =================
extern "C" void kernel_launch(void* const* d_in, const int* in_sizes, int n_in,
                              void* d_out, int out_size, void* d_ws, size_t ws_size,
                              hipStream_t stream) {
  (void)in_sizes; (void)n_in; (void)out_size; (void)ws_size;
  const float* x        = (const float*)d_in[0];
  const float* cache_k  = (const float*)d_in[1];
  const float* cache_v  = (const float*)d_in[2];
  const float* in_W     = (const float*)d_in[3];
  const float* in_b     = (const float*)d_in[4];
  const float* ln1_g    = (const float*)d_in[5];
  const float* ln1_b    = (const float*)d_in[6];
  const float* Wq       = (const float*)d_in[7];
  const float* bq       = (const float*)d_in[8];
  const float* Wk       = (const float*)d_in[9];
  const float* bk       = (const float*)d_in[10];
  const float* Wv       = (const float*)d_in[11];
  const float* bv       = (const float*)d_in[12];
  const float* Wo       = (const float*)d_in[13];
  const float* bo       = (const float*)d_in[14];
  const float* rel_time = (const float*)d_in[15];
  const float* rel_freq = (const float*)d_in[16];
  const float* res_a    = (const float*)d_in[17];
  const float* ln2_g    = (const float*)d_in[18];
  const float* ln2_b    = (const float*)d_in[19];
  const float* W1       = (const float*)d_in[20];
  const float* b1       = (const float*)d_in[21];
  const float* W3       = (const float*)d_in[22];
  const float* b3       = (const float*)d_in[23];
  const float* W2       = (const float*)d_in[24];
  const float* b2       = (const float*)d_in[25];
  const float* res_f    = (const float*)d_in[26];
  const float* out_W    = (const float*)d_in[27];
  const float* out_b    = (const float*)d_in[28];

  char* ws = (char*)d_ws;
  size_t o = 0;
  float* h            = (float*)(ws + o);          o += (size_t)4096*512*4;
  unsigned short* xin = (unsigned short*)(ws + o); o += (size_t)4096*512*2;
  unsigned short* qb  = (unsigned short*)(ws + o); o += (size_t)4096*512*2;
  unsigned short* att = (unsigned short*)(ws + o); o += (size_t)4096*512*2;
  unsigned short* kfb = (unsigned short*)(ws + o); o += (size_t)64*1024*64*2;
  unsigned short* vtb = (unsigned short*)(ws + o); o += (size_t)64*64*1024*2;
  unsigned short* vnw = (unsigned short*)(ws + o); o += (size_t)4096*256*2;
  float* smean        = (float*)(ws + o);          o += (size_t)4096*4;
  float* srstd        = (float*)(ws + o);          o += (size_t)4096*4;
  unsigned short* Wqt = (unsigned short*)(ws + o); o += (size_t)4*512*512*2;
  unsigned short* Wkt = (unsigned short*)(ws + o); o += (size_t)4*256*512*2;
  unsigned short* Wvt = (unsigned short*)(ws + o); o += (size_t)4*256*512*2;
  unsigned short* Wot = (unsigned short*)(ws + o); o += (size_t)4*512*512*2;
  unsigned short* W1t = (unsigned short*)(ws + o); o += (size_t)4*2048*512*2;
  unsigned short* W3t = (unsigned short*)(ws + o); o += (size_t)4*2048*512*2;
  unsigned short* W2t = (unsigned short*)(ws + o); o += (size_t)4*512*2048*2;
  unsigned short* ffb = (unsigned short*)(ws + o);

  float* y    = (float*)d_out;
  float* nck0 = y + 131072;
  float* ncv0 = nck0 + 12582912;

  transpose_all<<<3840, 256, 0, stream>>>(Wq, Wk, Wv, Wo, W1, W3, W2,
                                          Wqt, Wkt, Wvt, Wot, W1t, W3t, W2t);

  patchify_inproj<<<256, 256, 0, stream>>>(x, in_W, in_b, h);

  for (int l = 0; l < L_; ++l) {
    ln_stats<<<256, 256, 0, stream>>>(h, smean, srstd);
    qkv_ln_gemm<<<512, 256, 0, stream>>>(
        h, smean, srstd, ln1_g + l*512, ln1_b + l*512,
        Wqt + (size_t)l*512*512, Wkt + (size_t)l*256*512, Wvt + (size_t)l*256*512,
        bq + l*512, bk + l*256, bv + l*256,
        qb, kfb, vnw, nck0 + (size_t)l*3145728, ncv0 + (size_t)l*3145728);
    merge_kv<<<4096, 256, 0, stream>>>(
        cache_k + (size_t)l*3145728, cache_v + (size_t)l*3145728, vnw,
        kfb, vtb, nck0 + (size_t)l*3145728, ncv0 + (size_t)l*3145728);
    flash_attn<<<256, 512, 0, stream>>>(qb, kfb, vtb,
        rel_time + l*31*8, rel_freq + l*127*8, att);
    res_gemm<<<512, 256, 0, stream>>>(att, 512, Wot + (size_t)l*512*512, 512,
                                      bo + l*512, res_a + l, h);
    ln_kernel<<<256, 256, 0, stream>>>(h, xin, ln2_g + l*512, ln2_b + l*512);
    ffn1_gemm<<<1024, 256, 0, stream>>>(
        xin, W1t + (size_t)l*2048*512, W3t + (size_t)l*2048*512,
        b1 + l*2048, b3 + l*2048, ffb);
    res_gemm<<<512, 256, 0, stream>>>(ffb, 2048, W2t + (size_t)l*512*2048, 2048,
                                      b2 + l*512, res_f + l, h);
  }

  outproj_kernel<<<M_, 256, 0, stream>>>(h, out_W, out_b, y);
}

// Round 19
// 596.162 us; speedup vs baseline: 1.0224x; 1.0009x over previous
//
#include <hip/hip_runtime.h>
#include <stdint.h>

typedef __attribute__((ext_vector_type(8))) short bf16x8;
typedef __attribute__((ext_vector_type(4))) float f32x4;

// ---- problem dims ----
#define B_    16
#define S_    256
#define LEFT_ 768
#define KT_   1024
#define D_    512
#define H_    8
#define G_    4
#define HD_   64
#define L_    4
#define FFH_  2048
#define M_    4096   // B*S
#define LOG2E 1.44269504f

__device__ __forceinline__ unsigned short f2b(float f){
  unsigned u = __float_as_uint(f);
  u += 0x7fffu + ((u>>16)&1u);
  return (unsigned short)(u>>16);
}

__device__ __forceinline__ void gl_lds16(const unsigned short* g, void* l){
  __builtin_amdgcn_global_load_lds(
    (const __attribute__((address_space(1))) unsigned int*)g,
    (__attribute__((address_space(3))) unsigned int*)l, 16, 0, 0);
}

// ================= MFMA GEMM core (NT layout), double-buffered, BK=32 ============
template<int BM, int BN, int WM, int WN, class BRowF>
__device__ __forceinline__ void mfma_core(
    const unsigned short* Abase, int lda, int m0, BRowF brow,
    int kd, char* As, char* Bs, f32x4* acc)
{
  constexpr int FR = WM/16, FC = WN/16;
  constexpr int NWC = BN/WN;
  constexpr int CA = BM/64, CB = BN/64;
  const int tid = threadIdx.x, wave = tid>>6, lane = tid&63;
  const int wr = wave / NWC, wc = wave % NWC;
  const int lr = lane>>2;
  const int swl = (lane&3) ^ ((lane>>2)&3) ^ (lane>>4);

  auto stage = [&](int buf, int k0){
    #pragma unroll
    for (int i = 0; i < CA; ++i) {
      const int chunk = wave*CA + i;
      const unsigned short* gp = Abase + (size_t)(m0 + chunk*16 + lr)*lda + k0 + swl*8;
      gl_lds16(gp, As + buf*(BM*64) + chunk*1024);
    }
    #pragma unroll
    for (int i = 0; i < CB; ++i) {
      const int chunk = wave*CB + i;
      const unsigned short* gp = brow(chunk*16 + lr) + k0 + swl*8;
      gl_lds16(gp, Bs + buf*(BN*64) + chunk*1024);
    }
  };

  stage(0, 0);
  __syncthreads();
  int cur = 0;
  for (int k0 = 0; k0 < kd; k0 += 32) {
    if (k0 + 32 < kd) stage(cur^1, k0 + 32);
    bf16x8 af[FR], bfr[FC];
    #pragma unroll
    for (int r = 0; r < FR; ++r)
      af[r] = *(const bf16x8*)(As + cur*(BM*64) + (wr*WM + r*16 + (lane&15))*64 + swl*16);
    #pragma unroll
    for (int c = 0; c < FC; ++c)
      bfr[c] = *(const bf16x8*)(Bs + cur*(BN*64) + (wc*WN + c*16 + (lane&15))*64 + swl*16);
    #pragma unroll
    for (int r = 0; r < FR; ++r)
      #pragma unroll
      for (int c = 0; c < FC; ++c)
        acc[r*FC+c] = __builtin_amdgcn_mfma_f32_16x16x32_bf16(af[r], bfr[c], acc[r*FC+c], 0, 0, 0);
    __syncthreads();
    cur ^= 1;
  }
}

// ================= unified weight transpose+convert =================
__device__ __forceinline__ void tcvt_body(
    const float* __restrict__ src, unsigned short* __restrict__ dst,
    int K, int N, int ntk, int ntn, int bx)
{
  __shared__ float t[64][65];
  int kt = bx % ntk; int nt = (bx/ntk) % ntn; int l = bx/(ntk*ntn);
  src += (size_t)l*K*N; dst += (size_t)l*N*K;
  const int k0 = kt*64, n0 = nt*64;
  const int tid = threadIdx.x;
  #pragma unroll
  for (int i = 0; i < 4; ++i) {
    int kr = (tid>>4) + i*16;
    const float4 v = *(const float4*)&src[(size_t)(k0+kr)*N + n0 + (tid&15)*4];
    t[kr][(tid&15)*4+0]=v.x; t[kr][(tid&15)*4+1]=v.y;
    t[kr][(tid&15)*4+2]=v.z; t[kr][(tid&15)*4+3]=v.w;
  }
  __syncthreads();
  const int nn = tid>>2, kk = (tid&3)*16;
  unsigned w[8];
  #pragma unroll
  for (int j = 0; j < 8; ++j)
    w[j] = (unsigned)f2b(t[kk+2*j][nn]) | ((unsigned)f2b(t[kk+2*j+1][nn])<<16);
  size_t off = (size_t)(n0+nn)*K + k0 + kk;
  *(uint4*)&dst[off]     = make_uint4(w[0],w[1],w[2],w[3]);
  *(uint4*)&dst[off + 8] = make_uint4(w[4],w[5],w[6],w[7]);
}

__global__ __launch_bounds__(256) void transpose_all(
    const float* __restrict__ Wq, const float* __restrict__ Wk,
    const float* __restrict__ Wv, const float* __restrict__ Wo,
    const float* __restrict__ W1, const float* __restrict__ W3,
    const float* __restrict__ W2,
    unsigned short* __restrict__ Wqt, unsigned short* __restrict__ Wkt,
    unsigned short* __restrict__ Wvt, unsigned short* __restrict__ Wot,
    unsigned short* __restrict__ W1t, unsigned short* __restrict__ W3t,
    unsigned short* __restrict__ W2t)
{
  int bx = blockIdx.x;
  if      (bx < 256)  tcvt_body(Wq, Wqt, 512, 512, 8, 8,  bx);
  else if (bx < 384)  tcvt_body(Wk, Wkt, 512, 256, 8, 4,  bx-256);
  else if (bx < 512)  tcvt_body(Wv, Wvt, 512, 256, 8, 4,  bx-384);
  else if (bx < 768)  tcvt_body(Wo, Wot, 512, 512, 8, 8,  bx-512);
  else if (bx < 1792) tcvt_body(W1, W1t, 512, 2048, 8, 32, bx-768);
  else if (bx < 2816) tcvt_body(W3, W3t, 512, 2048, 8, 32, bx-1792);
  else                tcvt_body(W2, W2t, 2048, 512, 32, 8, bx-2816);
}

// ======= patchify + input projection: 16 tokens/block, inW staged in LDS =======
__global__ __launch_bounds__(256) void patchify_inproj(
    const float* __restrict__ x, const float* __restrict__ inW,
    const float* __restrict__ inb, float* __restrict__ h)
{
  __shared__ float wlds[32*512];
  __shared__ float ps[16][33];
  const int tid = threadIdx.x;
  const int tb = blockIdx.x*16;

  #pragma unroll
  for (int i = 0; i < 16; ++i)
    ((float4*)wlds)[i*256 + tid] = ((const float4*)inW)[i*256 + tid];
  {
    int tok = tid >> 5, idx = tid & 31;
    int bs = tb + tok;
    int b = bs >> 8, s = bs & 255;
    int tic = s >> 6, mf = s & 63;
    int tp = idx >> 3, fp = (idx >> 1) & 3, c = idx & 1;
    ps[tok][idx] = x[((size_t)(b*2 + c)*16 + tic*4 + tp)*256 + mf*4 + fp];
    int tok2 = tok + 8;
    int bs2 = tb + tok2;
    int b2 = bs2 >> 8, s2 = bs2 & 255;
    int tic2 = s2 >> 6, mf2 = s2 & 63;
    ps[tok2][idx] = x[((size_t)(b2*2 + c)*16 + tic2*4 + tp)*256 + mf2*4 + fp];
  }
  __syncthreads();

  const int g = tid >> 4, qd = tid & 15;
  const int bs = tb + g;
  for (int j = 0; j < 32; ++j) {
    int d = j*16 + qd;
    float acc = inb[d];
    #pragma unroll
    for (int i = 0; i < 32; ++i) acc += ps[g][i] * wlds[i*512 + d];
    h[(size_t)bs*512 + d] = acc;
  }
}

// ================= LN1 row stats (one pass over h) =================
__global__ __launch_bounds__(256) void ln_stats(
    const float* __restrict__ h, float* __restrict__ smean, float* __restrict__ srstd)
{
  const int tid = threadIdx.x;
  const int row = blockIdx.x*16 + (tid>>4);
  const int qd = tid & 15;
  const float* rp = h + (size_t)row*512 + qd*32;
  float s = 0.f, sq = 0.f;
  #pragma unroll
  for (int i = 0; i < 8; ++i) {
    float4 v = ((const float4*)rp)[i];
    s  += (v.x+v.y)+(v.z+v.w);
    sq += (v.x*v.x+v.y*v.y)+(v.z*v.z+v.w*v.w);
  }
  #pragma unroll
  for (int o = 1; o < 16; o <<= 1) { s += __shfl_xor(s,o,64); sq += __shfl_xor(sq,o,64); }
  if (qd == 0) {
    float mean = s*(1.f/512.f);
    smean[row] = mean;
    srstd[row] = rsqrtf(sq*(1.f/512.f) - mean*mean + 1e-5f);
  }
}

// ================= lean layernorm f32 -> bf16 (ln2): 16 rows/block =============
__global__ __launch_bounds__(256) void ln_kernel(
    const float* __restrict__ in, unsigned short* __restrict__ out,
    const float* __restrict__ g, const float* __restrict__ bta)
{
  const int tid = threadIdx.x;
  const int row = blockIdx.x*16 + (tid>>4);
  const int qd = tid & 15;
  const float* rp = in + (size_t)row*512 + qd*32;
  float4 xv[8];
  float s = 0.f, sq = 0.f;
  #pragma unroll
  for (int i = 0; i < 8; ++i) {
    xv[i] = ((const float4*)rp)[i];
    s  += (xv[i].x+xv[i].y)+(xv[i].z+xv[i].w);
    sq += (xv[i].x*xv[i].x + xv[i].y*xv[i].y)+(xv[i].z*xv[i].z + xv[i].w*xv[i].w);
  }
  #pragma unroll
  for (int o = 1; o < 16; o <<= 1) { s += __shfl_xor(s,o,64); sq += __shfl_xor(sq,o,64); }
  const float mean = s*(1.f/512.f);
  const float rstd = rsqrtf(sq*(1.f/512.f) - mean*mean + 1e-5f);
  const float* gp = g + qd*32;
  const float* bp = bta + qd*32;
  unsigned short* op = out + (size_t)row*512 + qd*32;
  #pragma unroll
  for (int i = 0; i < 4; ++i) {
    float4 a  = xv[2*i],                 b2 = xv[2*i+1];
    float4 ga = ((const float4*)gp)[2*i], gb = ((const float4*)gp)[2*i+1];
    float4 ba = ((const float4*)bp)[2*i], bb = ((const float4*)bp)[2*i+1];
    unsigned w0 = (unsigned)f2b((a.x-mean)*rstd*ga.x + ba.x) | ((unsigned)f2b((a.y-mean)*rstd*ga.y + ba.y)<<16);
    unsigned w1 = (unsigned)f2b((a.z-mean)*rstd*ga.z + ba.z) | ((unsigned)f2b((a.w-mean)*rstd*ga.w + ba.w)<<16);
    unsigned w2 = (unsigned)f2b((b2.x-mean)*rstd*gb.x + bb.x) | ((unsigned)f2b((b2.y-mean)*rstd*gb.y + bb.y)<<16);
    unsigned w3 = (unsigned)f2b((b2.z-mean)*rstd*gb.z + bb.z) | ((unsigned)f2b((b2.w-mean)*rstd*gb.w + bb.w)<<16);
    *(uint4*)(op + i*8) = make_uint4(w0,w1,w2,w3);
  }
}

// ================= QKV GEMM with fused LN1 (stats precomputed) ==============
__global__ __launch_bounds__(256) void qkv_ln_gemm(
    const float* __restrict__ h,
    const float* __restrict__ smean, const float* __restrict__ srstd,
    const float* __restrict__ lng, const float* __restrict__ lnb,
    const unsigned short* __restrict__ Wqt, const unsigned short* __restrict__ Wkt,
    const unsigned short* __restrict__ Wvt,
    const float* __restrict__ bq, const float* __restrict__ bk_, const float* __restrict__ bv_,
    unsigned short* __restrict__ q_bf, unsigned short* __restrict__ kf_bf,
    unsigned short* __restrict__ vnew, float* __restrict__ nck, float* __restrict__ ncv)
{
  __shared__ alignas(16) char As[2][64*64];
  __shared__ alignas(16) char Bs[2][128*64];
  int bx = (blockIdx.x & 7)*64 + (blockIdx.x >> 3);   // XCD-chunked swizzle (nwg=512)
  const int mt = bx >> 3, nt = bx & 7;
  const int m0 = mt*64, n0 = nt*128;
  const int tid = threadIdx.x, wave = tid>>6, lane = tid&63;

  const int ar = tid >> 2, au = tid & 3;
  const int ap = au ^ (ar&3) ^ ((ar>>2)&3);
  const float* arow = h + (size_t)(m0 + ar)*512;
  const float mean_r = smean[m0 + ar];
  const float rstd_r = srstd[m0 + ar];

  const int lr = lane>>2;
  const int swl = (lane&3) ^ ((lane>>2)&3) ^ (lane>>4);
  auto brow = [&](int rr) -> const unsigned short* {
    int n = n0 + rr;
    return n < 512 ? Wqt + (size_t)n*512
         : n < 768 ? Wkt + (size_t)(n-512)*512
                   : Wvt + (size_t)(n-768)*512;
  };
  auto stageB = [&](int buf, int k0){
    #pragma unroll
    for (int i = 0; i < 2; ++i) {
      const int chunk = wave*2 + i;
      gl_lds16(brow(chunk*16+lr) + k0 + swl*8, (char*)Bs[buf] + chunk*1024);
    }
  };

  float4 av[6];
  auto loadA = [&](int k0){
    av[0] = *(const float4*)(arow + k0 + au*8);
    av[1] = *(const float4*)(arow + k0 + au*8 + 4);
    av[2] = *(const float4*)(lng  + k0 + au*8);
    av[3] = *(const float4*)(lng  + k0 + au*8 + 4);
    av[4] = *(const float4*)(lnb  + k0 + au*8);
    av[5] = *(const float4*)(lnb  + k0 + au*8 + 4);
  };
  auto writeA = [&](int buf){
    const float* xv = (const float*)&av[0];
    const float* gv = (const float*)&av[2];
    const float* bv2 = (const float*)&av[4];
    unsigned w[4];
    #pragma unroll
    for (int j = 0; j < 4; ++j) {
      float e0 = (xv[2*j]   - mean_r)*rstd_r*gv[2*j]   + bv2[2*j];
      float e1 = (xv[2*j+1] - mean_r)*rstd_r*gv[2*j+1] + bv2[2*j+1];
      w[j] = (unsigned)f2b(e0) | ((unsigned)f2b(e1)<<16);
    }
    *(uint4*)((char*)As[buf] + ar*64 + ap*16) = make_uint4(w[0],w[1],w[2],w[3]);
  };

  loadA(0);
  stageB(0, 0);
  writeA(0);
  __syncthreads();

  f32x4 acc[8] = {};
  const int wr = wave >> 1, wc = wave & 1;
  for (int k0 = 0; k0 < 512; k0 += 32) {
    const int cur = (k0>>5)&1;
    const bool more = (k0 + 32 < 512);
    if (more) { stageB(cur^1, k0+32); loadA(k0+32); }
    bf16x8 af[2], bfv[4];
    #pragma unroll
    for (int r = 0; r < 2; ++r)
      af[r] = *(const bf16x8*)((char*)As[cur] + (wr*32 + r*16 + (lane&15))*64 + swl*16);
    #pragma unroll
    for (int c = 0; c < 4; ++c)
      bfv[c] = *(const bf16x8*)((char*)Bs[cur] + (wc*64 + c*16 + (lane&15))*64 + swl*16);
    #pragma unroll
    for (int r = 0; r < 2; ++r)
      #pragma unroll
      for (int c = 0; c < 4; ++c)
        acc[r*4+c] = __builtin_amdgcn_mfma_f32_16x16x32_bf16(af[r], bfv[c], acc[r*4+c], 0,0,0);
    if (more) writeA(cur^1);
    __syncthreads();
  }

  #pragma unroll
  for (int r = 0; r < 2; ++r)
  #pragma unroll
  for (int c = 0; c < 4; ++c) {
    f32x4 v = acc[r*4+c];
    #pragma unroll
    for (int reg = 0; reg < 4; ++reg) {
      int m = m0 + wr*32 + r*16 + ((lane>>4)<<2) + reg;
      int n = n0 + wc*64 + c*16 + (lane&15);
      float val = v[reg];
      int b = m >> 8, s = m & 255;
      if (n < 512) {
        q_bf[(size_t)m*512 + n] = f2b(val + bq[n]);
      } else if (n < 768) {
        int g = (n-512) >> 6, hd = n & 63;
        float kv = val + bk_[n-512];
        kf_bf[((size_t)(b*4+g)*1024 + 768 + s)*64 + hd] = f2b(kv);
        nck [((size_t)(b*4+g)*768  + 512 + s)*64 + hd] = kv;
      } else {
        int g = (n-768) >> 6, hd = n & 63;
        float vv = val + bv_[n-768];
        vnew[(size_t)m*256 + (n-768)] = f2b(vv);     // coalesced (consecutive n)
        ncv [((size_t)(b*4+g)*768 + 512 + s)*64 + hd] = vv;
      }
    }
  }
}

// ================= fused cache merge + new-V transpose =================
__global__ __launch_bounds__(256) void merge_kv(
    const float* __restrict__ ck, const float* __restrict__ cv,
    const unsigned short* __restrict__ vnew,
    unsigned short* __restrict__ kf_bf, unsigned short* __restrict__ vt_bf,
    float* __restrict__ nck, float* __restrict__ ncv)
{
  __shared__ float t[64][65];
  const int bb = blockIdx.x;
  const int tid = threadIdx.x;
  if (bb < 3072) {
    size_t idx = (size_t)bb*256 + tid;
    int hd4 = idx & 15;
    size_t tt = (idx >> 4) % 768;
    size_t bg = idx / (16*768);
    const float4 v = ((const float4*)ck)[idx];
    uint2 pk;
    pk.x = (unsigned)f2b(v.x) | ((unsigned)f2b(v.y)<<16);
    pk.y = (unsigned)f2b(v.z) | ((unsigned)f2b(v.w)<<16);
    *(uint2*)&kf_bf[((bg*1024 + tt)*64) + hd4*4] = pk;
    if (tt >= 256)
      ((float4*)nck)[(bg*768 + (tt-256))*16 + hd4] = v;
  } else if (bb < 3840) {
    const int bi = bb - 3072;
    const int bg = bi / 12, tt = bi % 12;
    const int t0 = tt*64;
    #pragma unroll
    for (int i = 0; i < 4; ++i) {
      int tr = (tid>>4) + i*16;
      const float4 v = ((const float4*)cv)[((size_t)bg*768 + t0+tr)*16 + (tid&15)];
      t[tr][(tid&15)*4+0]=v.x; t[tr][(tid&15)*4+1]=v.y;
      t[tr][(tid&15)*4+2]=v.z; t[tr][(tid&15)*4+3]=v.w;
      if (t0+tr >= 256)
        ((float4*)ncv)[((size_t)bg*768 + t0+tr-256)*16 + (tid&15)] = v;
    }
    __syncthreads();
    const int hd = tid>>2, tc = (tid&3)*16;
    unsigned w[8];
    #pragma unroll
    for (int j = 0; j < 8; ++j)
      w[j] = (unsigned)f2b(t[tc+2*j][hd]) | ((unsigned)f2b(t[tc+2*j+1][hd])<<16);
    size_t off = ((size_t)bg*64 + hd)*1024 + t0 + tc;
    *(uint4*)&vt_bf[off]     = make_uint4(w[0],w[1],w[2],w[3]);
    *(uint4*)&vt_bf[off + 8] = make_uint4(w[4],w[5],w[6],w[7]);
  } else {
    const int bi = bb - 3840;            // 0..255
    const int bg = bi >> 2, tt4 = bi & 3;
    const int b = bg >> 2, g = bg & 3;
    const int t0 = 768 + tt4*64;
    unsigned short* ts = (unsigned short*)&t[0][0];   // reuse LDS, stride 68 shorts
    #pragma unroll
    for (int i = 0; i < 4; ++i) {
      int tr = (tid>>4) + i*16;          // token s = (t0-768) + tr
      uint2 v = *(const uint2*)&vnew[((size_t)(b*256 + (t0-768) + tr))*256 + g*64 + (tid&15)*4];
      const unsigned short* pv4 = (const unsigned short*)&v;
      ts[tr*68 + (tid&15)*4 + 0] = pv4[0];
      ts[tr*68 + (tid&15)*4 + 1] = pv4[1];
      ts[tr*68 + (tid&15)*4 + 2] = pv4[2];
      ts[tr*68 + (tid&15)*4 + 3] = pv4[3];
    }
    __syncthreads();
    const int hd = tid>>2, tc = (tid&3)*16;
    unsigned w[8];
    #pragma unroll
    for (int j = 0; j < 8; ++j)
      w[j] = (unsigned)ts[(tc+2*j)*68 + hd] | ((unsigned)ts[(tc+2*j+1)*68 + hd] << 16);
    size_t off = ((size_t)bg*64 + hd)*1024 + t0 + tc;
    *(uint4*)&vt_bf[off]     = make_uint4(w[0],w[1],w[2],w[3]);
    *(uint4*)&vt_bf[off + 8] = make_uint4(w[4],w[5],w[6],w[7]);
  }
}

// ======== fused flash attention, KVBLK=128, QBLK=128, exp2-domain softmax ========
// grid: b(16) * hh(8) * qt(2) = 256 blocks, 512 threads.
__global__ __launch_bounds__(512) void flash_attn(
    const unsigned short* __restrict__ q_bf,   // [B*256][512]
    const unsigned short* __restrict__ kf_bf,  // [bg][1024][64]
    const unsigned short* __restrict__ vt_bf,  // [bg][64hd][1024]
    const float* __restrict__ relt,            // [31][8]
    const float* __restrict__ relf,            // [127][8]
    unsigned short* __restrict__ att_bf)       // [B*256][512]
{
  int bx = (blockIdx.x & 7)*32 + (blockIdx.x >> 3);   // XCD-chunked swizzle (nwg=256)
  const int qt = bx & 1, hh = (bx>>1) & 7, b = bx >> 4;
  const int g = hh >> 1;
  const int tid = threadIdx.x, wave = tid>>6, lane = tid&63;
  const int lg = lane>>4, lq = lane&15;
  const int qloc = wave*16 + lq;         // 0..127
  const int q0 = qt*128;
  const int qtg = qt*2 + (wave>>2);      // query time tile in [0,4)

  __shared__ alignas(16) char Ks[2][16384];
  __shared__ alignas(16) char Vs[2][16384];

  const unsigned short* kfb  = kf_bf + (size_t)(b*4+g)*1024*64;
  const unsigned short* vtb2 = vt_bf + (size_t)(b*4+g)*64*1024;

  auto stage = [&](int buf, int t){
    #pragma unroll
    for (int it = 0; it < 2; ++it) {
      int slot = it*512 + tid;                 // 1024 slots each
      int kr = slot>>3, kp = slot&7,  ku = kp ^ (kr&7);
      gl_lds16(kfb + (size_t)(t*128 + kr)*64 + ku*8, Ks[buf] + slot*16);
      int vr = slot>>4, vp = slot&15, vu = vp ^ (vr&15);
      gl_lds16(vtb2 + (size_t)vr*1024 + t*128 + vu*8, Vs[buf] + slot*16);
    }
  };

  const unsigned short* qrow = q_bf + ((size_t)(b*256 + q0 + qloc))*512 + hh*64;
  bf16x8 qfrag[2];
  qfrag[0] = *(const bf16x8*)(qrow + lg*8);
  qfrag[1] = *(const bf16x8*)(qrow + 32 + lg*8);

  float bias_f[4][4];
  {
    int sq = qloc & 63;
    #pragma unroll
    for (int f = 0; f < 4; ++f)
      #pragma unroll
      for (int r = 0; r < 4; ++r)
        bias_f[f][r] = relf[((sq - (f*16 + lg*4 + r)) + 63)*8 + hh] * LOG2E;
  }
  const float scale2 = 0.125f * LOG2E;

  f32x4 ot[4] = {};
  float m_run = -1e30f, l_part = 0.f;

  stage(0, 0);
  __syncthreads();

  for (int t = 0; t < 8; ++t) {
    const int cur = t & 1;
    if (t + 1 < 8) stage(cur^1, t+1);

    f32x4 st[8] = {};
    __builtin_amdgcn_s_setprio(1);
    #pragma unroll
    for (int c = 0; c < 2; ++c)
      #pragma unroll
      for (int f = 0; f < 8; ++f) {
        int row = f*16 + lq;
        int pu = (c*4 + lg) ^ (row & 7);
        bf16x8 kf_ = *(const bf16x8*)(Ks[cur] + row*128 + pu*16);
        st[f] = __builtin_amdgcn_mfma_f32_16x16x32_bf16(kf_, qfrag[c], st[f], 0,0,0);
      }
    __builtin_amdgcn_s_setprio(0);

    const float bt0 = relt[(27 + qtg - 2*t)*8 + hh] * LOG2E;
    const float bt1 = relt[(27 + qtg - 2*t - 1)*8 + hh] * LOG2E;
    float mt = -1e30f;
    #pragma unroll
    for (int f = 0; f < 8; ++f) {
      const float bt = (f < 4) ? bt0 : bt1;
      #pragma unroll
      for (int r = 0; r < 4; ++r) {
        float v = st[f][r]*scale2 + bt + bias_f[f&3][r];
        st[f][r] = v;
        mt = fmaxf(mt, v);
      }
    }
    mt = fmaxf(mt, __shfl_xor(mt, 16, 64));
    mt = fmaxf(mt, __shfl_xor(mt, 32, 64));
    // T13 defer-max (log2 domain: 8*log2e)
    if (!__all(mt - m_run <= 11.5416f)) {
      const float m_new = fmaxf(m_run, mt);
      const float corr = exp2f(m_run - m_new);
      m_run = m_new;
      l_part *= corr;
      #pragma unroll
      for (int f = 0; f < 4; ++f) {
        ot[f][0] *= corr; ot[f][1] *= corr; ot[f][2] *= corr; ot[f][3] *= corr;
      }
    }
    float psum = 0.f;
    unsigned r01[8], r23[8];
    #pragma unroll
    for (int f = 0; f < 8; ++f) {
      float e0 = exp2f(st[f][0] - m_run);
      float e1 = exp2f(st[f][1] - m_run);
      float e2 = exp2f(st[f][2] - m_run);
      float e3 = exp2f(st[f][3] - m_run);
      psum += (e0+e1)+(e2+e3);
      r01[f] = (unsigned)f2b(e0) | ((unsigned)f2b(e1)<<16);
      r23[f] = (unsigned)f2b(e2) | ((unsigned)f2b(e3)<<16);
    }
    l_part += psum;

    const int src0 = (lg&1)*32 + lq;
    const int src1 = src0 + 16;
    const bool hi = (lg>>1) != 0;
    #pragma unroll
    for (int c = 0; c < 4; ++c) {
      unsigned a0 = (unsigned)__shfl((int)r01[c*2],   src0, 64);
      unsigned b0 = (unsigned)__shfl((int)r01[c*2+1], src0, 64);
      unsigned a1 = (unsigned)__shfl((int)r23[c*2],   src0, 64);
      unsigned b1 = (unsigned)__shfl((int)r23[c*2+1], src0, 64);
      unsigned a2 = (unsigned)__shfl((int)r01[c*2],   src1, 64);
      unsigned b2 = (unsigned)__shfl((int)r01[c*2+1], src1, 64);
      unsigned a3 = (unsigned)__shfl((int)r23[c*2],   src1, 64);
      unsigned b3 = (unsigned)__shfl((int)r23[c*2+1], src1, 64);
      uint4 bw;
      bw.x = hi ? b0 : a0;
      bw.y = hi ? b1 : a1;
      bw.z = hi ? b2 : a2;
      bw.w = hi ? b3 : a3;
      bf16x8 pfrag = *(bf16x8*)&bw;
      __builtin_amdgcn_s_setprio(1);
      #pragma unroll
      for (int f = 0; f < 4; ++f) {
        int row = f*16 + lq;
        int pu = (c*4 + lg) ^ (row & 15);
        bf16x8 vf_ = *(const bf16x8*)(Vs[cur] + row*256 + pu*16);
        ot[f] = __builtin_amdgcn_mfma_f32_16x16x32_bf16(vf_, pfrag, ot[f], 0,0,0);
      }
      __builtin_amdgcn_s_setprio(0);
    }
    __syncthreads();
  }

  float l_tot = l_part + __shfl_xor(l_part, 16, 64);
  l_tot += __shfl_xor(l_tot, 32, 64);
  const float inv = 1.0f / l_tot;
  unsigned short* orow = att_bf + ((size_t)(b*256 + q0 + qloc))*512 + hh*64;
  #pragma unroll
  for (int f = 0; f < 4; ++f) {
    uint2 w;
    w.x = (unsigned)f2b(ot[f][0]*inv) | ((unsigned)f2b(ot[f][1]*inv)<<16);
    w.y = (unsigned)f2b(ot[f][2]*inv) | ((unsigned)f2b(ot[f][3]*inv)<<16);
    *(uint2*)(orow + f*16 + lg*4) = w;
  }
}

// ================= FFN1: interleaved W1|W3 + SwiGLU =================
__global__ __launch_bounds__(256) void ffn1_gemm(
    const unsigned short* __restrict__ xin,
    const unsigned short* __restrict__ W1t, const unsigned short* __restrict__ W3t,
    const float* __restrict__ b1_, const float* __restrict__ b3_,
    unsigned short* __restrict__ ff_bf)
{
  __shared__ alignas(16) char As[2*128*64];
  __shared__ alignas(16) char Bs[2*128*64];
  f32x4 acc[16] = {};
  // Column-chunk XCD swizzle (nwg=1024): XCD k = bid&7 owns nt in [4k,4k+4),
  // so its B-slice (1 MB of W1t|W3t) and A (4 MB xin) are both L2-resident.
  const int bid = blockIdx.x;
  const int q = bid >> 3;
  int bx = (q >> 2)*32 + (bid & 7)*4 + (q & 3);
  const int nt = bx & 31, mt = bx >> 5;
  const int m0 = mt*128, n0 = nt*128;
  auto brow = [&](int r) -> const unsigned short* {
    int p = n0 + r;
    int pb = p >> 4;
    int j = ((pb>>1)<<4) | (p & 15);
    return (pb & 1) ? W3t + (size_t)j*512 : W1t + (size_t)j*512;
  };
  mfma_core<128,128,64,64>(xin, 512, m0, brow, 512, As, Bs, acc);
  const int lane = threadIdx.x & 63, wave = threadIdx.x >> 6;
  const int wr = wave >> 1, wc = wave & 1;
  #pragma unroll
  for (int r = 0; r < 4; ++r)
  #pragma unroll
  for (int cp = 0; cp < 4; cp += 2) {
    f32x4 va = acc[r*4+cp];
    f32x4 vb = acc[r*4+cp+1];
    #pragma unroll
    for (int reg = 0; reg < 4; ++reg) {
      int m = m0 + wr*64 + r*16 + ((lane>>4)<<2) + reg;
      int p = n0 + wc*64 + cp*16 + (lane&15);
      int j = ((p>>5)<<4) | (p & 15);
      float a = va[reg] + b1_[j];
      float bb = vb[reg] + b3_[j];
      float gval = (a / (1.0f + __expf(-a))) * bb;
      ff_bf[(size_t)m*2048 + j] = f2b(gval);
    }
  }
}

// ====== residual GEMM (64x64 tile, BK=64: two 32-k panels per barrier) ==========
__global__ __launch_bounds__(256) void res_gemm(
    const unsigned short* __restrict__ A, int lda,
    const unsigned short* __restrict__ Wt, int kd,
    const float* __restrict__ bias, const float* __restrict__ resv,
    float* __restrict__ h)
{
  __shared__ alignas(16) char As[4][64*64];
  __shared__ alignas(16) char Bs[4][64*64];
  f32x4 acc[4] = {};
  int bx = (blockIdx.x & 7)*64 + (blockIdx.x >> 3);   // XCD-chunked swizzle (nwg=512)
  const int mt = bx >> 3, nt = bx & 7;
  const int m0 = mt*64, n0 = nt*64;
  const int tid = threadIdx.x, wave = tid>>6, lane = tid&63;
  const int wr = wave >> 1, wc = wave & 1;
  const int lr = lane>>2;
  const int swl = (lane&3) ^ ((lane>>2)&3) ^ (lane>>4);

  auto stageP = [&](int slot, int k0){
    gl_lds16(A  + (size_t)(m0 + wave*16 + lr)*lda + k0 + swl*8, As[slot] + wave*1024);
    gl_lds16(Wt + (size_t)(n0 + wave*16 + lr)*kd  + k0 + swl*8, Bs[slot] + wave*1024);
  };

  stageP(0, 0);
  stageP(1, 32);
  __syncthreads();
  int cur = 0;
  for (int k0 = 0; k0 < kd; k0 += 64) {
    if (k0 + 64 < kd) { stageP((cur^1)*2, k0+64); stageP((cur^1)*2+1, k0+96); }
    #pragma unroll
    for (int p = 0; p < 2; ++p) {
      const char* ab = As[cur*2+p];
      const char* bb = Bs[cur*2+p];
      bf16x8 af[2], bfv[2];
      #pragma unroll
      for (int r = 0; r < 2; ++r)
        af[r] = *(const bf16x8*)(ab + (wr*32 + r*16 + (lane&15))*64 + swl*16);
      #pragma unroll
      for (int c = 0; c < 2; ++c)
        bfv[c] = *(const bf16x8*)(bb + (wc*32 + c*16 + (lane&15))*64 + swl*16);
      #pragma unroll
      for (int r = 0; r < 2; ++r)
        #pragma unroll
        for (int c = 0; c < 2; ++c)
          acc[r*2+c] = __builtin_amdgcn_mfma_f32_16x16x32_bf16(af[r], bfv[c], acc[r*2+c], 0,0,0);
    }
    __syncthreads();
    cur ^= 1;
  }

  const float rv = resv[0];
  #pragma unroll
  for (int r = 0; r < 2; ++r)
  #pragma unroll
  for (int c = 0; c < 2; ++c) {
    f32x4 v = acc[r*2+c];
    #pragma unroll
    for (int reg = 0; reg < 4; ++reg) {
      int m = m0 + wr*32 + r*16 + ((lane>>4)<<2) + reg;
      int n = n0 + wc*32 + c*16 + (lane&15);
      h[(size_t)m*512 + n] += rv * (v[reg] + bias[n]);
    }
  }
}

// ================= output projection + unpatchify (f32) =================
__global__ __launch_bounds__(256) void outproj_kernel(
    const float* __restrict__ h, const float* __restrict__ outW,
    const float* __restrict__ outb, float* __restrict__ y)
{
  int bs = blockIdx.x;
  int b = bs >> 8, s = bs & 255;
  int tic = s >> 6, mf = s & 63;
  __shared__ float hr[512];
  __shared__ float part[8][32];
  int tid = threadIdx.x;
  hr[tid]     = h[(size_t)bs*D_ + tid];
  hr[tid+256] = h[(size_t)bs*D_ + tid + 256];
  __syncthreads();
  int i = tid & 31, seg = tid >> 5;
  float acc = 0.0f;
  #pragma unroll
  for (int k = 0; k < 64; ++k) acc += hr[seg*64 + k] * outW[(seg*64 + k)*32 + i];
  part[seg][i] = acc;
  __syncthreads();
  if (tid < 32) {
    float v = outb[tid];
    #pragma unroll
    for (int s2 = 0; s2 < 8; ++s2) v += part[s2][tid];
    int tp = tid >> 3, fp = (tid >> 1) & 3, c = tid & 1;
    y[((size_t)(b*2 + c)*16 + tic*4 + tp)*256 + mf*4 + fp] = v;
  }
}

// ================= launch =================
extern "C" void kernel_launch(void* const* d_in, const int* in_sizes, int n_in,
                              void* d_out, int out_size, void* d_ws, size_t ws_size,
                              hipStream_t stream) {
  (void)in_sizes; (void)n_in; (void)out_size; (void)ws_size;
  const float* x        = (const float*)d_in[0];
  const float* cache_k  = (const float*)d_in[1];
  const float* cache_v  = (const float*)d_in[2];
  const float* in_W     = (const float*)d_in[3];
  const float* in_b     = (const float*)d_in[4];
  const float* ln1_g    = (const float*)d_in[5];
  const float* ln1_b    = (const float*)d_in[6];
  const float* Wq       = (const float*)d_in[7];
  const float* bq       = (const float*)d_in[8];
  const float* Wk       = (const float*)d_in[9];
  const float* bk       = (const float*)d_in[10];
  const float* Wv       = (const float*)d_in[11];
  const float* bv       = (const float*)d_in[12];
  const float* Wo       = (const float*)d_in[13];
  const float* bo       = (const float*)d_in[14];
  const float* rel_time = (const float*)d_in[15];
  const float* rel_freq = (const float*)d_in[16];
  const float* res_a    = (const float*)d_in[17];
  const float* ln2_g    = (const float*)d_in[18];
  const float* ln2_b    = (const float*)d_in[19];
  const float* W1       = (const float*)d_in[20];
  const float* b1       = (const float*)d_in[21];
  const float* W3       = (const float*)d_in[22];
  const float* b3       = (const float*)d_in[23];
  const float* W2       = (const float*)d_in[24];
  const float* b2       = (const float*)d_in[25];
  const float* res_f    = (const float*)d_in[26];
  const float* out_W    = (const float*)d_in[27];
  const float* out_b    = (const float*)d_in[28];

  char* ws = (char*)d_ws;
  size_t o = 0;
  float* h            = (float*)(ws + o);          o += (size_t)4096*512*4;
  unsigned short* xin = (unsigned short*)(ws + o); o += (size_t)4096*512*2;
  unsigned short* qb  = (unsigned short*)(ws + o); o += (size_t)4096*512*2;
  unsigned short* att = (unsigned short*)(ws + o); o += (size_t)4096*512*2;
  unsigned short* kfb = (unsigned short*)(ws + o); o += (size_t)64*1024*64*2;
  unsigned short* vtb = (unsigned short*)(ws + o); o += (size_t)64*64*1024*2;
  unsigned short* vnw = (unsigned short*)(ws + o); o += (size_t)4096*256*2;
  float* smean        = (float*)(ws + o);          o += (size_t)4096*4;
  float* srstd        = (float*)(ws + o);          o += (size_t)4096*4;
  unsigned short* Wqt = (unsigned short*)(ws + o); o += (size_t)4*512*512*2;
  unsigned short* Wkt = (unsigned short*)(ws + o); o += (size_t)4*256*512*2;
  unsigned short* Wvt = (unsigned short*)(ws + o); o += (size_t)4*256*512*2;
  unsigned short* Wot = (unsigned short*)(ws + o); o += (size_t)4*512*512*2;
  unsigned short* W1t = (unsigned short*)(ws + o); o += (size_t)4*2048*512*2;
  unsigned short* W3t = (unsigned short*)(ws + o); o += (size_t)4*2048*512*2;
  unsigned short* W2t = (unsigned short*)(ws + o); o += (size_t)4*512*2048*2;
  unsigned short* ffb = (unsigned short*)(ws + o);

  float* y    = (float*)d_out;
  float* nck0 = y + 131072;
  float* ncv0 = nck0 + 12582912;

  transpose_all<<<3840, 256, 0, stream>>>(Wq, Wk, Wv, Wo, W1, W3, W2,
                                          Wqt, Wkt, Wvt, Wot, W1t, W3t, W2t);

  patchify_inproj<<<256, 256, 0, stream>>>(x, in_W, in_b, h);

  for (int l = 0; l < L_; ++l) {
    ln_stats<<<256, 256, 0, stream>>>(h, smean, srstd);
    qkv_ln_gemm<<<512, 256, 0, stream>>>(
        h, smean, srstd, ln1_g + l*512, ln1_b + l*512,
        Wqt + (size_t)l*512*512, Wkt + (size_t)l*256*512, Wvt + (size_t)l*256*512,
        bq + l*512, bk + l*256, bv + l*256,
        qb, kfb, vnw, nck0 + (size_t)l*3145728, ncv0 + (size_t)l*3145728);
    merge_kv<<<4096, 256, 0, stream>>>(
        cache_k + (size_t)l*3145728, cache_v + (size_t)l*3145728, vnw,
        kfb, vtb, nck0 + (size_t)l*3145728, ncv0 + (size_t)l*3145728);
    flash_attn<<<256, 512, 0, stream>>>(qb, kfb, vtb,
        rel_time + l*31*8, rel_freq + l*127*8, att);
    res_gemm<<<512, 256, 0, stream>>>(att, 512, Wot + (size_t)l*512*512, 512,
                                      bo + l*512, res_a + l, h);
    ln_kernel<<<256, 256, 0, stream>>>(h, xin, ln2_g + l*512, ln2_b + l*512);
    ffn1_gemm<<<1024, 256, 0, stream>>>(
        xin, W1t + (size_t)l*2048*512, W3t + (size_t)l*2048*512,
        b1 + l*2048, b3 + l*2048, ffb);
    res_gemm<<<512, 256, 0, stream>>>(ffb, 2048, W2t + (size_t)l*512*2048, 2048,
                                      b2 + l*512, res_f + l, h);
  }

  outproj_kernel<<<M_, 256, 0, stream>>>(h, out_W, out_b, y);
}

// Round 20
// 591.655 us; speedup vs baseline: 1.0301x; 1.0076x over previous
//
#include <hip/hip_runtime.h>
#include <stdint.h>

typedef __attribute__((ext_vector_type(8))) short bf16x8;
typedef __attribute__((ext_vector_type(4))) float f32x4;

// ---- problem dims ----
#define B_    16
#define S_    256
#define LEFT_ 768
#define KT_   1024
#define D_    512
#define H_    8
#define G_    4
#define HD_   64
#define L_    4
#define FFH_  2048
#define M_    4096   // B*S
#define LOG2E 1.44269504f

__device__ __forceinline__ unsigned short f2b(float f){
  unsigned u = __float_as_uint(f);
  u += 0x7fffu + ((u>>16)&1u);
  return (unsigned short)(u>>16);
}

__device__ __forceinline__ void gl_lds16(const unsigned short* g, void* l){
  __builtin_amdgcn_global_load_lds(
    (const __attribute__((address_space(1))) unsigned int*)g,
    (__attribute__((address_space(3))) unsigned int*)l, 16, 0, 0);
}

// ================= MFMA GEMM core (NT layout), double-buffered, BK=32 ============
template<int BM, int BN, int WM, int WN, class BRowF>
__device__ __forceinline__ void mfma_core(
    const unsigned short* Abase, int lda, int m0, BRowF brow,
    int kd, char* As, char* Bs, f32x4* acc)
{
  constexpr int FR = WM/16, FC = WN/16;
  constexpr int NWC = BN/WN;
  constexpr int CA = BM/64, CB = BN/64;
  const int tid = threadIdx.x, wave = tid>>6, lane = tid&63;
  const int wr = wave / NWC, wc = wave % NWC;
  const int lr = lane>>2;
  const int swl = (lane&3) ^ ((lane>>2)&3) ^ (lane>>4);

  auto stage = [&](int buf, int k0){
    #pragma unroll
    for (int i = 0; i < CA; ++i) {
      const int chunk = wave*CA + i;
      const unsigned short* gp = Abase + (size_t)(m0 + chunk*16 + lr)*lda + k0 + swl*8;
      gl_lds16(gp, As + buf*(BM*64) + chunk*1024);
    }
    #pragma unroll
    for (int i = 0; i < CB; ++i) {
      const int chunk = wave*CB + i;
      const unsigned short* gp = brow(chunk*16 + lr) + k0 + swl*8;
      gl_lds16(gp, Bs + buf*(BN*64) + chunk*1024);
    }
  };

  stage(0, 0);
  __syncthreads();
  int cur = 0;
  for (int k0 = 0; k0 < kd; k0 += 32) {
    if (k0 + 32 < kd) stage(cur^1, k0 + 32);
    bf16x8 af[FR], bfr[FC];
    #pragma unroll
    for (int r = 0; r < FR; ++r)
      af[r] = *(const bf16x8*)(As + cur*(BM*64) + (wr*WM + r*16 + (lane&15))*64 + swl*16);
    #pragma unroll
    for (int c = 0; c < FC; ++c)
      bfr[c] = *(const bf16x8*)(Bs + cur*(BN*64) + (wc*WN + c*16 + (lane&15))*64 + swl*16);
    #pragma unroll
    for (int r = 0; r < FR; ++r)
      #pragma unroll
      for (int c = 0; c < FC; ++c)
        acc[r*FC+c] = __builtin_amdgcn_mfma_f32_16x16x32_bf16(af[r], bfr[c], acc[r*FC+c], 0, 0, 0);
    __syncthreads();
    cur ^= 1;
  }
}

// ================= unified weight transpose+convert =================
__device__ __forceinline__ void tcvt_body(
    const float* __restrict__ src, unsigned short* __restrict__ dst,
    int K, int N, int ntk, int ntn, int bx)
{
  __shared__ float t[64][65];
  int kt = bx % ntk; int nt = (bx/ntk) % ntn; int l = bx/(ntk*ntn);
  src += (size_t)l*K*N; dst += (size_t)l*N*K;
  const int k0 = kt*64, n0 = nt*64;
  const int tid = threadIdx.x;
  #pragma unroll
  for (int i = 0; i < 4; ++i) {
    int kr = (tid>>4) + i*16;
    const float4 v = *(const float4*)&src[(size_t)(k0+kr)*N + n0 + (tid&15)*4];
    t[kr][(tid&15)*4+0]=v.x; t[kr][(tid&15)*4+1]=v.y;
    t[kr][(tid&15)*4+2]=v.z; t[kr][(tid&15)*4+3]=v.w;
  }
  __syncthreads();
  const int nn = tid>>2, kk = (tid&3)*16;
  unsigned w[8];
  #pragma unroll
  for (int j = 0; j < 8; ++j)
    w[j] = (unsigned)f2b(t[kk+2*j][nn]) | ((unsigned)f2b(t[kk+2*j+1][nn])<<16);
  size_t off = (size_t)(n0+nn)*K + k0 + kk;
  *(uint4*)&dst[off]     = make_uint4(w[0],w[1],w[2],w[3]);
  *(uint4*)&dst[off + 8] = make_uint4(w[4],w[5],w[6],w[7]);
}

__global__ __launch_bounds__(256) void transpose_all(
    const float* __restrict__ Wq, const float* __restrict__ Wk,
    const float* __restrict__ Wv, const float* __restrict__ Wo,
    const float* __restrict__ W1, const float* __restrict__ W3,
    const float* __restrict__ W2,
    unsigned short* __restrict__ Wqt, unsigned short* __restrict__ Wkt,
    unsigned short* __restrict__ Wvt, unsigned short* __restrict__ Wot,
    unsigned short* __restrict__ W1t, unsigned short* __restrict__ W3t,
    unsigned short* __restrict__ W2t)
{
  int bx = blockIdx.x;
  if      (bx < 256)  tcvt_body(Wq, Wqt, 512, 512, 8, 8,  bx);
  else if (bx < 384)  tcvt_body(Wk, Wkt, 512, 256, 8, 4,  bx-256);
  else if (bx < 512)  tcvt_body(Wv, Wvt, 512, 256, 8, 4,  bx-384);
  else if (bx < 768)  tcvt_body(Wo, Wot, 512, 512, 8, 8,  bx-512);
  else if (bx < 1792) tcvt_body(W1, W1t, 512, 2048, 8, 32, bx-768);
  else if (bx < 2816) tcvt_body(W3, W3t, 512, 2048, 8, 32, bx-1792);
  else                tcvt_body(W2, W2t, 2048, 512, 32, 8, bx-2816);
}

// ======= patchify + input projection: 16 tokens/block, inW staged in LDS =======
__global__ __launch_bounds__(256) void patchify_inproj(
    const float* __restrict__ x, const float* __restrict__ inW,
    const float* __restrict__ inb, float* __restrict__ h)
{
  __shared__ float wlds[32*512];
  __shared__ float ps[16][33];
  const int tid = threadIdx.x;
  const int tb = blockIdx.x*16;

  #pragma unroll
  for (int i = 0; i < 16; ++i)
    ((float4*)wlds)[i*256 + tid] = ((const float4*)inW)[i*256 + tid];
  {
    int tok = tid >> 5, idx = tid & 31;
    int bs = tb + tok;
    int b = bs >> 8, s = bs & 255;
    int tic = s >> 6, mf = s & 63;
    int tp = idx >> 3, fp = (idx >> 1) & 3, c = idx & 1;
    ps[tok][idx] = x[((size_t)(b*2 + c)*16 + tic*4 + tp)*256 + mf*4 + fp];
    int tok2 = tok + 8;
    int bs2 = tb + tok2;
    int b2 = bs2 >> 8, s2 = bs2 & 255;
    int tic2 = s2 >> 6, mf2 = s2 & 63;
    ps[tok2][idx] = x[((size_t)(b2*2 + c)*16 + tic2*4 + tp)*256 + mf2*4 + fp];
  }
  __syncthreads();

  const int g = tid >> 4, qd = tid & 15;
  const int bs = tb + g;
  for (int j = 0; j < 32; ++j) {
    int d = j*16 + qd;
    float acc = inb[d];
    #pragma unroll
    for (int i = 0; i < 32; ++i) acc += ps[g][i] * wlds[i*512 + d];
    h[(size_t)bs*512 + d] = acc;
  }
}

// ================= LN1 row stats (one pass over h) =================
__global__ __launch_bounds__(256) void ln_stats(
    const float* __restrict__ h, float* __restrict__ smean, float* __restrict__ srstd)
{
  const int tid = threadIdx.x;
  const int row = blockIdx.x*16 + (tid>>4);
  const int qd = tid & 15;
  const float* rp = h + (size_t)row*512 + qd*32;
  float s = 0.f, sq = 0.f;
  #pragma unroll
  for (int i = 0; i < 8; ++i) {
    float4 v = ((const float4*)rp)[i];
    s  += (v.x+v.y)+(v.z+v.w);
    sq += (v.x*v.x+v.y*v.y)+(v.z*v.z+v.w*v.w);
  }
  #pragma unroll
  for (int o = 1; o < 16; o <<= 1) { s += __shfl_xor(s,o,64); sq += __shfl_xor(sq,o,64); }
  if (qd == 0) {
    float mean = s*(1.f/512.f);
    smean[row] = mean;
    srstd[row] = rsqrtf(sq*(1.f/512.f) - mean*mean + 1e-5f);
  }
}

// ================= lean layernorm f32 -> bf16 (ln2): 16 rows/block =============
__global__ __launch_bounds__(256) void ln_kernel(
    const float* __restrict__ in, unsigned short* __restrict__ out,
    const float* __restrict__ g, const float* __restrict__ bta)
{
  const int tid = threadIdx.x;
  const int row = blockIdx.x*16 + (tid>>4);
  const int qd = tid & 15;
  const float* rp = in + (size_t)row*512 + qd*32;
  float4 xv[8];
  float s = 0.f, sq = 0.f;
  #pragma unroll
  for (int i = 0; i < 8; ++i) {
    xv[i] = ((const float4*)rp)[i];
    s  += (xv[i].x+xv[i].y)+(xv[i].z+xv[i].w);
    sq += (xv[i].x*xv[i].x + xv[i].y*xv[i].y)+(xv[i].z*xv[i].z + xv[i].w*xv[i].w);
  }
  #pragma unroll
  for (int o = 1; o < 16; o <<= 1) { s += __shfl_xor(s,o,64); sq += __shfl_xor(sq,o,64); }
  const float mean = s*(1.f/512.f);
  const float rstd = rsqrtf(sq*(1.f/512.f) - mean*mean + 1e-5f);
  const float* gp = g + qd*32;
  const float* bp = bta + qd*32;
  unsigned short* op = out + (size_t)row*512 + qd*32;
  #pragma unroll
  for (int i = 0; i < 4; ++i) {
    float4 a  = xv[2*i],                 b2 = xv[2*i+1];
    float4 ga = ((const float4*)gp)[2*i], gb = ((const float4*)gp)[2*i+1];
    float4 ba = ((const float4*)bp)[2*i], bb = ((const float4*)bp)[2*i+1];
    unsigned w0 = (unsigned)f2b((a.x-mean)*rstd*ga.x + ba.x) | ((unsigned)f2b((a.y-mean)*rstd*ga.y + ba.y)<<16);
    unsigned w1 = (unsigned)f2b((a.z-mean)*rstd*ga.z + ba.z) | ((unsigned)f2b((a.w-mean)*rstd*ga.w + ba.w)<<16);
    unsigned w2 = (unsigned)f2b((b2.x-mean)*rstd*gb.x + bb.x) | ((unsigned)f2b((b2.y-mean)*rstd*gb.y + bb.y)<<16);
    unsigned w3 = (unsigned)f2b((b2.z-mean)*rstd*gb.z + bb.z) | ((unsigned)f2b((b2.w-mean)*rstd*gb.w + bb.w)<<16);
    *(uint4*)(op + i*8) = make_uint4(w0,w1,w2,w3);
  }
}

// ================= QKV GEMM with fused LN1 (stats precomputed) ==============
__global__ __launch_bounds__(256) void qkv_ln_gemm(
    const float* __restrict__ h,
    const float* __restrict__ smean, const float* __restrict__ srstd,
    const float* __restrict__ lng, const float* __restrict__ lnb,
    const unsigned short* __restrict__ Wqt, const unsigned short* __restrict__ Wkt,
    const unsigned short* __restrict__ Wvt,
    const float* __restrict__ bq, const float* __restrict__ bk_, const float* __restrict__ bv_,
    unsigned short* __restrict__ q_bf, unsigned short* __restrict__ kf_bf,
    unsigned short* __restrict__ vnew, float* __restrict__ nck, float* __restrict__ ncv)
{
  __shared__ alignas(16) char As[2][64*64];
  __shared__ alignas(16) char Bs[2][128*64];
  int bx = (blockIdx.x & 7)*64 + (blockIdx.x >> 3);   // XCD-chunked swizzle (nwg=512)
  const int mt = bx >> 3, nt = bx & 7;
  const int m0 = mt*64, n0 = nt*128;
  const int tid = threadIdx.x, wave = tid>>6, lane = tid&63;

  const int ar = tid >> 2, au = tid & 3;
  const int ap = au ^ (ar&3) ^ ((ar>>2)&3);
  const float* arow = h + (size_t)(m0 + ar)*512;
  const float mean_r = smean[m0 + ar];
  const float rstd_r = srstd[m0 + ar];

  const int lr = lane>>2;
  const int swl = (lane&3) ^ ((lane>>2)&3) ^ (lane>>4);
  auto brow = [&](int rr) -> const unsigned short* {
    int n = n0 + rr;
    return n < 512 ? Wqt + (size_t)n*512
         : n < 768 ? Wkt + (size_t)(n-512)*512
                   : Wvt + (size_t)(n-768)*512;
  };
  auto stageB = [&](int buf, int k0){
    #pragma unroll
    for (int i = 0; i < 2; ++i) {
      const int chunk = wave*2 + i;
      gl_lds16(brow(chunk*16+lr) + k0 + swl*8, (char*)Bs[buf] + chunk*1024);
    }
  };

  float4 av[6];
  auto loadA = [&](int k0){
    av[0] = *(const float4*)(arow + k0 + au*8);
    av[1] = *(const float4*)(arow + k0 + au*8 + 4);
    av[2] = *(const float4*)(lng  + k0 + au*8);
    av[3] = *(const float4*)(lng  + k0 + au*8 + 4);
    av[4] = *(const float4*)(lnb  + k0 + au*8);
    av[5] = *(const float4*)(lnb  + k0 + au*8 + 4);
  };
  auto writeA = [&](int buf){
    const float* xv = (const float*)&av[0];
    const float* gv = (const float*)&av[2];
    const float* bv2 = (const float*)&av[4];
    unsigned w[4];
    #pragma unroll
    for (int j = 0; j < 4; ++j) {
      float e0 = (xv[2*j]   - mean_r)*rstd_r*gv[2*j]   + bv2[2*j];
      float e1 = (xv[2*j+1] - mean_r)*rstd_r*gv[2*j+1] + bv2[2*j+1];
      w[j] = (unsigned)f2b(e0) | ((unsigned)f2b(e1)<<16);
    }
    *(uint4*)((char*)As[buf] + ar*64 + ap*16) = make_uint4(w[0],w[1],w[2],w[3]);
  };

  loadA(0);
  stageB(0, 0);
  writeA(0);
  __syncthreads();

  f32x4 acc[8] = {};
  const int wr = wave >> 1, wc = wave & 1;
  for (int k0 = 0; k0 < 512; k0 += 32) {
    const int cur = (k0>>5)&1;
    const bool more = (k0 + 32 < 512);
    if (more) { stageB(cur^1, k0+32); loadA(k0+32); }
    bf16x8 af[2], bfv[4];
    #pragma unroll
    for (int r = 0; r < 2; ++r)
      af[r] = *(const bf16x8*)((char*)As[cur] + (wr*32 + r*16 + (lane&15))*64 + swl*16);
    #pragma unroll
    for (int c = 0; c < 4; ++c)
      bfv[c] = *(const bf16x8*)((char*)Bs[cur] + (wc*64 + c*16 + (lane&15))*64 + swl*16);
    #pragma unroll
    for (int r = 0; r < 2; ++r)
      #pragma unroll
      for (int c = 0; c < 4; ++c)
        acc[r*4+c] = __builtin_amdgcn_mfma_f32_16x16x32_bf16(af[r], bfv[c], acc[r*4+c], 0,0,0);
    if (more) writeA(cur^1);
    __syncthreads();
  }

  #pragma unroll
  for (int r = 0; r < 2; ++r)
  #pragma unroll
  for (int c = 0; c < 4; ++c) {
    f32x4 v = acc[r*4+c];
    #pragma unroll
    for (int reg = 0; reg < 4; ++reg) {
      int m = m0 + wr*32 + r*16 + ((lane>>4)<<2) + reg;
      int n = n0 + wc*64 + c*16 + (lane&15);
      float val = v[reg];
      int b = m >> 8, s = m & 255;
      if (n < 512) {
        q_bf[(size_t)m*512 + n] = f2b(val + bq[n]);
      } else if (n < 768) {
        int g = (n-512) >> 6, hd = n & 63;
        float kv = val + bk_[n-512];
        kf_bf[((size_t)(b*4+g)*1024 + 768 + s)*64 + hd] = f2b(kv);
        nck [((size_t)(b*4+g)*768  + 512 + s)*64 + hd] = kv;
      } else {
        int g = (n-768) >> 6, hd = n & 63;
        float vv = val + bv_[n-768];
        vnew[(size_t)m*256 + (n-768)] = f2b(vv);     // coalesced (consecutive n)
        ncv [((size_t)(b*4+g)*768 + 512 + s)*64 + hd] = vv;
      }
    }
  }
}

// ================= fused cache merge + new-V transpose =================
__global__ __launch_bounds__(256) void merge_kv(
    const float* __restrict__ ck, const float* __restrict__ cv,
    const unsigned short* __restrict__ vnew,
    unsigned short* __restrict__ kf_bf, unsigned short* __restrict__ vt_bf,
    float* __restrict__ nck, float* __restrict__ ncv)
{
  __shared__ float t[64][65];
  const int bb = blockIdx.x;
  const int tid = threadIdx.x;
  if (bb < 3072) {
    size_t idx = (size_t)bb*256 + tid;
    int hd4 = idx & 15;
    size_t tt = (idx >> 4) % 768;
    size_t bg = idx / (16*768);
    const float4 v = ((const float4*)ck)[idx];
    uint2 pk;
    pk.x = (unsigned)f2b(v.x) | ((unsigned)f2b(v.y)<<16);
    pk.y = (unsigned)f2b(v.z) | ((unsigned)f2b(v.w)<<16);
    *(uint2*)&kf_bf[((bg*1024 + tt)*64) + hd4*4] = pk;
    if (tt >= 256)
      ((float4*)nck)[(bg*768 + (tt-256))*16 + hd4] = v;
  } else if (bb < 3840) {
    const int bi = bb - 3072;
    const int bg = bi / 12, tt = bi % 12;
    const int t0 = tt*64;
    #pragma unroll
    for (int i = 0; i < 4; ++i) {
      int tr = (tid>>4) + i*16;
      const float4 v = ((const float4*)cv)[((size_t)bg*768 + t0+tr)*16 + (tid&15)];
      t[tr][(tid&15)*4+0]=v.x; t[tr][(tid&15)*4+1]=v.y;
      t[tr][(tid&15)*4+2]=v.z; t[tr][(tid&15)*4+3]=v.w;
      if (t0+tr >= 256)
        ((float4*)ncv)[((size_t)bg*768 + t0+tr-256)*16 + (tid&15)] = v;
    }
    __syncthreads();
    const int hd = tid>>2, tc = (tid&3)*16;
    unsigned w[8];
    #pragma unroll
    for (int j = 0; j < 8; ++j)
      w[j] = (unsigned)f2b(t[tc+2*j][hd]) | ((unsigned)f2b(t[tc+2*j+1][hd])<<16);
    size_t off = ((size_t)bg*64 + hd)*1024 + t0 + tc;
    *(uint4*)&vt_bf[off]     = make_uint4(w[0],w[1],w[2],w[3]);
    *(uint4*)&vt_bf[off + 8] = make_uint4(w[4],w[5],w[6],w[7]);
  } else {
    const int bi = bb - 3840;            // 0..255
    const int bg = bi >> 2, tt4 = bi & 3;
    const int b = bg >> 2, g = bg & 3;
    const int t0 = 768 + tt4*64;
    unsigned short* ts = (unsigned short*)&t[0][0];   // reuse LDS, stride 68 shorts
    #pragma unroll
    for (int i = 0; i < 4; ++i) {
      int tr = (tid>>4) + i*16;          // token s = (t0-768) + tr
      uint2 v = *(const uint2*)&vnew[((size_t)(b*256 + (t0-768) + tr))*256 + g*64 + (tid&15)*4];
      const unsigned short* pv4 = (const unsigned short*)&v;
      ts[tr*68 + (tid&15)*4 + 0] = pv4[0];
      ts[tr*68 + (tid&15)*4 + 1] = pv4[1];
      ts[tr*68 + (tid&15)*4 + 2] = pv4[2];
      ts[tr*68 + (tid&15)*4 + 3] = pv4[3];
    }
    __syncthreads();
    const int hd = tid>>2, tc = (tid&3)*16;
    unsigned w[8];
    #pragma unroll
    for (int j = 0; j < 8; ++j)
      w[j] = (unsigned)ts[(tc+2*j)*68 + hd] | ((unsigned)ts[(tc+2*j+1)*68 + hd] << 16);
    size_t off = ((size_t)bg*64 + hd)*1024 + t0 + tc;
    *(uint4*)&vt_bf[off]     = make_uint4(w[0],w[1],w[2],w[3]);
    *(uint4*)&vt_bf[off + 8] = make_uint4(w[4],w[5],w[6],w[7]);
  }
}

// ======== fused flash attention, KVBLK=128, QBLK=128, exp2-domain softmax ========
// grid: b(16) * hh(8) * qt(2) = 256 blocks, 512 threads.
__global__ __launch_bounds__(512) void flash_attn(
    const unsigned short* __restrict__ q_bf,   // [B*256][512]
    const unsigned short* __restrict__ kf_bf,  // [bg][1024][64]
    const unsigned short* __restrict__ vt_bf,  // [bg][64hd][1024]
    const float* __restrict__ relt,            // [31][8]
    const float* __restrict__ relf,            // [127][8]
    unsigned short* __restrict__ att_bf)       // [B*256][512]
{
  int bx = (blockIdx.x & 7)*32 + (blockIdx.x >> 3);   // XCD-chunked swizzle (nwg=256)
  const int qt = bx & 1, hh = (bx>>1) & 7, b = bx >> 4;
  const int g = hh >> 1;
  const int tid = threadIdx.x, wave = tid>>6, lane = tid&63;
  const int lg = lane>>4, lq = lane&15;
  const int qloc = wave*16 + lq;         // 0..127
  const int q0 = qt*128;
  const int qtg = qt*2 + (wave>>2);      // query time tile in [0,4)

  __shared__ alignas(16) char Ks[2][16384];
  __shared__ alignas(16) char Vs[2][16384];

  const unsigned short* kfb  = kf_bf + (size_t)(b*4+g)*1024*64;
  const unsigned short* vtb2 = vt_bf + (size_t)(b*4+g)*64*1024;

  auto stage = [&](int buf, int t){
    #pragma unroll
    for (int it = 0; it < 2; ++it) {
      int slot = it*512 + tid;                 // 1024 slots each
      int kr = slot>>3, kp = slot&7,  ku = kp ^ (kr&7);
      gl_lds16(kfb + (size_t)(t*128 + kr)*64 + ku*8, Ks[buf] + slot*16);
      int vr = slot>>4, vp = slot&15, vu = vp ^ (vr&15);
      gl_lds16(vtb2 + (size_t)vr*1024 + t*128 + vu*8, Vs[buf] + slot*16);
    }
  };

  const unsigned short* qrow = q_bf + ((size_t)(b*256 + q0 + qloc))*512 + hh*64;
  bf16x8 qfrag[2];
  qfrag[0] = *(const bf16x8*)(qrow + lg*8);
  qfrag[1] = *(const bf16x8*)(qrow + 32 + lg*8);

  float bias_f[4][4];
  {
    int sq = qloc & 63;
    #pragma unroll
    for (int f = 0; f < 4; ++f)
      #pragma unroll
      for (int r = 0; r < 4; ++r)
        bias_f[f][r] = relf[((sq - (f*16 + lg*4 + r)) + 63)*8 + hh] * LOG2E;
  }
  const float scale2 = 0.125f * LOG2E;

  f32x4 ot[4] = {};
  float m_run = -1e30f, l_part = 0.f;

  stage(0, 0);
  __syncthreads();

  for (int t = 0; t < 8; ++t) {
    const int cur = t & 1;
    if (t + 1 < 8) stage(cur^1, t+1);

    f32x4 st[8] = {};
    __builtin_amdgcn_s_setprio(1);
    #pragma unroll
    for (int c = 0; c < 2; ++c)
      #pragma unroll
      for (int f = 0; f < 8; ++f) {
        int row = f*16 + lq;
        int pu = (c*4 + lg) ^ (row & 7);
        bf16x8 kf_ = *(const bf16x8*)(Ks[cur] + row*128 + pu*16);
        st[f] = __builtin_amdgcn_mfma_f32_16x16x32_bf16(kf_, qfrag[c], st[f], 0,0,0);
      }
    __builtin_amdgcn_s_setprio(0);

    const float bt0 = relt[(27 + qtg - 2*t)*8 + hh] * LOG2E;
    const float bt1 = relt[(27 + qtg - 2*t - 1)*8 + hh] * LOG2E;
    float mt = -1e30f;
    #pragma unroll
    for (int f = 0; f < 8; ++f) {
      const float bt = (f < 4) ? bt0 : bt1;
      #pragma unroll
      for (int r = 0; r < 4; ++r) {
        float v = st[f][r]*scale2 + bt + bias_f[f&3][r];
        st[f][r] = v;
        mt = fmaxf(mt, v);
      }
    }
    mt = fmaxf(mt, __shfl_xor(mt, 16, 64));
    mt = fmaxf(mt, __shfl_xor(mt, 32, 64));
    // T13 defer-max (log2 domain: 8*log2e)
    if (!__all(mt - m_run <= 11.5416f)) {
      const float m_new = fmaxf(m_run, mt);
      const float corr = exp2f(m_run - m_new);
      m_run = m_new;
      l_part *= corr;
      #pragma unroll
      for (int f = 0; f < 4; ++f) {
        ot[f][0] *= corr; ot[f][1] *= corr; ot[f][2] *= corr; ot[f][3] *= corr;
      }
    }
    float psum = 0.f;
    unsigned r01[8], r23[8];
    #pragma unroll
    for (int f = 0; f < 8; ++f) {
      float e0 = exp2f(st[f][0] - m_run);
      float e1 = exp2f(st[f][1] - m_run);
      float e2 = exp2f(st[f][2] - m_run);
      float e3 = exp2f(st[f][3] - m_run);
      psum += (e0+e1)+(e2+e3);
      r01[f] = (unsigned)f2b(e0) | ((unsigned)f2b(e1)<<16);
      r23[f] = (unsigned)f2b(e2) | ((unsigned)f2b(e3)<<16);
    }
    l_part += psum;

    const int src0 = (lg&1)*32 + lq;
    const int src1 = src0 + 16;
    const bool hi = (lg>>1) != 0;
    #pragma unroll
    for (int c = 0; c < 4; ++c) {
      unsigned a0 = (unsigned)__shfl((int)r01[c*2],   src0, 64);
      unsigned b0 = (unsigned)__shfl((int)r01[c*2+1], src0, 64);
      unsigned a1 = (unsigned)__shfl((int)r23[c*2],   src0, 64);
      unsigned b1 = (unsigned)__shfl((int)r23[c*2+1], src0, 64);
      unsigned a2 = (unsigned)__shfl((int)r01[c*2],   src1, 64);
      unsigned b2 = (unsigned)__shfl((int)r01[c*2+1], src1, 64);
      unsigned a3 = (unsigned)__shfl((int)r23[c*2],   src1, 64);
      unsigned b3 = (unsigned)__shfl((int)r23[c*2+1], src1, 64);
      uint4 bw;
      bw.x = hi ? b0 : a0;
      bw.y = hi ? b1 : a1;
      bw.z = hi ? b2 : a2;
      bw.w = hi ? b3 : a3;
      bf16x8 pfrag = *(bf16x8*)&bw;
      __builtin_amdgcn_s_setprio(1);
      #pragma unroll
      for (int f = 0; f < 4; ++f) {
        int row = f*16 + lq;
        int pu = (c*4 + lg) ^ (row & 15);
        bf16x8 vf_ = *(const bf16x8*)(Vs[cur] + row*256 + pu*16);
        ot[f] = __builtin_amdgcn_mfma_f32_16x16x32_bf16(vf_, pfrag, ot[f], 0,0,0);
      }
      __builtin_amdgcn_s_setprio(0);
    }
    __syncthreads();
  }

  float l_tot = l_part + __shfl_xor(l_part, 16, 64);
  l_tot += __shfl_xor(l_tot, 32, 64);
  const float inv = 1.0f / l_tot;
  unsigned short* orow = att_bf + ((size_t)(b*256 + q0 + qloc))*512 + hh*64;
  #pragma unroll
  for (int f = 0; f < 4; ++f) {
    uint2 w;
    w.x = (unsigned)f2b(ot[f][0]*inv) | ((unsigned)f2b(ot[f][1]*inv)<<16);
    w.y = (unsigned)f2b(ot[f][2]*inv) | ((unsigned)f2b(ot[f][3]*inv)<<16);
    *(uint2*)(orow + f*16 + lg*4) = w;
  }
}

// ================= FFN1: interleaved W1|W3 + SwiGLU =================
__global__ __launch_bounds__(256) void ffn1_gemm(
    const unsigned short* __restrict__ xin,
    const unsigned short* __restrict__ W1t, const unsigned short* __restrict__ W3t,
    const float* __restrict__ b1_, const float* __restrict__ b3_,
    unsigned short* __restrict__ ff_bf)
{
  __shared__ alignas(16) char As[2*128*64];
  __shared__ alignas(16) char Bs[2*128*64];
  f32x4 acc[16] = {};
  // Column-chunk XCD swizzle (nwg=1024): XCD k = bid&7 owns nt in [4k,4k+4),
  // so its B-slice (1 MB of W1t|W3t) and A (4 MB xin) are both L2-resident.
  const int bid = blockIdx.x;
  const int q = bid >> 3;
  int bx = (q >> 2)*32 + (bid & 7)*4 + (q & 3);
  const int nt = bx & 31, mt = bx >> 5;
  const int m0 = mt*128, n0 = nt*128;
  auto brow = [&](int r) -> const unsigned short* {
    int p = n0 + r;
    int pb = p >> 4;
    int j = ((pb>>1)<<4) | (p & 15);
    return (pb & 1) ? W3t + (size_t)j*512 : W1t + (size_t)j*512;
  };
  mfma_core<128,128,64,64>(xin, 512, m0, brow, 512, As, Bs, acc);
  const int lane = threadIdx.x & 63, wave = threadIdx.x >> 6;
  const int wr = wave >> 1, wc = wave & 1;
  #pragma unroll
  for (int r = 0; r < 4; ++r)
  #pragma unroll
  for (int cp = 0; cp < 4; cp += 2) {
    f32x4 va = acc[r*4+cp];
    f32x4 vb = acc[r*4+cp+1];
    #pragma unroll
    for (int reg = 0; reg < 4; ++reg) {
      int m = m0 + wr*64 + r*16 + ((lane>>4)<<2) + reg;
      int p = n0 + wc*64 + cp*16 + (lane&15);
      int j = ((p>>5)<<4) | (p & 15);
      float a = va[reg] + b1_[j];
      float bb = vb[reg] + b3_[j];
      float gval = (a / (1.0f + __expf(-a))) * bb;
      ff_bf[(size_t)m*2048 + j] = f2b(gval);
    }
  }
}

// ====== residual GEMM (64x64 tile, BK=64: two 32-k panels per barrier) ==========
__global__ __launch_bounds__(256) void res_gemm(
    const unsigned short* __restrict__ A, int lda,
    const unsigned short* __restrict__ Wt, int kd,
    const float* __restrict__ bias, const float* __restrict__ resv,
    float* __restrict__ h)
{
  __shared__ alignas(16) char As[4][64*64];
  __shared__ alignas(16) char Bs[4][64*64];
  f32x4 acc[4] = {};
  int bx = (blockIdx.x & 7)*64 + (blockIdx.x >> 3);   // XCD-chunked swizzle (nwg=512)
  const int mt = bx >> 3, nt = bx & 7;
  const int m0 = mt*64, n0 = nt*64;
  const int tid = threadIdx.x, wave = tid>>6, lane = tid&63;
  const int wr = wave >> 1, wc = wave & 1;
  const int lr = lane>>2;
  const int swl = (lane&3) ^ ((lane>>2)&3) ^ (lane>>4);

  auto stageP = [&](int slot, int k0){
    gl_lds16(A  + (size_t)(m0 + wave*16 + lr)*lda + k0 + swl*8, As[slot] + wave*1024);
    gl_lds16(Wt + (size_t)(n0 + wave*16 + lr)*kd  + k0 + swl*8, Bs[slot] + wave*1024);
  };

  stageP(0, 0);
  stageP(1, 32);
  __syncthreads();
  int cur = 0;
  for (int k0 = 0; k0 < kd; k0 += 64) {
    if (k0 + 64 < kd) { stageP((cur^1)*2, k0+64); stageP((cur^1)*2+1, k0+96); }
    #pragma unroll
    for (int p = 0; p < 2; ++p) {
      const char* ab = As[cur*2+p];
      const char* bb = Bs[cur*2+p];
      bf16x8 af[2], bfv[2];
      #pragma unroll
      for (int r = 0; r < 2; ++r)
        af[r] = *(const bf16x8*)(ab + (wr*32 + r*16 + (lane&15))*64 + swl*16);
      #pragma unroll
      for (int c = 0; c < 2; ++c)
        bfv[c] = *(const bf16x8*)(bb + (wc*32 + c*16 + (lane&15))*64 + swl*16);
      #pragma unroll
      for (int r = 0; r < 2; ++r)
        #pragma unroll
        for (int c = 0; c < 2; ++c)
          acc[r*2+c] = __builtin_amdgcn_mfma_f32_16x16x32_bf16(af[r], bfv[c], acc[r*2+c], 0,0,0);
    }
    __syncthreads();
    cur ^= 1;
  }

  const float rv = resv[0];
  #pragma unroll
  for (int r = 0; r < 2; ++r)
  #pragma unroll
  for (int c = 0; c < 2; ++c) {
    f32x4 v = acc[r*2+c];
    #pragma unroll
    for (int reg = 0; reg < 4; ++reg) {
      int m = m0 + wr*32 + r*16 + ((lane>>4)<<2) + reg;
      int n = n0 + wc*32 + c*16 + (lane&15);
      h[(size_t)m*512 + n] += rv * (v[reg] + bias[n]);
    }
  }
}

// ================= output projection + unpatchify (f32) =================
__global__ __launch_bounds__(256) void outproj_kernel(
    const float* __restrict__ h, const float* __restrict__ outW,
    const float* __restrict__ outb, float* __restrict__ y)
{
  int bs = blockIdx.x;
  int b = bs >> 8, s = bs & 255;
  int tic = s >> 6, mf = s & 63;
  __shared__ float hr[512];
  __shared__ float part[8][32];
  int tid = threadIdx.x;
  hr[tid]     = h[(size_t)bs*D_ + tid];
  hr[tid+256] = h[(size_t)bs*D_ + tid + 256];
  __syncthreads();
  int i = tid & 31, seg = tid >> 5;
  float acc = 0.0f;
  #pragma unroll
  for (int k = 0; k < 64; ++k) acc += hr[seg*64 + k] * outW[(seg*64 + k)*32 + i];
  part[seg][i] = acc;
  __syncthreads();
  if (tid < 32) {
    float v = outb[tid];
    #pragma unroll
    for (int s2 = 0; s2 < 8; ++s2) v += part[s2][tid];
    int tp = tid >> 3, fp = (tid >> 1) & 3, c = tid & 1;
    y[((size_t)(b*2 + c)*16 + tic*4 + tp)*256 + mf*4 + fp] = v;
  }
}

// ================= launch =================
extern "C" void kernel_launch(void* const* d_in, const int* in_sizes, int n_in,
                              void* d_out, int out_size, void* d_ws, size_t ws_size,
                              hipStream_t stream) {
  (void)in_sizes; (void)n_in; (void)out_size; (void)ws_size;
  const float* x        = (const float*)d_in[0];
  const float* cache_k  = (const float*)d_in[1];
  const float* cache_v  = (const float*)d_in[2];
  const float* in_W     = (const float*)d_in[3];
  const float* in_b     = (const float*)d_in[4];
  const float* ln1_g    = (const float*)d_in[5];
  const float* ln1_b    = (const float*)d_in[6];
  const float* Wq       = (const float*)d_in[7];
  const float* bq       = (const float*)d_in[8];
  const float* bk       = (const float*)d_in[10];
  const float* Wk       = (const float*)d_in[9];
  const float* Wv       = (const float*)d_in[11];
  const float* bv       = (const float*)d_in[12];
  const float* Wo       = (const float*)d_in[13];
  const float* bo       = (const float*)d_in[14];
  const float* rel_time = (const float*)d_in[15];
  const float* rel_freq = (const float*)d_in[16];
  const float* res_a    = (const float*)d_in[17];
  const float* ln2_g    = (const float*)d_in[18];
  const float* ln2_b    = (const float*)d_in[19];
  const float* W1       = (const float*)d_in[20];
  const float* b1       = (const float*)d_in[21];
  const float* W3       = (const float*)d_in[22];
  const float* b3       = (const float*)d_in[23];
  const float* W2       = (const float*)d_in[24];
  const float* b2       = (const float*)d_in[25];
  const float* res_f    = (const float*)d_in[26];
  const float* out_W    = (const float*)d_in[27];
  const float* out_b    = (const float*)d_in[28];

  char* ws = (char*)d_ws;
  size_t o = 0;
  float* h            = (float*)(ws + o);          o += (size_t)4096*512*4;
  unsigned short* xin = (unsigned short*)(ws + o); o += (size_t)4096*512*2;
  unsigned short* qb  = (unsigned short*)(ws + o); o += (size_t)4096*512*2;
  unsigned short* att = (unsigned short*)(ws + o); o += (size_t)4096*512*2;
  unsigned short* kfb = (unsigned short*)(ws + o); o += (size_t)64*1024*64*2;
  unsigned short* vtb = (unsigned short*)(ws + o); o += (size_t)64*64*1024*2;
  unsigned short* vnw = (unsigned short*)(ws + o); o += (size_t)4096*256*2;
  float* smean        = (float*)(ws + o);          o += (size_t)4096*4;
  float* srstd        = (float*)(ws + o);          o += (size_t)4096*4;
  unsigned short* Wqt = (unsigned short*)(ws + o); o += (size_t)4*512*512*2;
  unsigned short* Wkt = (unsigned short*)(ws + o); o += (size_t)4*256*512*2;
  unsigned short* Wvt = (unsigned short*)(ws + o); o += (size_t)4*256*512*2;
  unsigned short* Wot = (unsigned short*)(ws + o); o += (size_t)4*512*512*2;
  unsigned short* W1t = (unsigned short*)(ws + o); o += (size_t)4*2048*512*2;
  unsigned short* W3t = (unsigned short*)(ws + o); o += (size_t)4*2048*512*2;
  unsigned short* W2t = (unsigned short*)(ws + o); o += (size_t)4*512*2048*2;
  unsigned short* ffb = (unsigned short*)(ws + o);

  float* y    = (float*)d_out;
  float* nck0 = y + 131072;
  float* ncv0 = nck0 + 12582912;

  transpose_all<<<3840, 256, 0, stream>>>(Wq, Wk, Wv, Wo, W1, W3, W2,
                                          Wqt, Wkt, Wvt, Wot, W1t, W3t, W2t);

  patchify_inproj<<<256, 256, 0, stream>>>(x, in_W, in_b, h);

  for (int l = 0; l < L_; ++l) {
    ln_stats<<<256, 256, 0, stream>>>(h, smean, srstd);
    qkv_ln_gemm<<<512, 256, 0, stream>>>(
        h, smean, srstd, ln1_g + l*512, ln1_b + l*512,
        Wqt + (size_t)l*512*512, Wkt + (size_t)l*256*512, Wvt + (size_t)l*256*512,
        bq + l*512, bk + l*256, bv + l*256,
        qb, kfb, vnw, nck0 + (size_t)l*3145728, ncv0 + (size_t)l*3145728);
    merge_kv<<<4096, 256, 0, stream>>>(
        cache_k + (size_t)l*3145728, cache_v + (size_t)l*3145728, vnw,
        kfb, vtb, nck0 + (size_t)l*3145728, ncv0 + (size_t)l*3145728);
    flash_attn<<<256, 512, 0, stream>>>(qb, kfb, vtb,
        rel_time + l*31*8, rel_freq + l*127*8, att);
    res_gemm<<<512, 256, 0, stream>>>(att, 512, Wot + (size_t)l*512*512, 512,
                                      bo + l*512, res_a + l, h);
    ln_kernel<<<256, 256, 0, stream>>>(h, xin, ln2_g + l*512, ln2_b + l*512);
    ffn1_gemm<<<1024, 256, 0, stream>>>(
        xin, W1t + (size_t)l*2048*512, W3t + (size_t)l*2048*512,
        b1 + l*2048, b3 + l*2048, ffb);
    res_gemm<<<512, 256, 0, stream>>>(ffb, 2048, W2t + (size_t)l*512*2048, 2048,
                                      b2 + l*512, res_f + l, h);
  }

  outproj_kernel<<<M_, 256, 0, stream>>>(h, out_W, out_b, y);
}